// Round 1
// baseline (194.713 us; speedup 1.0000x reference)
//
#include <hip/hip_runtime.h>
#include <hip/hip_bf16.h>
#include <hip/hip_fp16.h>
#include <stdint.h>

typedef _Float16 f16;
typedef _Float16 f16x4 __attribute__((ext_vector_type(4)));
typedef _Float16 f16x8 __attribute__((ext_vector_type(8)));
typedef float f32x4 __attribute__((ext_vector_type(4)));

#define B_ 4
#define QL_ 1024
#define D_ 1024
#define H_ 16
#define HD_ 64
#define KVL_ 2048

// ---- async global->LDS, 16B per lane, wave-uniform LDS base ----
__device__ __forceinline__ void g2lds16(const void* g, void* l) {
    __builtin_amdgcn_global_load_lds(
        (const __attribute__((address_space(1))) uint32_t*)g,
        (__attribute__((address_space(3))) uint32_t*)l,
        16, 0, 0);
}

// ---- elementwise f32 -> f16 convert (vectorized) ----
__global__ void cvt_f32_f16(const float* __restrict__ s, f16* __restrict__ d, int n4) {
    int i = blockIdx.x * blockDim.x + threadIdx.x;
    int st = gridDim.x * blockDim.x;
    for (; i < n4; i += st) {
        float4 v = ((const float4*)s)[i];
        f16x4 o = { (f16)v.x, (f16)v.y, (f16)v.z, (f16)v.w };
        ((f16x4*)d)[i] = o;
    }
}

// ---- 1024x1024 f32 -> transposed f16 (for Wq, Wo: we need B^T row-major-in-K) ----
__global__ void wt_transpose(const float* __restrict__ src, f16* __restrict__ dst) {
    __shared__ float t[64][65];
    int k0 = (blockIdx.x >> 4) << 6;
    int n0 = (blockIdx.x & 15) << 6;
    int tid = threadIdx.x;
    int rr = tid >> 4;          // 0..15
    int c4 = (tid & 15) << 2;   // 0..60
#pragma unroll
    for (int i = 0; i < 4; ++i) {
        int r = i * 16 + rr;
        float4 v = *(const float4*)(src + (size_t)(k0 + r) * 1024 + n0 + c4);
        t[r][c4 + 0] = v.x; t[r][c4 + 1] = v.y; t[r][c4 + 2] = v.z; t[r][c4 + 3] = v.w;
    }
    __syncthreads();
#pragma unroll
    for (int i = 0; i < 4; ++i) {
        int n = i * 16 + rr;
        f16x4 o;
#pragma unroll
        for (int j = 0; j < 4; ++j) o[j] = (f16)t[c4 + j][n];
        *(f16x4*)(dst + (size_t)(n0 + n) * 1024 + k0 + c4) = o;
    }
}

// ---- V (bh,2048,64) f32 -> V_t (bh,64,2048) f16 ----
__global__ void v_transpose(const float* __restrict__ src, f16* __restrict__ dst) {
    __shared__ float t[64][65];
    int bh = blockIdx.x >> 5;           // 0..63
    int kv0 = (blockIdx.x & 31) << 6;
    int tid = threadIdx.x;
    int rr = tid >> 4;
    int c4 = (tid & 15) << 2;
#pragma unroll
    for (int i = 0; i < 4; ++i) {
        int r = i * 16 + rr;            // kv within tile
        float4 v = *(const float4*)(src + ((size_t)bh * KVL_ + kv0 + r) * HD_ + c4);
        t[r][c4 + 0] = v.x; t[r][c4 + 1] = v.y; t[r][c4 + 2] = v.z; t[r][c4 + 3] = v.w;
    }
    __syncthreads();
#pragma unroll
    for (int i = 0; i < 4; ++i) {
        int d = i * 16 + rr;
        f16x4 o;
#pragma unroll
        for (int j = 0; j < 4; ++j) o[j] = (f16)t[c4 + j][d];
        *(f16x4*)(dst + ((size_t)bh * HD_ + d) * KVL_ + kv0 + c4) = o;
    }
}

// ---- GEMM: C[M][N] = A[M][K] * BT[N][K]^T, f16 in, fp32 acc ----
// EPI==0: write f16 to q layout (b,h,q,d); EPI==1: write fp32 row-major
template <int EPI>
__global__ __launch_bounds__(256) void gemm_tn(
    const f16* __restrict__ A, const f16* __restrict__ BT, void* __restrict__ Cout,
    int M, int N, int K) {
    __shared__ char Alds[16384];  // 128 rows x 64 f16 (128B), XOR-swizzled
    __shared__ char Blds[16384];
    int nb = N >> 7;
    int bm = blockIdx.x / nb, bn = blockIdx.x % nb;
    int tid = threadIdx.x, w = tid >> 6, l = tid & 63;
    int l15 = l & 15, lg = l >> 4;
    int wm = w >> 1, wn = w & 1;
    f32x4 acc[4][4] = {};

    // staging descriptors: 16 instrs per tile, 4 per wave; source pre-swizzled
    const char* ag[4]; char* al[4];
    const char* bg[4]; char* bl[4];
#pragma unroll
    for (int jj = 0; jj < 4; ++jj) {
        int instr = w + 4 * jj;               // 0..15
        int r = instr * 8 + (l >> 3);          // LDS row 0..127
        int c = l & 7, cc = c ^ (r & 7);       // inverse-swizzled source chunk
        ag[jj] = (const char*)A + ((size_t)(bm * 128 + r) * K + cc * 8) * 2;
        al[jj] = Alds + instr * 1024;
        bg[jj] = (const char*)BT + ((size_t)(bn * 128 + r) * K + cc * 8) * 2;
        bl[jj] = Blds + instr * 1024;
    }

    int nk = K >> 6;
    for (int kt = 0; kt < nk; ++kt) {
        __syncthreads();
#pragma unroll
        for (int jj = 0; jj < 4; ++jj) g2lds16(ag[jj] + (size_t)kt * 128, al[jj]);
#pragma unroll
        for (int jj = 0; jj < 4; ++jj) g2lds16(bg[jj] + (size_t)kt * 128, bl[jj]);
        asm volatile("s_waitcnt vmcnt(0)" ::: "memory");
        __syncthreads();
#pragma unroll
        for (int ks = 0; ks < 2; ++ks) {
            f16x8 af[4], bf[4];
#pragma unroll
            for (int m = 0; m < 4; ++m) {
                int r = wm * 64 + m * 16 + l15;
                af[m] = *(const f16x8*)(Alds + r * 128 + ((ks * 64 + lg * 16) ^ ((r & 7) << 4)));
            }
#pragma unroll
            for (int n = 0; n < 4; ++n) {
                int r = wn * 64 + n * 16 + l15;
                bf[n] = *(const f16x8*)(Blds + r * 128 + ((ks * 64 + lg * 16) ^ ((r & 7) << 4)));
            }
#pragma unroll
            for (int m = 0; m < 4; ++m)
#pragma unroll
                for (int n = 0; n < 4; ++n)
                    acc[m][n] = __builtin_amdgcn_mfma_f32_16x16x32_f16(af[m], bf[n], acc[m][n], 0, 0, 0);
        }
    }

#pragma unroll
    for (int m = 0; m < 4; ++m)
#pragma unroll
        for (int n = 0; n < 4; ++n)
#pragma unroll
            for (int i = 0; i < 4; ++i) {
                int row = bm * 128 + wm * 64 + m * 16 + lg * 4 + i;
                int col = bn * 128 + wn * 64 + n * 16 + l15;
                if (EPI == 0) {
                    int b = row >> 10, q = row & 1023, h = col >> 6, d = col & 63;
                    ((f16*)Cout)[(((size_t)b * H_ + h) * QL_ + q) * HD_ + d] = (f16)acc[m][n][i];
                } else {
                    ((float*)Cout)[(size_t)row * N + col] = acc[m][n][i];
                }
            }
}

// ---- fused flash attention: q(b,h,q,d) f16, K(b,h,kv,d) f16, V_t(b,h,d,kv) f16 ----
__global__ __launch_bounds__(256) void attn_fused(
    const f16* __restrict__ qh, const f16* __restrict__ kh, const f16* __restrict__ vt,
    const float* __restrict__ mask, f16* __restrict__ aout) {
    __shared__ char lds[8192 * 2 + 4 * 2048];
    char* Klds = lds;            // [64 kv][64 d] f16, swizzled
    char* Vlds = lds + 8192;     // [64 d][64 kv] f16, swizzled
    char* Plds = lds + 16384;    // per-wave [16 q][64 kv] f16, swizzled

    int tid = threadIdx.x, w = tid >> 6, l = tid & 63;
    int l15 = l & 15, lg = l >> 4;
    int bh = blockIdx.x >> 4, qt = blockIdx.x & 15;
    int b = bh >> 4, h = bh & 15;

    // Q fragments held in registers for the whole kernel
    const f16* qp = qh + ((size_t)bh * QL_ + qt * 64 + w * 16 + l15) * HD_ + lg * 8;
    f16x8 qa0 = *(const f16x8*)qp;
    f16x8 qa1 = *(const f16x8*)(qp + 32);

    // staging descriptors (2 K-instrs + 2 V-instrs per wave), source pre-swizzled
    const char* kg[2]; char* klp[2];
    const char* vg[2]; char* vlp[2];
#pragma unroll
    for (int jj = 0; jj < 2; ++jj) {
        int instr = w + 4 * jj;                 // 0..7
        int r = instr * 8 + (l >> 3);            // LDS row 0..63
        int c = l & 7, cc = c ^ (r & 7);
        kg[jj] = (const char*)kh + ((size_t)bh * KVL_ + r) * 128 + cc * 16;
        klp[jj] = Klds + instr * 1024;
        vg[jj] = (const char*)vt + ((size_t)bh * HD_ + r) * (KVL_ * 2) + cc * 16;
        vlp[jj] = Vlds + instr * 1024;
    }

    float mrun[4] = {-1e30f, -1e30f, -1e30f, -1e30f};
    float ssum[4] = {0.f, 0.f, 0.f, 0.f};
    f32x4 acc[4] = {};
    const float* mp = mask + b * KVL_;
    char* P = Plds + w * 2048;

    for (int ch = 0; ch < KVL_ / 64; ++ch) {
        __syncthreads();
        g2lds16(kg[0] + (size_t)ch * 8192, klp[0]);
        g2lds16(kg[1] + (size_t)ch * 8192, klp[1]);
        g2lds16(vg[0] + (size_t)ch * 128, vlp[0]);
        g2lds16(vg[1] + (size_t)ch * 128, vlp[1]);
        asm volatile("s_waitcnt vmcnt(0)" ::: "memory");
        __syncthreads();

        // S = Q K^T  (+mask), 4 tiles of 16q x 16kv
        f32x4 S[4];
#pragma unroll
        for (int t = 0; t < 4; ++t) {
            int r = t * 16 + l15;
            int swz = (r & 7) << 4;
            f16x8 k0 = *(const f16x8*)(Klds + r * 128 + ((lg * 16) ^ swz));
            f16x8 k1 = *(const f16x8*)(Klds + r * 128 + ((64 + lg * 16) ^ swz));
            f32x4 s = {};
            s = __builtin_amdgcn_mfma_f32_16x16x32_f16(qa0, k0, s, 0, 0, 0);
            s = __builtin_amdgcn_mfma_f32_16x16x32_f16(qa1, k1, s, 0, 0, 0);
            float mk = mp[ch * 64 + t * 16 + l15];
            S[t] = s + mk;
        }

        // online softmax: row r = lg*4 + i; reduce across 16 lanes of the group
        float fac[4];
#pragma unroll
        for (int i = 0; i < 4; ++i) {
            float v = fmaxf(fmaxf(S[0][i], S[1][i]), fmaxf(S[2][i], S[3][i]));
            v = fmaxf(v, __shfl_xor(v, 1));
            v = fmaxf(v, __shfl_xor(v, 2));
            v = fmaxf(v, __shfl_xor(v, 4));
            v = fmaxf(v, __shfl_xor(v, 8));
            float mn = fmaxf(mrun[i], v);
            fac[i] = __expf(mrun[i] - mn);
            mrun[i] = mn;
        }
        float rs[4] = {0.f, 0.f, 0.f, 0.f};
#pragma unroll
        for (int t = 0; t < 4; ++t)
#pragma unroll
            for (int i = 0; i < 4; ++i) {
                float p = __expf(S[t][i] - mrun[i]);
                S[t][i] = p;
                rs[i] += p;
            }
#pragma unroll
        for (int i = 0; i < 4; ++i) {
            float v = rs[i];
            v += __shfl_xor(v, 1);
            v += __shfl_xor(v, 2);
            v += __shfl_xor(v, 4);
            v += __shfl_xor(v, 8);
            ssum[i] = ssum[i] * fac[i] + v;
            acc[0][i] *= fac[i]; acc[1][i] *= fac[i];
            acc[2][i] *= fac[i]; acc[3][i] *= fac[i];
        }

        // P -> per-wave LDS (swizzled), then PV
#pragma unroll
        for (int t = 0; t < 4; ++t)
#pragma unroll
            for (int i = 0; i < 4; ++i) {
                int row = lg * 4 + i;
                int byte = row * 128 + ((((t * 16 + l15) * 2)) ^ ((row & 7) << 4));
                *(f16*)(P + byte) = (f16)S[t][i];
            }
#pragma unroll
        for (int ks = 0; ks < 2; ++ks) {
            int pr = l15;
            f16x8 pa = *(const f16x8*)(P + pr * 128 + ((ks * 64 + lg * 16) ^ ((pr & 7) << 4)));
#pragma unroll
            for (int nt = 0; nt < 4; ++nt) {
                int vr = nt * 16 + l15;
                f16x8 vb = *(const f16x8*)(Vlds + vr * 128 + ((ks * 64 + lg * 16) ^ ((vr & 7) << 4)));
                acc[nt] = __builtin_amdgcn_mfma_f32_16x16x32_f16(pa, vb, acc[nt], 0, 0, 0);
            }
        }
    }

    // epilogue: normalize and store to (b, q, h*64+d) f16
#pragma unroll
    for (int nt = 0; nt < 4; ++nt)
#pragma unroll
        for (int i = 0; i < 4; ++i) {
            int q = qt * 64 + w * 16 + lg * 4 + i;
            int d = nt * 16 + l15;
            float o = acc[nt][i] / ssum[i];
            aout[((size_t)b * QL_ + q) * D_ + h * HD_ + d] = (f16)o;
        }
}

extern "C" void kernel_launch(void* const* d_in, const int* in_sizes, int n_in,
                              void* d_out, int out_size, void* d_ws, size_t ws_size,
                              hipStream_t stream) {
    const float* hs = (const float*)d_in[0];
    const float* K  = (const float*)d_in[1];
    const float* V  = (const float*)d_in[2];
    const float* mask = (const float*)d_in[3];
    const float* Wq = (const float*)d_in[4];
    const float* Wo = (const float*)d_in[5];
    float* out = (float*)d_out;
    char* ws = (char*)d_ws;

    f16* hs_h = (f16*)(ws + 0);           //  8 MB
    f16* Wq_t = (f16*)(ws + 8388608);     //  2 MB (Wq^T)
    f16* Wo_t = (f16*)(ws + 10485760);    //  2 MB (Wo^T)
    f16* K_h  = (f16*)(ws + 12582912);    // 16 MB
    f16* V_t  = (f16*)(ws + 29360128);    // 16 MB (b,h,d,kv)
    f16* q_h  = (f16*)(ws + 46137344);    //  8 MB (b,h,q,d)
    f16* a_o  = (f16*)(ws + 54525952);    //  8 MB (b,q,h*64+d)

    cvt_f32_f16<<<1024, 256, 0, stream>>>(hs, hs_h, (B_ * QL_ * D_) / 4);
    cvt_f32_f16<<<1024, 256, 0, stream>>>(K, K_h, (B_ * H_ * KVL_ * HD_) / 4);
    wt_transpose<<<256, 256, 0, stream>>>(Wq, Wq_t);
    wt_transpose<<<256, 256, 0, stream>>>(Wo, Wo_t);
    v_transpose<<<2048, 256, 0, stream>>>(V, V_t);

    gemm_tn<0><<<256, 256, 0, stream>>>(hs_h, Wq_t, (void*)q_h, 4096, 1024, 1024);
    attn_fused<<<1024, 256, 0, stream>>>(q_h, K_h, V_t, mask, a_o);
    gemm_tn<1><<<256, 256, 0, stream>>>(a_o, Wo_t, (void*)out, 4096, 1024, 1024);
}

// Round 2
// 177.731 us; speedup vs baseline: 1.0956x; 1.0956x over previous
//
#include <hip/hip_runtime.h>
#include <hip/hip_bf16.h>
#include <hip/hip_fp16.h>
#include <stdint.h>

typedef _Float16 f16;
typedef _Float16 f16x4 __attribute__((ext_vector_type(4)));
typedef _Float16 f16x8 __attribute__((ext_vector_type(8)));
typedef float f32x4 __attribute__((ext_vector_type(4)));

#define B_ 4
#define QL_ 1024
#define D_ 1024
#define H_ 16
#define HD_ 64
#define KVL_ 2048

// ---- async global->LDS, 16B per lane, wave-uniform LDS base ----
__device__ __forceinline__ void g2lds16(const void* g, void* l) {
    __builtin_amdgcn_global_load_lds(
        (const __attribute__((address_space(1))) uint32_t*)g,
        (__attribute__((address_space(3))) uint32_t*)l,
        16, 0, 0);
}

// ---- elementwise f32 -> f16 convert (vectorized) ----
__global__ void cvt_f32_f16(const float* __restrict__ s, f16* __restrict__ d, int n4) {
    int i = blockIdx.x * blockDim.x + threadIdx.x;
    int st = gridDim.x * blockDim.x;
    for (; i < n4; i += st) {
        float4 v = ((const float4*)s)[i];
        f16x4 o = { (f16)v.x, (f16)v.y, (f16)v.z, (f16)v.w };
        ((f16x4*)d)[i] = o;
    }
}

// ---- 1024x1024 f32 -> transposed f16 (for Wq, Wo) ----
__global__ void wt_transpose(const float* __restrict__ src, f16* __restrict__ dst) {
    __shared__ float t[64][65];
    int k0 = (blockIdx.x >> 4) << 6;
    int n0 = (blockIdx.x & 15) << 6;
    int tid = threadIdx.x;
    int rr = tid >> 4;          // 0..15
    int c4 = (tid & 15) << 2;   // 0..60
#pragma unroll
    for (int i = 0; i < 4; ++i) {
        int r = i * 16 + rr;
        float4 v = *(const float4*)(src + (size_t)(k0 + r) * 1024 + n0 + c4);
        t[r][c4 + 0] = v.x; t[r][c4 + 1] = v.y; t[r][c4 + 2] = v.z; t[r][c4 + 3] = v.w;
    }
    __syncthreads();
#pragma unroll
    for (int i = 0; i < 4; ++i) {
        int n = i * 16 + rr;
        f16x4 o;
#pragma unroll
        for (int j = 0; j < 4; ++j) o[j] = (f16)t[c4 + j][n];
        *(f16x4*)(dst + (size_t)(n0 + n) * 1024 + k0 + c4) = o;
    }
}

// ---- V (bh,2048,64) f32 -> V_t (bh,64,2048) f16 ----
__global__ void v_transpose(const float* __restrict__ src, f16* __restrict__ dst) {
    __shared__ float t[64][65];
    int bh = blockIdx.x >> 5;           // 0..63
    int kv0 = (blockIdx.x & 31) << 6;
    int tid = threadIdx.x;
    int rr = tid >> 4;
    int c4 = (tid & 15) << 2;
#pragma unroll
    for (int i = 0; i < 4; ++i) {
        int r = i * 16 + rr;            // kv within tile
        float4 v = *(const float4*)(src + ((size_t)bh * KVL_ + kv0 + r) * HD_ + c4);
        t[r][c4 + 0] = v.x; t[r][c4 + 1] = v.y; t[r][c4 + 2] = v.z; t[r][c4 + 3] = v.w;
    }
    __syncthreads();
#pragma unroll
    for (int i = 0; i < 4; ++i) {
        int d = i * 16 + rr;
        f16x4 o;
#pragma unroll
        for (int j = 0; j < 4; ++j) o[j] = (f16)t[c4 + j][d];
        *(f16x4*)(dst + ((size_t)bh * HD_ + d) * KVL_ + kv0 + c4) = o;
    }
}

// ---- GEMM: C[M][N] = A[M][K] * BT[N][K]^T, f16 in, fp32 acc, 2-phase dbuf ----
// EPI==0: write f16 to q layout (b,h,q,d); EPI==1: write fp32 row-major
template <int EPI>
__global__ __launch_bounds__(256) void gemm_tn(
    const f16* __restrict__ A, const f16* __restrict__ BT, void* __restrict__ Cout,
    int M, int N, int K) {
    __shared__ char Alds[2][16384];  // 128 rows x 64 f16 (128B), XOR-swizzled
    __shared__ char Blds[2][16384];
    // XCD-aware bijective swizzle: 4 bm-groups per XCD share A panels in L2
    int d0 = blockIdx.x;
    int bm = (d0 & 7) * 4 + ((d0 >> 3) & 3);   // 0..31 (assumes M=4096)
    int bn = d0 >> 5;                           // 0..7  (assumes N=1024)
    int tid = threadIdx.x, w = tid >> 6, l = tid & 63;
    int l15 = l & 15, lg = l >> 4;
    int wm = w >> 1, wn = w & 1;
    f32x4 acc[4][4] = {};

    const char* ag[4]; int ao[4];
    const char* bg[4]; int bo[4];
#pragma unroll
    for (int jj = 0; jj < 4; ++jj) {
        int instr = w + 4 * jj;               // 0..15
        int r = instr * 8 + (l >> 3);          // LDS row 0..127
        int cc = (l & 7) ^ (r & 7);            // inverse-swizzled source chunk
        ag[jj] = (const char*)A + ((size_t)(bm * 128 + r) * K + cc * 8) * 2;
        ao[jj] = instr * 1024;
        bg[jj] = (const char*)BT + ((size_t)(bn * 128 + r) * K + cc * 8) * 2;
        bo[jj] = instr * 1024;
    }

#define GSTAGE(buf, kt)                                                     \
    {                                                                       \
        _Pragma("unroll") for (int jj = 0; jj < 4; ++jj) {                  \
            g2lds16(ag[jj] + (size_t)(kt) * 128, &Alds[buf][ao[jj]]);       \
            g2lds16(bg[jj] + (size_t)(kt) * 128, &Blds[buf][bo[jj]]);       \
        }                                                                   \
    }

    int nk = K >> 6;
    GSTAGE(0, 0);
    asm volatile("s_waitcnt vmcnt(0)" ::: "memory");
    __syncthreads();

    for (int kt = 0; kt < nk; ++kt) {
        int cur = kt & 1;
        if (kt + 1 < nk) GSTAGE(cur ^ 1, kt + 1);
#pragma unroll
        for (int ks = 0; ks < 2; ++ks) {
            f16x8 af[4], bf[4];
#pragma unroll
            for (int m = 0; m < 4; ++m) {
                int r = wm * 64 + m * 16 + l15;
                af[m] = *(const f16x8*)(&Alds[cur][r * 128 + ((ks * 64 + lg * 16) ^ ((r & 7) << 4))]);
            }
#pragma unroll
            for (int n = 0; n < 4; ++n) {
                int r = wn * 64 + n * 16 + l15;
                bf[n] = *(const f16x8*)(&Blds[cur][r * 128 + ((ks * 64 + lg * 16) ^ ((r & 7) << 4))]);
            }
#pragma unroll
            for (int m = 0; m < 4; ++m)
#pragma unroll
                for (int n = 0; n < 4; ++n)
                    acc[m][n] = __builtin_amdgcn_mfma_f32_16x16x32_f16(af[m], bf[n], acc[m][n], 0, 0, 0);
        }
        asm volatile("s_waitcnt vmcnt(0)" ::: "memory");
        __syncthreads();
    }

#pragma unroll
    for (int m = 0; m < 4; ++m)
#pragma unroll
        for (int n = 0; n < 4; ++n)
#pragma unroll
            for (int i = 0; i < 4; ++i) {
                int row = bm * 128 + wm * 64 + m * 16 + lg * 4 + i;
                int col = bn * 128 + wn * 64 + n * 16 + l15;
                if (EPI == 0) {
                    int b = row >> 10, q = row & 1023, h = col >> 6, d = col & 63;
                    ((f16*)Cout)[(((size_t)b * H_ + h) * QL_ + q) * HD_ + d] = (f16)acc[m][n][i];
                } else {
                    ((float*)Cout)[(size_t)row * N + col] = acc[m][n][i];
                }
            }
#undef GSTAGE
}

// ---- fused flash attention, QBLK=128 (4 waves x 32 q-rows), KVBLK=64 dbuf ----
// q(b,h,q,d) f16, K(b,h,kv,d) f16, V_t(b,h,d,kv) f16
__global__ __launch_bounds__(256) void attn_fused(
    const f16* __restrict__ qh, const f16* __restrict__ kh, const f16* __restrict__ vt,
    const float* __restrict__ mask, f16* __restrict__ aout) {
    __shared__ char Klds[2][8192];   // [64 kv][64 d f16 = 128B], swizzled
    __shared__ char Vlds[2][8192];   // [64 d][64 kv f16 = 128B], swizzled
    __shared__ char Plds[4][4096];   // per-wave [32 q][64 kv f16], swizzled

    int tid = threadIdx.x, w = tid >> 6, l = tid & 63;
    int l15 = l & 15, lg = l >> 4;
    // bijective XCD swizzle: 8 bh per XCD -> K/V working set 4MB fits L2
    int d0 = blockIdx.x;                 // 0..511
    int bh = (d0 & 7) * 8 + (d0 >> 6);   // 0..63
    int qt = (d0 >> 3) & 7;              // 0..7
    int b = bh >> 4, h = bh & 15;

    // Q fragments held in registers for the whole kernel: rows w*32 + m*16 + l15
    f16x8 qa[2][2];
#pragma unroll
    for (int m = 0; m < 2; ++m) {
        const f16* qp = qh + ((size_t)bh * QL_ + qt * 128 + w * 32 + m * 16 + l15) * HD_ + lg * 8;
        qa[m][0] = *(const f16x8*)qp;
        qa[m][1] = *(const f16x8*)(qp + 32);
    }

    // staging descriptors (2 K-instrs + 2 V-instrs per wave), source pre-swizzled
    const char* kg[2]; const char* vg[2]; int ko[2], vo[2];
#pragma unroll
    for (int jj = 0; jj < 2; ++jj) {
        int instr = w + 4 * jj;                 // 0..7
        int r = instr * 8 + (l >> 3);            // LDS row 0..63
        int cc = (l & 7) ^ (r & 7);
        kg[jj] = (const char*)kh + ((size_t)bh * KVL_ + r) * 128 + cc * 16;
        ko[jj] = instr * 1024;
        vg[jj] = (const char*)vt + ((size_t)bh * HD_ + r) * (KVL_ * 2) + cc * 16;
        vo[jj] = instr * 1024;
    }

#define ASTAGE(buf, ch)                                          \
    {                                                            \
        g2lds16(kg[0] + (size_t)(ch) * 8192, &Klds[buf][ko[0]]); \
        g2lds16(kg[1] + (size_t)(ch) * 8192, &Klds[buf][ko[1]]); \
        g2lds16(vg[0] + (size_t)(ch) * 128, &Vlds[buf][vo[0]]);  \
        g2lds16(vg[1] + (size_t)(ch) * 128, &Vlds[buf][vo[1]]);  \
    }

    float mrun[2][4], ssum[2][4];
#pragma unroll
    for (int m = 0; m < 2; ++m)
#pragma unroll
        for (int i = 0; i < 4; ++i) { mrun[m][i] = -1e30f; ssum[m][i] = 0.f; }
    f32x4 acc[2][4] = {};
    const float* mp = mask + b * KVL_;
    char* P = Plds[w];

    ASTAGE(0, 0);
    asm volatile("s_waitcnt vmcnt(0)" ::: "memory");
    __syncthreads();

    for (int ch = 0; ch < KVL_ / 64; ++ch) {
        int cur = ch & 1;
        if (ch + 1 < KVL_ / 64) ASTAGE(cur ^ 1, ch + 1);

        // S = Q K^T (+mask): 2 m-tiles x 4 kv-tiles of 16x16
        f32x4 S[2][4];
#pragma unroll
        for (int t = 0; t < 4; ++t) {
            int r = t * 16 + l15;
            int swz = (r & 7) << 4;
            f16x8 k0 = *(const f16x8*)(&Klds[cur][r * 128 + ((lg * 16) ^ swz)]);
            f16x8 k1 = *(const f16x8*)(&Klds[cur][r * 128 + ((64 + lg * 16) ^ swz)]);
            float mk = mp[ch * 64 + t * 16 + l15];
#pragma unroll
            for (int m = 0; m < 2; ++m) {
                f32x4 s = {};
                s = __builtin_amdgcn_mfma_f32_16x16x32_f16(qa[m][0], k0, s, 0, 0, 0);
                s = __builtin_amdgcn_mfma_f32_16x16x32_f16(qa[m][1], k1, s, 0, 0, 0);
                S[m][t] = s + mk;
            }
        }

        // online softmax: row = m*16 + lg*4 + i; reduce over t and the 16-lane group
        float fac[2][4];
#pragma unroll
        for (int m = 0; m < 2; ++m)
#pragma unroll
            for (int i = 0; i < 4; ++i) {
                float v = fmaxf(fmaxf(S[m][0][i], S[m][1][i]), fmaxf(S[m][2][i], S[m][3][i]));
                v = fmaxf(v, __shfl_xor(v, 1));
                v = fmaxf(v, __shfl_xor(v, 2));
                v = fmaxf(v, __shfl_xor(v, 4));
                v = fmaxf(v, __shfl_xor(v, 8));
                float mn = fmaxf(mrun[m][i], v);
                fac[m][i] = __expf(mrun[m][i] - mn);
                mrun[m][i] = mn;
            }
        float rs[2][4] = {};
#pragma unroll
        for (int m = 0; m < 2; ++m)
#pragma unroll
            for (int t = 0; t < 4; ++t)
#pragma unroll
                for (int i = 0; i < 4; ++i) {
                    float p = __expf(S[m][t][i] - mrun[m][i]);
                    S[m][t][i] = p;
                    rs[m][i] += p;
                }
#pragma unroll
        for (int m = 0; m < 2; ++m)
#pragma unroll
            for (int i = 0; i < 4; ++i) {
                float v = rs[m][i];
                v += __shfl_xor(v, 1);
                v += __shfl_xor(v, 2);
                v += __shfl_xor(v, 4);
                v += __shfl_xor(v, 8);
                ssum[m][i] = ssum[m][i] * fac[m][i] + v;
#pragma unroll
                for (int nt = 0; nt < 4; ++nt) acc[m][nt][i] *= fac[m][i];
            }

        // P -> per-wave LDS (swizzled)
#pragma unroll
        for (int m = 0; m < 2; ++m)
#pragma unroll
            for (int t = 0; t < 4; ++t)
#pragma unroll
                for (int i = 0; i < 4; ++i) {
                    int row = m * 16 + lg * 4 + i;
                    int byte = row * 128 + ((((t * 16 + l15) * 2)) ^ ((row & 7) << 4));
                    *(f16*)(P + byte) = (f16)S[m][t][i];
                }
        // PV
#pragma unroll
        for (int ks = 0; ks < 2; ++ks) {
            f16x8 pa[2];
#pragma unroll
            for (int m = 0; m < 2; ++m) {
                int pr = m * 16 + l15;
                pa[m] = *(const f16x8*)(P + pr * 128 + ((ks * 64 + lg * 16) ^ ((pr & 7) << 4)));
            }
#pragma unroll
            for (int nt = 0; nt < 4; ++nt) {
                int vr = nt * 16 + l15;
                f16x8 vb = *(const f16x8*)(&Vlds[cur][vr * 128 + ((ks * 64 + lg * 16) ^ ((vr & 7) << 4))]);
#pragma unroll
                for (int m = 0; m < 2; ++m)
                    acc[m][nt] = __builtin_amdgcn_mfma_f32_16x16x32_f16(pa[m], vb, acc[m][nt], 0, 0, 0);
            }
        }
        asm volatile("s_waitcnt vmcnt(0)" ::: "memory");
        __syncthreads();
    }

    // epilogue: normalize and store to (b, q, h*64+d) f16
#pragma unroll
    for (int m = 0; m < 2; ++m)
#pragma unroll
        for (int nt = 0; nt < 4; ++nt)
#pragma unroll
            for (int i = 0; i < 4; ++i) {
                int q = qt * 128 + w * 32 + m * 16 + lg * 4 + i;
                int d = nt * 16 + l15;
                float o = acc[m][nt][i] / ssum[m][i];
                aout[((size_t)b * QL_ + q) * D_ + h * HD_ + d] = (f16)o;
            }
#undef ASTAGE
}

extern "C" void kernel_launch(void* const* d_in, const int* in_sizes, int n_in,
                              void* d_out, int out_size, void* d_ws, size_t ws_size,
                              hipStream_t stream) {
    const float* hs = (const float*)d_in[0];
    const float* K  = (const float*)d_in[1];
    const float* V  = (const float*)d_in[2];
    const float* mask = (const float*)d_in[3];
    const float* Wq = (const float*)d_in[4];
    const float* Wo = (const float*)d_in[5];
    float* out = (float*)d_out;
    char* ws = (char*)d_ws;

    f16* hs_h = (f16*)(ws + 0);           //  8 MB
    f16* Wq_t = (f16*)(ws + 8388608);     //  2 MB (Wq^T)
    f16* Wo_t = (f16*)(ws + 10485760);    //  2 MB (Wo^T)
    f16* K_h  = (f16*)(ws + 12582912);    // 16 MB
    f16* V_t  = (f16*)(ws + 29360128);    // 16 MB (b,h,d,kv)
    f16* q_h  = (f16*)(ws + 46137344);    //  8 MB (b,h,q,d)
    f16* a_o  = (f16*)(ws + 54525952);    //  8 MB (b,q,h*64+d)

    cvt_f32_f16<<<1024, 256, 0, stream>>>(hs, hs_h, (B_ * QL_ * D_) / 4);
    cvt_f32_f16<<<1024, 256, 0, stream>>>(K, K_h, (B_ * H_ * KVL_ * HD_) / 4);
    wt_transpose<<<256, 256, 0, stream>>>(Wq, Wq_t);
    wt_transpose<<<256, 256, 0, stream>>>(Wo, Wo_t);
    v_transpose<<<2048, 256, 0, stream>>>(V, V_t);

    gemm_tn<0><<<256, 256, 0, stream>>>(hs_h, Wq_t, (void*)q_h, 4096, 1024, 1024);
    attn_fused<<<512, 256, 0, stream>>>(q_h, K_h, V_t, mask, a_o);
    gemm_tn<1><<<256, 256, 0, stream>>>(a_o, Wo_t, (void*)out, 4096, 1024, 1024);
}

// Round 3
// 168.603 us; speedup vs baseline: 1.1549x; 1.0541x over previous
//
#include <hip/hip_runtime.h>
#include <hip/hip_bf16.h>
#include <hip/hip_fp16.h>
#include <stdint.h>

typedef _Float16 f16;
typedef _Float16 f16x4 __attribute__((ext_vector_type(4)));
typedef _Float16 f16x8 __attribute__((ext_vector_type(8)));
typedef float f32x4 __attribute__((ext_vector_type(4)));

#define B_ 4
#define QL_ 1024
#define D_ 1024
#define H_ 16
#define HD_ 64
#define KVL_ 2048
#define L2E 1.44269504088896f

// ---- async global->LDS, 16B per lane, wave-uniform LDS base ----
__device__ __forceinline__ void g2lds16(const void* g, void* l) {
    __builtin_amdgcn_global_load_lds(
        (const __attribute__((address_space(1))) uint32_t*)g,
        (__attribute__((address_space(3))) uint32_t*)l,
        16, 0, 0);
}

// ---- elementwise f32 -> f16 convert (vectorized) ----
__global__ void cvt_f32_f16(const float* __restrict__ s, f16* __restrict__ d, int n4) {
    int i = blockIdx.x * blockDim.x + threadIdx.x;
    int st = gridDim.x * blockDim.x;
    for (; i < n4; i += st) {
        float4 v = ((const float4*)s)[i];
        f16x4 o = { (f16)v.x, (f16)v.y, (f16)v.z, (f16)v.w };
        ((f16x4*)d)[i] = o;
    }
}

// ---- 1024x1024 f32 -> transposed f16, two matrices in one launch ----
__global__ void wt_transpose2(const float* __restrict__ s0, f16* __restrict__ d0p,
                              const float* __restrict__ s1, f16* __restrict__ d1p) {
    __shared__ float t[64][65];
    const float* src = blockIdx.x < 256 ? s0 : s1;
    f16* dst = blockIdx.x < 256 ? d0p : d1p;
    int bid = blockIdx.x & 255;
    int k0 = (bid >> 4) << 6;
    int n0 = (bid & 15) << 6;
    int tid = threadIdx.x;
    int rr = tid >> 4;          // 0..15
    int c4 = (tid & 15) << 2;   // 0..60
#pragma unroll
    for (int i = 0; i < 4; ++i) {
        int r = i * 16 + rr;
        float4 v = *(const float4*)(src + (size_t)(k0 + r) * 1024 + n0 + c4);
        t[r][c4 + 0] = v.x; t[r][c4 + 1] = v.y; t[r][c4 + 2] = v.z; t[r][c4 + 3] = v.w;
    }
    __syncthreads();
#pragma unroll
    for (int i = 0; i < 4; ++i) {
        int n = i * 16 + rr;
        f16x4 o;
#pragma unroll
        for (int j = 0; j < 4; ++j) o[j] = (f16)t[c4 + j][n];
        *(f16x4*)(dst + (size_t)(n0 + n) * 1024 + k0 + c4) = o;
    }
}

// ---- V (bh,2048,64) f32 -> V_t (bh,64,2048) f16 ----
__global__ void v_transpose(const float* __restrict__ src, f16* __restrict__ dst) {
    __shared__ float t[64][65];
    int bh = blockIdx.x >> 5;           // 0..63
    int kv0 = (blockIdx.x & 31) << 6;
    int tid = threadIdx.x;
    int rr = tid >> 4;
    int c4 = (tid & 15) << 2;
#pragma unroll
    for (int i = 0; i < 4; ++i) {
        int r = i * 16 + rr;            // kv within tile
        float4 v = *(const float4*)(src + ((size_t)bh * KVL_ + kv0 + r) * HD_ + c4);
        t[r][c4 + 0] = v.x; t[r][c4 + 1] = v.y; t[r][c4 + 2] = v.z; t[r][c4 + 3] = v.w;
    }
    __syncthreads();
#pragma unroll
    for (int i = 0; i < 4; ++i) {
        int d = i * 16 + rr;
        f16x4 o;
#pragma unroll
        for (int j = 0; j < 4; ++j) o[j] = (f16)t[c4 + j][d];
        *(f16x4*)(dst + ((size_t)bh * HD_ + d) * KVL_ + kv0 + c4) = o;
    }
}

// ---- GEMM: C[M][N] = A[M][K] * BT[N][K]^T, f16 in, fp32 acc, 2-phase dbuf ----
// BM=128, BN=64, BK=64, 512 threads (8 waves, 32x32 per wave), grid = (M/128)*(N/64)
// EPI==0: write f16*L2E to q layout (b,h,q,d); EPI==1: write fp32 row-major
template <int EPI>
__global__ __launch_bounds__(512) void gemm_tn(
    const f16* __restrict__ A, const f16* __restrict__ BT, void* __restrict__ Cout,
    int M, int N, int K) {
    __shared__ char Alds[2][16384];  // 128 rows x 64 f16 (128B), XOR-swizzled
    __shared__ char Blds[2][8192];   // 64 rows x 64 f16
    // bijective XCD swizzle (assumes grid 512: M=4096,N=1024): 4 bm x 16 bn per XCD
    int d0 = blockIdx.x;
    int xcd = d0 & 7, sx = d0 >> 3;            // sx 0..63
    int bm = xcd * 4 + (sx & 3);               // 0..31
    int bn = sx >> 2;                          // 0..15
    int tid = threadIdx.x, w = tid >> 6, l = tid & 63;
    int l15 = l & 15, lg = l >> 4;
    int wm = w >> 1, wn = w & 1;               // 4 x 2 wave grid
    f32x4 acc[2][2] = {};

    const char* ag[2]; int ao[2];
#pragma unroll
    for (int jj = 0; jj < 2; ++jj) {
        int instr = w + 8 * jj;                // 0..15
        int r = instr * 8 + (l >> 3);          // LDS row 0..127
        int cc = (l & 7) ^ (r & 7);            // inverse-swizzled source chunk
        ag[jj] = (const char*)A + ((size_t)(bm * 128 + r) * K + cc * 8) * 2;
        ao[jj] = instr * 1024;
    }
    int rB = w * 8 + (l >> 3);                 // 0..63
    int ccB = (l & 7) ^ (rB & 7);
    const char* bgp = (const char*)BT + ((size_t)(bn * 64 + rB) * K + ccB * 8) * 2;
    int boB = w * 1024;

#define GSTAGE(buf, kt)                                       \
    {                                                         \
        g2lds16(ag[0] + (size_t)(kt) * 128, &Alds[buf][ao[0]]); \
        g2lds16(ag[1] + (size_t)(kt) * 128, &Alds[buf][ao[1]]); \
        g2lds16(bgp + (size_t)(kt) * 128, &Blds[buf][boB]);     \
    }

    int nk = K >> 6;
    GSTAGE(0, 0);
    asm volatile("s_waitcnt vmcnt(0)" ::: "memory");
    __syncthreads();

    for (int kt = 0; kt < nk; ++kt) {
        int cur = kt & 1;
        if (kt + 1 < nk) GSTAGE(cur ^ 1, kt + 1);
#pragma unroll
        for (int ks = 0; ks < 2; ++ks) {
            f16x8 af[2], bf[2];
#pragma unroll
            for (int m = 0; m < 2; ++m) {
                int r = wm * 32 + m * 16 + l15;
                af[m] = *(const f16x8*)(&Alds[cur][r * 128 + ((ks * 64 + lg * 16) ^ ((r & 7) << 4))]);
            }
#pragma unroll
            for (int n = 0; n < 2; ++n) {
                int r = wn * 32 + n * 16 + l15;
                bf[n] = *(const f16x8*)(&Blds[cur][r * 128 + ((ks * 64 + lg * 16) ^ ((r & 7) << 4))]);
            }
#pragma unroll
            for (int m = 0; m < 2; ++m)
#pragma unroll
                for (int n = 0; n < 2; ++n)
                    acc[m][n] = __builtin_amdgcn_mfma_f32_16x16x32_f16(af[m], bf[n], acc[m][n], 0, 0, 0);
        }
        asm volatile("s_waitcnt vmcnt(0)" ::: "memory");
        __syncthreads();
    }

#pragma unroll
    for (int m = 0; m < 2; ++m)
#pragma unroll
        for (int n = 0; n < 2; ++n)
#pragma unroll
            for (int i = 0; i < 4; ++i) {
                int row = bm * 128 + wm * 32 + m * 16 + lg * 4 + i;
                int col = bn * 64 + wn * 32 + n * 16 + l15;
                if (EPI == 0) {
                    // fold log2(e) into Q so attention can use native exp2
                    float v = acc[m][n][i] * L2E;
                    int b = row >> 10, q = row & 1023, h = col >> 6, d = col & 63;
                    ((f16*)Cout)[(((size_t)b * H_ + h) * QL_ + q) * HD_ + d] = (f16)v;
                } else {
                    ((float*)Cout)[(size_t)row * N + col] = acc[m][n][i];
                }
            }
#undef GSTAGE
}

// ---- fused flash attention, QBLK=64 (4 waves x 16 q-rows), KVBLK=64 dbuf ----
// q(b,h,q,d) f16 pre-scaled by log2e, K(b,h,kv,d) f16, V_t(b,h,d,kv) f16
// exp2-domain online softmax with deferred max (THR=12 log2-units)
__global__ __launch_bounds__(256) void attn_fused(
    const f16* __restrict__ qh, const f16* __restrict__ kh, const f16* __restrict__ vt,
    const float* __restrict__ mask, f16* __restrict__ aout) {
    __shared__ char Klds[2][8192];   // [64 kv][64 d f16 = 128B], swizzled
    __shared__ char Vlds[2][8192];   // [64 d][64 kv f16 = 128B], swizzled
    __shared__ char Plds[4][2048];   // per-wave [16 q][64 kv f16], swizzled

    int tid = threadIdx.x, w = tid >> 6, l = tid & 63;
    int l15 = l & 15, lg = l >> 4;
    // bijective XCD swizzle: 8 bh per XCD (K/V set ~4MB fits per-XCD L2)
    int d0 = blockIdx.x;                 // 0..1023
    int xcd = d0 & 7, sx = d0 >> 3;      // sx 0..127
    int bh = xcd * 8 + (sx & 7);         // 0..63
    int qt = sx >> 3;                    // 0..15
    int b = bh >> 4, h = bh & 15;

    // Q fragments in registers (A-operand row = l15)
    const f16* qp = qh + ((size_t)bh * QL_ + qt * 64 + w * 16 + l15) * HD_ + lg * 8;
    f16x8 qa0 = *(const f16x8*)qp;
    f16x8 qa1 = *(const f16x8*)(qp + 32);

    // staging descriptors (2 K + 2 V instrs per wave), source pre-swizzled
    const char* kg[2]; const char* vg[2]; int ko[2], vo[2];
#pragma unroll
    for (int jj = 0; jj < 2; ++jj) {
        int instr = w + 4 * jj;                 // 0..7
        int r = instr * 8 + (l >> 3);            // LDS row 0..63
        int cc = (l & 7) ^ (r & 7);
        kg[jj] = (const char*)kh + ((size_t)bh * KVL_ + r) * 128 + cc * 16;
        ko[jj] = instr * 1024;
        vg[jj] = (const char*)vt + ((size_t)bh * HD_ + r) * (KVL_ * 2) + cc * 16;
        vo[jj] = instr * 1024;
    }

#define ASTAGE(buf, ch)                                          \
    {                                                            \
        g2lds16(kg[0] + (size_t)(ch) * 8192, &Klds[buf][ko[0]]); \
        g2lds16(kg[1] + (size_t)(ch) * 8192, &Klds[buf][ko[1]]); \
        g2lds16(vg[0] + (size_t)(ch) * 128, &Vlds[buf][vo[0]]);  \
        g2lds16(vg[1] + (size_t)(ch) * 128, &Vlds[buf][vo[1]]);  \
    }

    float mrun[4] = {-1e30f, -1e30f, -1e30f, -1e30f};
    float ssum[4] = {0.f, 0.f, 0.f, 0.f};   // per-lane partial (this lane's 4 cols)
    f32x4 acc[4] = {};
    const float* mp = mask + b * KVL_;
    char* P = Plds[w];

    ASTAGE(0, 0);
    asm volatile("s_waitcnt vmcnt(0)" ::: "memory");
    __syncthreads();

    for (int ch = 0; ch < KVL_ / 64; ++ch) {
        int cur = ch & 1;
        if (ch + 1 < KVL_ / 64) ASTAGE(cur ^ 1, ch + 1);

        // S2 = (QK^T)*log2e + mask*log2e : 4 kv-tiles of 16x16
        f32x4 S[4];
#pragma unroll
        for (int t = 0; t < 4; ++t) {
            int r = t * 16 + l15;
            int swz = (r & 7) << 4;
            f16x8 k0 = *(const f16x8*)(&Klds[cur][r * 128 + ((lg * 16) ^ swz)]);
            f16x8 k1 = *(const f16x8*)(&Klds[cur][r * 128 + ((64 + lg * 16) ^ swz)]);
            f32x4 s = {};
            s = __builtin_amdgcn_mfma_f32_16x16x32_f16(qa0, k0, s, 0, 0, 0);
            s = __builtin_amdgcn_mfma_f32_16x16x32_f16(qa1, k1, s, 0, 0, 0);
            float mkL = mp[ch * 64 + t * 16 + l15] * L2E;
            S[t] = s + mkL;
        }

        // lane-local row max (row = lg*4+i, this lane's 4 cols)
        float lmax[4];
#pragma unroll
        for (int i = 0; i < 4; ++i)
            lmax[i] = fmaxf(fmaxf(fmaxf(S[0][i], S[1][i]), S[2][i]), S[3][i]);
        bool big = (lmax[0] > mrun[0] + 12.f) || (lmax[1] > mrun[1] + 12.f) ||
                   (lmax[2] > mrun[2] + 12.f) || (lmax[3] > mrun[3] + 12.f);
        if (__any(big)) {   // rare after warmup: full reduce + rescale
#pragma unroll
            for (int i = 0; i < 4; ++i) {
                float v = lmax[i];
                v = fmaxf(v, __shfl_xor(v, 1));
                v = fmaxf(v, __shfl_xor(v, 2));
                v = fmaxf(v, __shfl_xor(v, 4));
                v = fmaxf(v, __shfl_xor(v, 8));
                float mn = fmaxf(mrun[i], v);
                float fac = exp2f(mrun[i] - mn);
                mrun[i] = mn;
                ssum[i] *= fac;
#pragma unroll
                for (int nt = 0; nt < 4; ++nt) acc[nt][i] *= fac;
            }
        }

        // p = exp2(S2 - mrun) (bounded by 2^12); per-lane partial sums
#pragma unroll
        for (int i = 0; i < 4; ++i) {
            float p0 = exp2f(S[0][i] - mrun[i]);
            float p1 = exp2f(S[1][i] - mrun[i]);
            float p2 = exp2f(S[2][i] - mrun[i]);
            float p3 = exp2f(S[3][i] - mrun[i]);
            ssum[i] += (p0 + p1) + (p2 + p3);
            S[0][i] = p0; S[1][i] = p1; S[2][i] = p2; S[3][i] = p3;
        }

        // P -> per-wave LDS (swizzled)
#pragma unroll
        for (int t = 0; t < 4; ++t)
#pragma unroll
            for (int i = 0; i < 4; ++i) {
                int row = lg * 4 + i;
                int byte = row * 128 + ((((t * 16 + l15) * 2)) ^ ((row & 7) << 4));
                *(f16*)(P + byte) = (f16)S[t][i];
            }
        // PV
#pragma unroll
        for (int ks = 0; ks < 2; ++ks) {
            int pr = l15;
            f16x8 pa = *(const f16x8*)(P + pr * 128 + ((ks * 64 + lg * 16) ^ ((pr & 7) << 4)));
#pragma unroll
            for (int nt = 0; nt < 4; ++nt) {
                int vr = nt * 16 + l15;
                f16x8 vb = *(const f16x8*)(&Vlds[cur][vr * 128 + ((ks * 64 + lg * 16) ^ ((vr & 7) << 4))]);
                acc[nt] = __builtin_amdgcn_mfma_f32_16x16x32_f16(pa, vb, acc[nt], 0, 0, 0);
            }
        }
        asm volatile("s_waitcnt vmcnt(0)" ::: "memory");
        __syncthreads();
    }

    // epilogue: reduce per-lane ssum across the 16-lane group, normalize, store
#pragma unroll
    for (int i = 0; i < 4; ++i) {
        float v = ssum[i];
        v += __shfl_xor(v, 1);
        v += __shfl_xor(v, 2);
        v += __shfl_xor(v, 4);
        v += __shfl_xor(v, 8);
        ssum[i] = v;
    }
#pragma unroll
    for (int nt = 0; nt < 4; ++nt)
#pragma unroll
        for (int i = 0; i < 4; ++i) {
            int q = qt * 64 + w * 16 + lg * 4 + i;
            int d = nt * 16 + l15;
            float o = acc[nt][i] / ssum[i];
            aout[((size_t)b * QL_ + q) * D_ + h * HD_ + d] = (f16)o;
        }
#undef ASTAGE
}

extern "C" void kernel_launch(void* const* d_in, const int* in_sizes, int n_in,
                              void* d_out, int out_size, void* d_ws, size_t ws_size,
                              hipStream_t stream) {
    const float* hs = (const float*)d_in[0];
    const float* K  = (const float*)d_in[1];
    const float* V  = (const float*)d_in[2];
    const float* mask = (const float*)d_in[3];
    const float* Wq = (const float*)d_in[4];
    const float* Wo = (const float*)d_in[5];
    float* out = (float*)d_out;
    char* ws = (char*)d_ws;

    f16* hs_h = (f16*)(ws + 0);           //  8 MB
    f16* Wq_t = (f16*)(ws + 8388608);     //  2 MB (Wq^T)
    f16* Wo_t = (f16*)(ws + 10485760);    //  2 MB (Wo^T)
    f16* K_h  = (f16*)(ws + 12582912);    // 16 MB
    f16* V_t  = (f16*)(ws + 29360128);    // 16 MB (b,h,d,kv)
    f16* q_h  = (f16*)(ws + 46137344);    //  8 MB (b,h,q,d), pre-scaled by log2e
    f16* a_o  = (f16*)(ws + 54525952);    //  8 MB (b,q,h*64+d)

    cvt_f32_f16<<<1024, 256, 0, stream>>>(hs, hs_h, (B_ * QL_ * D_) / 4);
    cvt_f32_f16<<<1024, 256, 0, stream>>>(K, K_h, (B_ * H_ * KVL_ * HD_) / 4);
    wt_transpose2<<<512, 256, 0, stream>>>(Wq, Wq_t, Wo, Wo_t);
    v_transpose<<<2048, 256, 0, stream>>>(V, V_t);

    gemm_tn<0><<<512, 512, 0, stream>>>(hs_h, Wq_t, (void*)q_h, 4096, 1024, 1024);
    attn_fused<<<1024, 256, 0, stream>>>(q_h, K_h, V_t, mask, a_o);
    gemm_tn<1><<<512, 512, 0, stream>>>(a_o, Wo_t, (void*)out, 4096, 1024, 1024);
}

// Round 4
// 141.907 us; speedup vs baseline: 1.3721x; 1.1881x over previous
//
#include <hip/hip_runtime.h>
#include <hip/hip_bf16.h>
#include <hip/hip_fp16.h>
#include <stdint.h>

typedef _Float16 f16;
typedef _Float16 f16x4 __attribute__((ext_vector_type(4)));
typedef _Float16 f16x8 __attribute__((ext_vector_type(8)));
typedef float f32x4 __attribute__((ext_vector_type(4)));
typedef float f32x16 __attribute__((ext_vector_type(16)));

#define B_ 4
#define QL_ 1024
#define D_ 1024
#define H_ 16
#define HD_ 64
#define KVL_ 2048
#define L2E 1.44269504088896f

// ---- async global->LDS, 16B per lane, wave-uniform LDS base ----
__device__ __forceinline__ void g2lds16(const void* g, void* l) {
    __builtin_amdgcn_global_load_lds(
        (const __attribute__((address_space(1))) uint32_t*)g,
        (__attribute__((address_space(3))) uint32_t*)l,
        16, 0, 0);
}

union U8 { uint32_t u[4]; f16x8 v; };

__device__ __forceinline__ uint32_t pkrtz(float a, float b) {
    auto t = __builtin_amdgcn_cvt_pkrtz(a, b);
    return __builtin_bit_cast(uint32_t, t);
}

// ---- elementwise f32 -> f16 convert (vectorized) ----
__global__ void cvt_f32_f16(const float* __restrict__ s, f16* __restrict__ d, int n4) {
    int i = blockIdx.x * blockDim.x + threadIdx.x;
    int st = gridDim.x * blockDim.x;
    for (; i < n4; i += st) {
        float4 v = ((const float4*)s)[i];
        f16x4 o = { (f16)v.x, (f16)v.y, (f16)v.z, (f16)v.w };
        ((f16x4*)d)[i] = o;
    }
}

// ---- 1024x1024 f32 -> transposed f16, two matrices in one launch ----
__global__ void wt_transpose2(const float* __restrict__ s0, f16* __restrict__ d0p,
                              const float* __restrict__ s1, f16* __restrict__ d1p) {
    __shared__ float t[64][65];
    const float* src = blockIdx.x < 256 ? s0 : s1;
    f16* dst = blockIdx.x < 256 ? d0p : d1p;
    int bid = blockIdx.x & 255;
    int k0 = (bid >> 4) << 6;
    int n0 = (bid & 15) << 6;
    int tid = threadIdx.x;
    int rr = tid >> 4;          // 0..15
    int c4 = (tid & 15) << 2;   // 0..60
#pragma unroll
    for (int i = 0; i < 4; ++i) {
        int r = i * 16 + rr;
        float4 v = *(const float4*)(src + (size_t)(k0 + r) * 1024 + n0 + c4);
        t[r][c4 + 0] = v.x; t[r][c4 + 1] = v.y; t[r][c4 + 2] = v.z; t[r][c4 + 3] = v.w;
    }
    __syncthreads();
#pragma unroll
    for (int i = 0; i < 4; ++i) {
        int n = i * 16 + rr;
        f16x4 o;
#pragma unroll
        for (int j = 0; j < 4; ++j) o[j] = (f16)t[c4 + j][n];
        *(f16x4*)(dst + (size_t)(n0 + n) * 1024 + k0 + c4) = o;
    }
}

// ---- V (bh,2048,64) f32 -> V_t (bh,64,2048) f16 ----
__global__ void v_transpose(const float* __restrict__ src, f16* __restrict__ dst) {
    __shared__ float t[64][65];
    int bh = blockIdx.x >> 5;           // 0..63
    int kv0 = (blockIdx.x & 31) << 6;
    int tid = threadIdx.x;
    int rr = tid >> 4;
    int c4 = (tid & 15) << 2;
#pragma unroll
    for (int i = 0; i < 4; ++i) {
        int r = i * 16 + rr;            // kv within tile
        float4 v = *(const float4*)(src + ((size_t)bh * KVL_ + kv0 + r) * HD_ + c4);
        t[r][c4 + 0] = v.x; t[r][c4 + 1] = v.y; t[r][c4 + 2] = v.z; t[r][c4 + 3] = v.w;
    }
    __syncthreads();
#pragma unroll
    for (int i = 0; i < 4; ++i) {
        int d = i * 16 + rr;
        f16x4 o;
#pragma unroll
        for (int j = 0; j < 4; ++j) o[j] = (f16)t[c4 + j][d];
        *(f16x4*)(dst + ((size_t)bh * HD_ + d) * KVL_ + kv0 + c4) = o;
    }
}

// ---- GEMM: C[M][N] = A[M][K] * BT[N][K]^T, f16 in, fp32 acc, 2-phase dbuf ----
// BM=128, BN=64, BK=64, 512 threads (8 waves, 32x32 per wave), grid = (M/128)*(N/64)
// EPI==0: write f16*L2E to q layout (b,h,q,d); EPI==1: write fp32 row-major
template <int EPI>
__global__ __launch_bounds__(512) void gemm_tn(
    const f16* __restrict__ A, const f16* __restrict__ BT, void* __restrict__ Cout,
    int M, int N, int K) {
    __shared__ char Alds[2][16384];  // 128 rows x 64 f16 (128B), XOR-swizzled
    __shared__ char Blds[2][8192];   // 64 rows x 64 f16
    // bijective XCD swizzle (assumes grid 512: M=4096,N=1024): 4 bm x 16 bn per XCD
    int d0 = blockIdx.x;
    int xcd = d0 & 7, sx = d0 >> 3;            // sx 0..63
    int bm = xcd * 4 + (sx & 3);               // 0..31
    int bn = sx >> 2;                          // 0..15
    int tid = threadIdx.x, w = tid >> 6, l = tid & 63;
    int l15 = l & 15, lg = l >> 4;
    int wm = w >> 1, wn = w & 1;               // 4 x 2 wave grid
    f32x4 acc[2][2] = {};

    const char* ag[2]; int ao[2];
#pragma unroll
    for (int jj = 0; jj < 2; ++jj) {
        int instr = w + 8 * jj;                // 0..15
        int r = instr * 8 + (l >> 3);          // LDS row 0..127
        int cc = (l & 7) ^ (r & 7);            // inverse-swizzled source chunk
        ag[jj] = (const char*)A + ((size_t)(bm * 128 + r) * K + cc * 8) * 2;
        ao[jj] = instr * 1024;
    }
    int rB = w * 8 + (l >> 3);                 // 0..63
    int ccB = (l & 7) ^ (rB & 7);
    const char* bgp = (const char*)BT + ((size_t)(bn * 64 + rB) * K + ccB * 8) * 2;
    int boB = w * 1024;

#define GSTAGE(buf, kt)                                       \
    {                                                         \
        g2lds16(ag[0] + (size_t)(kt) * 128, &Alds[buf][ao[0]]); \
        g2lds16(ag[1] + (size_t)(kt) * 128, &Alds[buf][ao[1]]); \
        g2lds16(bgp + (size_t)(kt) * 128, &Blds[buf][boB]);     \
    }

    int nk = K >> 6;
    GSTAGE(0, 0);
    asm volatile("s_waitcnt vmcnt(0)" ::: "memory");
    __syncthreads();

    for (int kt = 0; kt < nk; ++kt) {
        int cur = kt & 1;
        if (kt + 1 < nk) GSTAGE(cur ^ 1, kt + 1);
#pragma unroll
        for (int ks = 0; ks < 2; ++ks) {
            f16x8 af[2], bf[2];
#pragma unroll
            for (int m = 0; m < 2; ++m) {
                int r = wm * 32 + m * 16 + l15;
                af[m] = *(const f16x8*)(&Alds[cur][r * 128 + ((ks * 64 + lg * 16) ^ ((r & 7) << 4))]);
            }
#pragma unroll
            for (int n = 0; n < 2; ++n) {
                int r = wn * 32 + n * 16 + l15;
                bf[n] = *(const f16x8*)(&Blds[cur][r * 128 + ((ks * 64 + lg * 16) ^ ((r & 7) << 4))]);
            }
#pragma unroll
            for (int m = 0; m < 2; ++m)
#pragma unroll
                for (int n = 0; n < 2; ++n)
                    acc[m][n] = __builtin_amdgcn_mfma_f32_16x16x32_f16(af[m], bf[n], acc[m][n], 0, 0, 0);
        }
        asm volatile("s_waitcnt vmcnt(0)" ::: "memory");
        __syncthreads();
    }

#pragma unroll
    for (int m = 0; m < 2; ++m)
#pragma unroll
        for (int n = 0; n < 2; ++n)
#pragma unroll
            for (int i = 0; i < 4; ++i) {
                int row = bm * 128 + wm * 32 + m * 16 + lg * 4 + i;
                int col = bn * 64 + wn * 32 + n * 16 + l15;
                if (EPI == 0) {
                    // fold log2(e) into Q so attention can use native exp2
                    float v = acc[m][n][i] * L2E;
                    int b = row >> 10, q = row & 1023, h = col >> 6, d = col & 63;
                    ((f16*)Cout)[(((size_t)b * H_ + h) * QL_ + q) * HD_ + d] = (f16)v;
                } else {
                    ((float*)Cout)[(size_t)row * N + col] = acc[m][n][i];
                }
            }
#undef GSTAGE
}

// ---- fused flash attention, swapped-operand 32x32x16 MFMA ----
// QBLK=128 (4 waves x 32 q), KVBLK=64 dbuf. q pre-scaled by log2e.
// S^T = mfma(K, Q): lane's q = l&31; softmax lane-local; P stays in registers
// (V B-frag gathered with 2x ds_read_b64 to match P's natural k-slot order).
__global__ __launch_bounds__(256) void attn_fused(
    const f16* __restrict__ qh, const f16* __restrict__ kh, const f16* __restrict__ vt,
    const float* __restrict__ mask, f16* __restrict__ aout) {
    __shared__ char Klds[2][8192];   // [64 kv][64 d f16 = 128B], XOR-swizzled rows
    __shared__ char Vlds[2][8192];   // [64 d][64 kv f16 = 128B], XOR-swizzled rows
    __shared__ float fr_lds[4][32];  // per-wave broadcast scratch (fac / 1/ssum)

    int tid = threadIdx.x, w = tid >> 6, l = tid & 63;
    int l31 = l & 31, hi = l >> 5;
    int swl = (l31 & 7) << 4;
    // bijective XCD swizzle: 8 bh per XCD
    int d0 = blockIdx.x;                 // 0..511
    int xcd = d0 & 7, sx = d0 >> 3;      // sx 0..63
    int bh = xcd * 8 + (sx & 7);         // 0..63
    int qt = sx >> 3;                    // 0..7
    int b = bh >> 4, h = bh & 15;

    // Q B-fragments in registers: col q = l31, k(d) = dstep*16 + hi*8 + j
    f16x8 Qf[4];
    {
        const f16* qp = qh + ((size_t)bh * QL_ + qt * 128 + w * 32 + l31) * HD_ + hi * 8;
#pragma unroll
        for (int ds_ = 0; ds_ < 4; ++ds_) Qf[ds_] = *(const f16x8*)(qp + ds_ * 16);
    }

    // staging descriptors (2 K + 2 V instrs per wave), source pre-swizzled
    const char* kg[2]; const char* vg[2]; int ko[2], vo[2];
#pragma unroll
    for (int jj = 0; jj < 2; ++jj) {
        int instr = w + 4 * jj;                 // 0..7
        int r = instr * 8 + (l >> 3);            // LDS row 0..63
        int cc = (l & 7) ^ (r & 7);
        kg[jj] = (const char*)kh + ((size_t)bh * KVL_ + r) * 128 + cc * 16;
        ko[jj] = instr * 1024;
        vg[jj] = (const char*)vt + ((size_t)bh * HD_ + r) * (KVL_ * 2) + cc * 16;
        vo[jj] = instr * 1024;
    }

#define ASTAGE(buf, ch)                                          \
    {                                                            \
        g2lds16(kg[0] + (size_t)(ch) * 8192, &Klds[buf][ko[0]]); \
        g2lds16(kg[1] + (size_t)(ch) * 8192, &Klds[buf][ko[1]]); \
        g2lds16(vg[0] + (size_t)(ch) * 128, &Vlds[buf][vo[0]]);  \
        g2lds16(vg[1] + (size_t)(ch) * 128, &Vlds[buf][vo[1]]);  \
    }

    float mrun = -1e30f, ssum = 0.f;     // per-lane: q = l31 (lanes l, l^32 mirror)
    f32x16 acc[2] = {};                  // O: col d = c*32+l31, row q' = (r&3)+8*(r>>2)+4hi
    const float* mpb = mask + b * KVL_;

    ASTAGE(0, 0);
    asm volatile("s_waitcnt vmcnt(0)" ::: "memory");
    __syncthreads();

    for (int ch = 0; ch < KVL_ / 64; ++ch) {
        int cur = ch & 1;
        if (ch + 1 < KVL_ / 64) ASTAGE(cur ^ 1, ch + 1);

        // S^T tiles: St[kb] covers kv = ch*64 + kb*32 + [(r&3)+8*(r>>2)+4hi], col q = l31
        f32x16 St[2] = {};
#pragma unroll
        for (int kb = 0; kb < 2; ++kb) {
#pragma unroll
            for (int ds_ = 0; ds_ < 4; ++ds_) {
                f16x8 kf = *(const f16x8*)(&Klds[cur][(kb * 32 + l31) * 128 + ((ds_ * 32 + hi * 16) ^ swl)]);
                St[kb] = __builtin_amdgcn_mfma_f32_32x32x16_f16(kf, Qf[ds_], St[kb], 0, 0, 0);
            }
            // + mask*log2e : reg r -> kv' = (r&3) + 8*(r>>2) + 4hi
#pragma unroll
            for (int g4 = 0; g4 < 4; ++g4) {
                f32x4 mv = *(const f32x4*)(mpb + ch * 64 + kb * 32 + g4 * 8 + hi * 4);
#pragma unroll
                for (int j = 0; j < 4; ++j) St[kb][g4 * 4 + j] += mv[j] * L2E;
            }
        }

        // full row max for q = l31 (lane-local 32 + partner half)
        float pm = St[0][0];
#pragma unroll
        for (int r = 1; r < 16; ++r) pm = fmaxf(pm, St[0][r]);
#pragma unroll
        for (int r = 0; r < 16; ++r) pm = fmaxf(pm, St[1][r]);
        pm = fmaxf(pm, __shfl_xor(pm, 32));

        // deferred-max: rescale only when max grew by >12 (log2 units)
        if (__any(pm > mrun + 12.f)) {
            float mn = fmaxf(mrun, pm);
            float fac = exp2f(mrun - mn);
            mrun = mn;
            ssum *= fac;
            fr_lds[w][l31] = fac;
            asm volatile("s_waitcnt lgkmcnt(0)" ::: "memory");
#pragma unroll
            for (int g4 = 0; g4 < 4; ++g4) {
                f32x4 fv = *(const f32x4*)&fr_lds[w][g4 * 8 + hi * 4];
#pragma unroll
                for (int c = 0; c < 2; ++c)
#pragma unroll
                    for (int j = 0; j < 4; ++j) acc[c][g4 * 4 + j] *= fv[j];
            }
        }

        // P = exp2(S - mrun), per-lane partial sum
#pragma unroll
        for (int kb = 0; kb < 2; ++kb)
#pragma unroll
            for (int r = 0; r < 16; ++r) {
                float p = exp2f(St[kb][r] - mrun);
                St[kb][r] = p;
                ssum += p;
            }

        // pack P to f16 pairs (consecutive kv): pk[kb][i] = (kv 2i, 2i+1) of lane's set
        uint32_t pk[2][8];
#pragma unroll
        for (int kb = 0; kb < 2; ++kb)
#pragma unroll
            for (int i = 0; i < 8; ++i) pk[kb][i] = pkrtz(St[kb][2 * i], St[kb][2 * i + 1]);

        // PV: 4 k-steps of 16 kv; A = P (natural order), B = V gathered to match:
        // k-slot (hi*8+j) holds kv = st*16 + (j>>2)*8 + 4hi + (j&3)
#pragma unroll
        for (int st_ = 0; st_ < 4; ++st_) {
            U8 pa;
            pa.u[0] = pk[st_ >> 1][(st_ & 1) * 4 + 0];
            pa.u[1] = pk[st_ >> 1][(st_ & 1) * 4 + 1];
            pa.u[2] = pk[st_ >> 1][(st_ & 1) * 4 + 2];
            pa.u[3] = pk[st_ >> 1][(st_ & 1) * 4 + 3];
#pragma unroll
            for (int c = 0; c < 2; ++c) {
                const char* vrow = &Vlds[cur][(c * 32 + l31) * 128];
                U8 vb;
                *(uint2*)&vb.u[0] = *(const uint2*)(vrow + ((st_ * 32 + hi * 8) ^ swl));
                *(uint2*)&vb.u[2] = *(const uint2*)(vrow + ((st_ * 32 + 16 + hi * 8) ^ swl));
                acc[c] = __builtin_amdgcn_mfma_f32_32x32x16_f16(pa.v, vb.v, acc[c], 0, 0, 0);
            }
        }
        asm volatile("s_waitcnt vmcnt(0)" ::: "memory");
        __syncthreads();
    }

    // epilogue: total sum (partner half), broadcast 1/ssum, normalize, store
    ssum += __shfl_xor(ssum, 32);
    float rinv = 1.0f / ssum;
    fr_lds[w][l31] = rinv;
    asm volatile("s_waitcnt lgkmcnt(0)" ::: "memory");
#pragma unroll
    for (int g4 = 0; g4 < 4; ++g4) {
        f32x4 rv = *(const f32x4*)&fr_lds[w][g4 * 8 + hi * 4];
#pragma unroll
        for (int c = 0; c < 2; ++c)
#pragma unroll
            for (int j = 0; j < 4; ++j) {
                float o = acc[c][g4 * 4 + j] * rv[j];
                int q = qt * 128 + w * 32 + g4 * 8 + hi * 4 + j;
                int dd = c * 32 + l31;
                aout[((size_t)b * QL_ + q) * D_ + h * HD_ + dd] = (f16)o;
            }
    }
#undef ASTAGE
}

extern "C" void kernel_launch(void* const* d_in, const int* in_sizes, int n_in,
                              void* d_out, int out_size, void* d_ws, size_t ws_size,
                              hipStream_t stream) {
    const float* hs = (const float*)d_in[0];
    const float* K  = (const float*)d_in[1];
    const float* V  = (const float*)d_in[2];
    const float* mask = (const float*)d_in[3];
    const float* Wq = (const float*)d_in[4];
    const float* Wo = (const float*)d_in[5];
    float* out = (float*)d_out;
    char* ws = (char*)d_ws;

    f16* hs_h = (f16*)(ws + 0);           //  8 MB
    f16* Wq_t = (f16*)(ws + 8388608);     //  2 MB (Wq^T)
    f16* Wo_t = (f16*)(ws + 10485760);    //  2 MB (Wo^T)
    f16* K_h  = (f16*)(ws + 12582912);    // 16 MB
    f16* V_t  = (f16*)(ws + 29360128);    // 16 MB (b,h,d,kv)
    f16* q_h  = (f16*)(ws + 46137344);    //  8 MB (b,h,q,d), pre-scaled by log2e
    f16* a_o  = (f16*)(ws + 54525952);    //  8 MB (b,q,h*64+d)

    cvt_f32_f16<<<1024, 256, 0, stream>>>(hs, hs_h, (B_ * QL_ * D_) / 4);
    cvt_f32_f16<<<1024, 256, 0, stream>>>(K, K_h, (B_ * H_ * KVL_ * HD_) / 4);
    wt_transpose2<<<512, 256, 0, stream>>>(Wq, Wq_t, Wo, Wo_t);
    v_transpose<<<2048, 256, 0, stream>>>(V, V_t);

    gemm_tn<0><<<512, 512, 0, stream>>>(hs_h, Wq_t, (void*)q_h, 4096, 1024, 1024);
    attn_fused<<<512, 256, 0, stream>>>(q_h, K_h, V_t, mask, a_o);
    gemm_tn<1><<<512, 512, 0, stream>>>(a_o, Wo_t, (void*)out, 4096, 1024, 1024);
}

// Round 5
// 137.639 us; speedup vs baseline: 1.4147x; 1.0310x over previous
//
#include <hip/hip_runtime.h>
#include <hip/hip_bf16.h>
#include <hip/hip_fp16.h>
#include <stdint.h>

typedef _Float16 f16;
typedef _Float16 f16x4 __attribute__((ext_vector_type(4)));
typedef _Float16 f16x8 __attribute__((ext_vector_type(8)));
typedef float f32x4 __attribute__((ext_vector_type(4)));
typedef float f32x16 __attribute__((ext_vector_type(16)));

#define B_ 4
#define QL_ 1024
#define D_ 1024
#define H_ 16
#define HD_ 64
#define KVL_ 2048
#define L2E 1.44269504088896f

// ---- async global->LDS, 16B per lane, wave-uniform LDS base ----
__device__ __forceinline__ void g2lds16(const void* g, void* l) {
    __builtin_amdgcn_global_load_lds(
        (const __attribute__((address_space(1))) uint32_t*)g,
        (__attribute__((address_space(3))) uint32_t*)l,
        16, 0, 0);
}

union U8 { uint32_t u[4]; f16x8 v; };

__device__ __forceinline__ uint32_t pkrtz(float a, float b) {
    auto t = __builtin_amdgcn_cvt_pkrtz(a, b);
    return __builtin_bit_cast(uint32_t, t);
}

// ---- elementwise f32 -> f16 convert (vectorized) ----
__global__ void cvt_f32_f16(const float* __restrict__ s, f16* __restrict__ d, int n4) {
    int i = blockIdx.x * blockDim.x + threadIdx.x;
    int st = gridDim.x * blockDim.x;
    for (; i < n4; i += st) {
        float4 v = ((const float4*)s)[i];
        f16x4 o = { (f16)v.x, (f16)v.y, (f16)v.z, (f16)v.w };
        ((f16x4*)d)[i] = o;
    }
}

// ---- 1024x1024 f32 -> transposed f16, two matrices in one launch ----
__global__ void wt_transpose2(const float* __restrict__ s0, f16* __restrict__ d0p,
                              const float* __restrict__ s1, f16* __restrict__ d1p) {
    __shared__ float t[64][65];
    const float* src = blockIdx.x < 256 ? s0 : s1;
    f16* dst = blockIdx.x < 256 ? d0p : d1p;
    int bid = blockIdx.x & 255;
    int k0 = (bid >> 4) << 6;
    int n0 = (bid & 15) << 6;
    int tid = threadIdx.x;
    int rr = tid >> 4;          // 0..15
    int c4 = (tid & 15) << 2;   // 0..60
#pragma unroll
    for (int i = 0; i < 4; ++i) {
        int r = i * 16 + rr;
        float4 v = *(const float4*)(src + (size_t)(k0 + r) * 1024 + n0 + c4);
        t[r][c4 + 0] = v.x; t[r][c4 + 1] = v.y; t[r][c4 + 2] = v.z; t[r][c4 + 3] = v.w;
    }
    __syncthreads();
#pragma unroll
    for (int i = 0; i < 4; ++i) {
        int n = i * 16 + rr;
        f16x4 o;
#pragma unroll
        for (int j = 0; j < 4; ++j) o[j] = (f16)t[c4 + j][n];
        *(f16x4*)(dst + (size_t)(n0 + n) * 1024 + k0 + c4) = o;
    }
}

// ---- V (bh,2048,64) f32 -> V_t (bh,64,2048) f16, kv quad-permuted per 16 ----
// storage quad order {0,2,1,3}: PV B-fragment becomes a single contiguous b128
__global__ void v_transpose(const float* __restrict__ src, f16* __restrict__ dst) {
    __shared__ float t[64][65];
    int bh = blockIdx.x >> 5;           // 0..63
    int kv0 = (blockIdx.x & 31) << 6;
    int tid = threadIdx.x;
    int rr = tid >> 4;
    int c4 = (tid & 15) << 2;
    const int permq[4] = {0, 2, 1, 3};
    int pc4 = (c4 & ~15) + permq[(c4 >> 2) & 3] * 4;
#pragma unroll
    for (int i = 0; i < 4; ++i) {
        int r = i * 16 + rr;            // kv within tile
        float4 v = *(const float4*)(src + ((size_t)bh * KVL_ + kv0 + r) * HD_ + c4);
        t[r][c4 + 0] = v.x; t[r][c4 + 1] = v.y; t[r][c4 + 2] = v.z; t[r][c4 + 3] = v.w;
    }
    __syncthreads();
#pragma unroll
    for (int i = 0; i < 4; ++i) {
        int d = i * 16 + rr;
        f16x4 o;
#pragma unroll
        for (int j = 0; j < 4; ++j) o[j] = (f16)t[c4 + j][d];
        *(f16x4*)(dst + ((size_t)bh * HD_ + d) * KVL_ + kv0 + pc4) = o;
    }
}

// ---- GEMM: C[M][N] = A[M][K] * BT[N][K]^T, f16 in, fp32 acc, 2-phase dbuf ----
template <int EPI>
__global__ __launch_bounds__(512) void gemm_tn(
    const f16* __restrict__ A, const f16* __restrict__ BT, void* __restrict__ Cout,
    int M, int N, int K) {
    __shared__ char Alds[2][16384];  // 128 rows x 64 f16 (128B), XOR-swizzled
    __shared__ char Blds[2][8192];   // 64 rows x 64 f16
    int d0 = blockIdx.x;
    int xcd = d0 & 7, sx = d0 >> 3;            // sx 0..63
    int bm = xcd * 4 + (sx & 3);               // 0..31
    int bn = sx >> 2;                          // 0..15
    int tid = threadIdx.x, w = tid >> 6, l = tid & 63;
    int l15 = l & 15, lg = l >> 4;
    int wm = w >> 1, wn = w & 1;               // 4 x 2 wave grid
    f32x4 acc[2][2] = {};

    const char* ag[2]; int ao[2];
#pragma unroll
    for (int jj = 0; jj < 2; ++jj) {
        int instr = w + 8 * jj;                // 0..15
        int r = instr * 8 + (l >> 3);          // LDS row 0..127
        int cc = (l & 7) ^ (r & 7);            // inverse-swizzled source chunk
        ag[jj] = (const char*)A + ((size_t)(bm * 128 + r) * K + cc * 8) * 2;
        ao[jj] = instr * 1024;
    }
    int rB = w * 8 + (l >> 3);                 // 0..63
    int ccB = (l & 7) ^ (rB & 7);
    const char* bgp = (const char*)BT + ((size_t)(bn * 64 + rB) * K + ccB * 8) * 2;
    int boB = w * 1024;

#define GSTAGE(buf, kt)                                       \
    {                                                         \
        g2lds16(ag[0] + (size_t)(kt) * 128, &Alds[buf][ao[0]]); \
        g2lds16(ag[1] + (size_t)(kt) * 128, &Alds[buf][ao[1]]); \
        g2lds16(bgp + (size_t)(kt) * 128, &Blds[buf][boB]);     \
    }

    int nk = K >> 6;
    GSTAGE(0, 0);
    asm volatile("s_waitcnt vmcnt(0)" ::: "memory");
    __syncthreads();

    for (int kt = 0; kt < nk; ++kt) {
        int cur = kt & 1;
        if (kt + 1 < nk) GSTAGE(cur ^ 1, kt + 1);
#pragma unroll
        for (int ks = 0; ks < 2; ++ks) {
            f16x8 af[2], bf[2];
#pragma unroll
            for (int m = 0; m < 2; ++m) {
                int r = wm * 32 + m * 16 + l15;
                af[m] = *(const f16x8*)(&Alds[cur][r * 128 + ((ks * 64 + lg * 16) ^ ((r & 7) << 4))]);
            }
#pragma unroll
            for (int n = 0; n < 2; ++n) {
                int r = wn * 32 + n * 16 + l15;
                bf[n] = *(const f16x8*)(&Blds[cur][r * 128 + ((ks * 64 + lg * 16) ^ ((r & 7) << 4))]);
            }
#pragma unroll
            for (int m = 0; m < 2; ++m)
#pragma unroll
                for (int n = 0; n < 2; ++n)
                    acc[m][n] = __builtin_amdgcn_mfma_f32_16x16x32_f16(af[m], bf[n], acc[m][n], 0, 0, 0);
        }
        asm volatile("s_waitcnt vmcnt(0)" ::: "memory");
        __syncthreads();
    }

#pragma unroll
    for (int m = 0; m < 2; ++m)
#pragma unroll
        for (int n = 0; n < 2; ++n)
#pragma unroll
            for (int i = 0; i < 4; ++i) {
                int row = bm * 128 + wm * 32 + m * 16 + lg * 4 + i;
                int col = bn * 64 + wn * 32 + n * 16 + l15;
                if (EPI == 0) {
                    float v = acc[m][n][i] * L2E;
                    int b = row >> 10, q = row & 1023, h = col >> 6, d = col & 63;
                    ((f16*)Cout)[(((size_t)b * H_ + h) * QL_ + q) * HD_ + d] = (f16)v;
                } else {
                    ((float*)Cout)[(size_t)row * N + col] = acc[m][n][i];
                }
            }
#undef GSTAGE
}

// ---- fused flash attention, swapped 32x32x16 MFMA + in-block kv-split ----
// 512 thr (8 waves). Waves 0-3: kv 0..1023. Waves 4-7: kv 1024..2047.
// QBLK=128 (4 q-tiles of 32), merge partials once per block via LDS.
__global__ __launch_bounds__(512, 4) void attn_fused(
    const f16* __restrict__ qh, const f16* __restrict__ kh, const f16* __restrict__ vt,
    const float* __restrict__ mask, f16* __restrict__ aout) {
    __shared__ char lds_buf[65536];  // per group g: K dbuf [g*32768, +16K), V dbuf +16K
    __shared__ float frl[8][32];     // in-loop rescale broadcast
    __shared__ float fr2[4][2][32];  // merge gA/gB broadcast
    __shared__ float2 msx[4][32];    // merge (m, s) exchange

    int tid = threadIdx.x, w = tid >> 6, l = tid & 63;
    int l31 = l & 31, hi = l >> 5;
    int swl = (l31 & 7) << 4;
    int g = w >> 2, wg = w & 3;
    // bijective XCD swizzle: 8 bh per XCD
    int d0 = blockIdx.x;                 // 0..511
    int xcd = d0 & 7, sx = d0 >> 3;      // sx 0..63
    int bh = xcd * 8 + (sx & 7);         // 0..63
    int qt = sx >> 3;                    // 0..7
    int b = bh >> 4, h = bh & 15;

    char* Kst = lds_buf + g * 32768;
    char* Vst = lds_buf + g * 32768 + 16384;

    // Q B-fragments: col q = l31, k(d) = ds*16 + hi*8 + j
    f16x8 Qf[4];
    {
        const f16* qp = qh + ((size_t)bh * QL_ + qt * 128 + wg * 32 + l31) * HD_ + hi * 8;
#pragma unroll
        for (int ds_ = 0; ds_ < 4; ++ds_) Qf[ds_] = *(const f16x8*)(qp + ds_ * 16);
    }

    // staging descriptors (2 K + 2 V per wave), source pre-swizzled; group kv base
    const char* kg[2]; const char* vg[2]; int ko[2], vo[2];
#pragma unroll
    for (int jj = 0; jj < 2; ++jj) {
        int instr = wg + 4 * jj;                // 0..7
        int r = instr * 8 + (l >> 3);            // LDS row 0..63
        int cc = (l & 7) ^ (r & 7);
        kg[jj] = (const char*)kh + ((size_t)bh * KVL_ + g * 1024 + r) * 128 + cc * 16;
        ko[jj] = instr * 1024;
        vg[jj] = (const char*)vt + ((size_t)bh * HD_ + r) * (KVL_ * 2) + g * 2048 + cc * 16;
        vo[jj] = instr * 1024;
    }

#define ASTAGE(buf, ch)                                                  \
    {                                                                    \
        g2lds16(kg[0] + (size_t)(ch) * 8192, Kst + (buf) * 8192 + ko[0]); \
        g2lds16(kg[1] + (size_t)(ch) * 8192, Kst + (buf) * 8192 + ko[1]); \
        g2lds16(vg[0] + (size_t)(ch) * 128, Vst + (buf) * 8192 + vo[0]);  \
        g2lds16(vg[1] + (size_t)(ch) * 128, Vst + (buf) * 8192 + vo[1]);  \
    }

    float mrun = -1e30f, ssum = 0.f;     // per lane: q = l31; rows split by hi
    f32x16 acc[2] = {};                  // O: col d = c*32+l31, row q' = (r&3)+8*(r>>2)+4hi
    const float* mpb = mask + b * KVL_ + g * 1024;

    ASTAGE(0, 0);
    asm volatile("s_waitcnt vmcnt(0)" ::: "memory");
    __syncthreads();

    for (int ch = 0; ch < 16; ++ch) {
        int cur = ch & 1;
        if (ch + 1 < 16) ASTAGE(cur ^ 1, ch + 1);
        const char* Kc = Kst + cur * 8192;
        const char* Vc = Vst + cur * 8192;

        // S^T tiles: St[kb] kv = kb*32 + (r&3)+8*(r>>2)+4hi, col q = l31
        f32x16 St[2] = {};
        __builtin_amdgcn_s_setprio(1);
#pragma unroll
        for (int kb = 0; kb < 2; ++kb)
#pragma unroll
            for (int ds_ = 0; ds_ < 4; ++ds_) {
                f16x8 kf = *(const f16x8*)(Kc + (kb * 32 + l31) * 128 + ((ds_ * 32 + hi * 16) ^ swl));
                St[kb] = __builtin_amdgcn_mfma_f32_32x32x16_f16(kf, Qf[ds_], St[kb], 0, 0, 0);
            }
        __builtin_amdgcn_s_setprio(0);
        // + mask*log2e
#pragma unroll
        for (int kb = 0; kb < 2; ++kb)
#pragma unroll
            for (int g4 = 0; g4 < 4; ++g4) {
                f32x4 mv = *(const f32x4*)(mpb + ch * 64 + kb * 32 + g4 * 8 + hi * 4);
#pragma unroll
                for (int j = 0; j < 4; ++j) St[kb][g4 * 4 + j] += mv[j] * L2E;
            }

        // balanced-tree row max (this lane's 32) + partner half
        float t8[8];
#pragma unroll
        for (int r = 0; r < 8; ++r)
            t8[r] = fmaxf(fmaxf(St[0][r], St[0][r + 8]), fmaxf(St[1][r], St[1][r + 8]));
        float pm = fmaxf(fmaxf(fmaxf(t8[0], t8[1]), fmaxf(t8[2], t8[3])),
                         fmaxf(fmaxf(t8[4], t8[5]), fmaxf(t8[6], t8[7])));
        pm = fmaxf(pm, __shfl_xor(pm, 32));

        // deferred-max rescale
        if (__any(pm > mrun + 12.f)) {
            float mn = fmaxf(mrun, pm);
            float fac = exp2f(mrun - mn);
            mrun = mn;
            ssum *= fac;
            frl[w][l31] = fac;
            asm volatile("s_waitcnt lgkmcnt(0)" ::: "memory");
#pragma unroll
            for (int g4 = 0; g4 < 4; ++g4) {
                f32x4 fv = *(const f32x4*)&frl[w][g4 * 8 + hi * 4];
#pragma unroll
                for (int c = 0; c < 2; ++c)
#pragma unroll
                    for (int j = 0; j < 4; ++j) acc[c][g4 * 4 + j] *= fv[j];
            }
        }

        // P = exp2(S - mrun); per-lane partial sum
#pragma unroll
        for (int kb = 0; kb < 2; ++kb)
#pragma unroll
            for (int r = 0; r < 16; ++r) {
                float p = exp2f(St[kb][r] - mrun);
                St[kb][r] = p;
                ssum += p;
            }

        // PV: A = P packed at point of use; B = single b128 (kv quad-permuted V)
        __builtin_amdgcn_s_setprio(1);
#pragma unroll
        for (int st_ = 0; st_ < 4; ++st_) {
            U8 pa;
            int kb = st_ >> 1, half = (st_ & 1) * 8;
#pragma unroll
            for (int ii = 0; ii < 4; ++ii)
                pa.u[ii] = pkrtz(St[kb][half + 2 * ii], St[kb][half + 2 * ii + 1]);
#pragma unroll
            for (int c = 0; c < 2; ++c) {
                U8 vb;
                vb.v = *(const f16x8*)(Vc + (c * 32 + l31) * 128 + ((st_ * 32 + hi * 16) ^ swl));
                acc[c] = __builtin_amdgcn_mfma_f32_32x32x16_f16(pa.v, vb.v, acc[c], 0, 0, 0);
            }
        }
        __builtin_amdgcn_s_setprio(0);
        asm volatile("s_waitcnt vmcnt(0)" ::: "memory");
        __syncthreads();
    }

    // ---- merge the two kv halves ----
    ssum += __shfl_xor(ssum, 32);     // full row sum for this group
    char* exch = lds_buf;             // 32KB, aliases group-A staging (done with it)
    if (g == 1) {
        int base = (wg * 64 + l) * 128;
#pragma unroll
        for (int i = 0; i < 8; ++i) {
            int c = i >> 2, j0 = (i & 3) * 4;
            f32x4 vv = { acc[c][j0], acc[c][j0 + 1], acc[c][j0 + 2], acc[c][j0 + 3] };
            *(f32x4*)(exch + base + ((i * 16) ^ ((l & 7) << 4))) = vv;
        }
        if (hi == 0) msx[wg][l31] = make_float2(mrun, ssum);
    }
    __syncthreads();
    if (g == 0) {
        float2 mb = msx[wg][l31];
        float m = fmaxf(mrun, mb.x);
        float fA = exp2f(mrun - m), fB = exp2f(mb.x - m);
        float s = ssum * fA + mb.y * fB;
        float rinv = 1.0f / s;
        if (hi == 0) { fr2[wg][0][l31] = fA * rinv; fr2[wg][1][l31] = fB * rinv; }
        asm volatile("s_waitcnt lgkmcnt(0)" ::: "memory");
        int base = (wg * 64 + l) * 128;
#pragma unroll
        for (int c = 0; c < 2; ++c)
#pragma unroll
            for (int g4 = 0; g4 < 4; ++g4) {
                f32x4 gAv = *(const f32x4*)&fr2[wg][0][g4 * 8 + hi * 4];
                f32x4 gBv = *(const f32x4*)&fr2[wg][1][g4 * 8 + hi * 4];
                int i = c * 4 + g4;
                f32x4 pv = *(const f32x4*)(exch + base + ((i * 16) ^ ((l & 7) << 4)));
#pragma unroll
                for (int j = 0; j < 4; ++j) {
                    float o = acc[c][g4 * 4 + j] * gAv[j] + pv[j] * gBv[j];
                    int q = qt * 128 + wg * 32 + g4 * 8 + hi * 4 + j;
                    int dd = c * 32 + l31;
                    aout[((size_t)b * QL_ + q) * D_ + h * HD_ + dd] = (f16)o;
                }
            }
    }
#undef ASTAGE
}

extern "C" void kernel_launch(void* const* d_in, const int* in_sizes, int n_in,
                              void* d_out, int out_size, void* d_ws, size_t ws_size,
                              hipStream_t stream) {
    const float* hs = (const float*)d_in[0];
    const float* K  = (const float*)d_in[1];
    const float* V  = (const float*)d_in[2];
    const float* mask = (const float*)d_in[3];
    const float* Wq = (const float*)d_in[4];
    const float* Wo = (const float*)d_in[5];
    float* out = (float*)d_out;
    char* ws = (char*)d_ws;

    f16* hs_h = (f16*)(ws + 0);           //  8 MB
    f16* Wq_t = (f16*)(ws + 8388608);     //  2 MB (Wq^T)
    f16* Wo_t = (f16*)(ws + 10485760);    //  2 MB (Wo^T)
    f16* K_h  = (f16*)(ws + 12582912);    // 16 MB
    f16* V_t  = (f16*)(ws + 29360128);    // 16 MB (b,h,d,kv) kv quad-permuted
    f16* q_h  = (f16*)(ws + 46137344);    //  8 MB (b,h,q,d), pre-scaled by log2e
    f16* a_o  = (f16*)(ws + 54525952);    //  8 MB (b,q,h*64+d)

    cvt_f32_f16<<<1024, 256, 0, stream>>>(hs, hs_h, (B_ * QL_ * D_) / 4);
    cvt_f32_f16<<<1024, 256, 0, stream>>>(K, K_h, (B_ * H_ * KVL_ * HD_) / 4);
    wt_transpose2<<<512, 256, 0, stream>>>(Wq, Wq_t, Wo, Wo_t);
    v_transpose<<<2048, 256, 0, stream>>>(V, V_t);

    gemm_tn<0><<<512, 512, 0, stream>>>(hs_h, Wq_t, (void*)q_h, 4096, 1024, 1024);
    attn_fused<<<512, 512, 0, stream>>>(q_h, K_h, V_t, mask, a_o);
    gemm_tn<1><<<512, 512, 0, stream>>>(a_o, Wo_t, (void*)out, 4096, 1024, 1024);
}

// Round 6
// 123.117 us; speedup vs baseline: 1.5815x; 1.1180x over previous
//
#include <hip/hip_runtime.h>
#include <hip/hip_bf16.h>
#include <hip/hip_fp16.h>
#include <stdint.h>

typedef _Float16 f16;
typedef _Float16 f16x4 __attribute__((ext_vector_type(4)));
typedef _Float16 f16x8 __attribute__((ext_vector_type(8)));
typedef float f32x4 __attribute__((ext_vector_type(4)));
typedef float f32x16 __attribute__((ext_vector_type(16)));

#define B_ 4
#define QL_ 1024
#define D_ 1024
#define H_ 16
#define HD_ 64
#define KVL_ 2048
#define L2E 1.44269504088896f

// ---- async global->LDS, 16B per lane, wave-uniform LDS base ----
__device__ __forceinline__ void g2lds16(const void* g, void* l) {
    __builtin_amdgcn_global_load_lds(
        (const __attribute__((address_space(1))) uint32_t*)g,
        (__attribute__((address_space(3))) uint32_t*)l,
        16, 0, 0);
}

union U8 { uint32_t u[4]; f16x8 v; };

__device__ __forceinline__ uint32_t pkrtz(float a, float b) {
    auto t = __builtin_amdgcn_cvt_pkrtz(a, b);
    return __builtin_bit_cast(uint32_t, t);
}

// ---- elementwise f32 -> f16 convert, two tensors in one launch ----
__global__ void cvt_both(const float* __restrict__ a, f16* __restrict__ da, int n4a,
                         const float* __restrict__ b, f16* __restrict__ db, int n4b) {
    int i = blockIdx.x * blockDim.x + threadIdx.x;
    int st = gridDim.x * blockDim.x;
    int tot = n4a + n4b;
    for (; i < tot; i += st) {
        float4 v = (i < n4a) ? ((const float4*)a)[i] : ((const float4*)b)[i - n4a];
        f16x4 o = { (f16)v.x, (f16)v.y, (f16)v.z, (f16)v.w };
        if (i < n4a) ((f16x4*)da)[i] = o; else ((f16x4*)db)[i - n4a] = o;
    }
}

// ---- 1024x1024 f32 -> transposed f16, two matrices in one launch ----
__global__ void wt_transpose2(const float* __restrict__ s0, f16* __restrict__ d0p,
                              const float* __restrict__ s1, f16* __restrict__ d1p) {
    __shared__ float t[64][65];
    const float* src = blockIdx.x < 256 ? s0 : s1;
    f16* dst = blockIdx.x < 256 ? d0p : d1p;
    int bid = blockIdx.x & 255;
    int k0 = (bid >> 4) << 6;
    int n0 = (bid & 15) << 6;
    int tid = threadIdx.x;
    int rr = tid >> 4;          // 0..15
    int c4 = (tid & 15) << 2;   // 0..60
#pragma unroll
    for (int i = 0; i < 4; ++i) {
        int r = i * 16 + rr;
        float4 v = *(const float4*)(src + (size_t)(k0 + r) * 1024 + n0 + c4);
        t[r][c4 + 0] = v.x; t[r][c4 + 1] = v.y; t[r][c4 + 2] = v.z; t[r][c4 + 3] = v.w;
    }
    __syncthreads();
#pragma unroll
    for (int i = 0; i < 4; ++i) {
        int n = i * 16 + rr;
        f16x4 o;
#pragma unroll
        for (int j = 0; j < 4; ++j) o[j] = (f16)t[c4 + j][n];
        *(f16x4*)(dst + (size_t)(n0 + n) * 1024 + k0 + c4) = o;
    }
}

// ---- V (bh,2048,64) f32 -> V_t (bh,64,2048) f16, kv quad-permuted per 16 ----
// storage quad order {0,2,1,3}: PV B-fragment becomes a single contiguous b128
__global__ void v_transpose(const float* __restrict__ src, f16* __restrict__ dst) {
    __shared__ float t[64][65];
    int bh = blockIdx.x >> 5;           // 0..63
    int kv0 = (blockIdx.x & 31) << 6;
    int tid = threadIdx.x;
    int rr = tid >> 4;
    int c4 = (tid & 15) << 2;
    const int permq[4] = {0, 2, 1, 3};
    int pc4 = (c4 & ~15) + permq[(c4 >> 2) & 3] * 4;
#pragma unroll
    for (int i = 0; i < 4; ++i) {
        int r = i * 16 + rr;            // kv within tile
        float4 v = *(const float4*)(src + ((size_t)bh * KVL_ + kv0 + r) * HD_ + c4);
        t[r][c4 + 0] = v.x; t[r][c4 + 1] = v.y; t[r][c4 + 2] = v.z; t[r][c4 + 3] = v.w;
    }
    __syncthreads();
#pragma unroll
    for (int i = 0; i < 4; ++i) {
        int d = i * 16 + rr;
        f16x4 o;
#pragma unroll
        for (int j = 0; j < 4; ++j) o[j] = (f16)t[c4 + j][d];
        *(f16x4*)(dst + ((size_t)bh * HD_ + d) * KVL_ + kv0 + pc4) = o;
    }
}

// ---- GEMM: C[M][N] = A[M][K] * BT[N][K]^T, f16 in, fp32 acc, 2-phase dbuf ----
template <int EPI>
__global__ __launch_bounds__(512) void gemm_tn(
    const f16* __restrict__ A, const f16* __restrict__ BT, void* __restrict__ Cout,
    int M, int N, int K) {
    __shared__ char Alds[2][16384];  // 128 rows x 64 f16 (128B), XOR-swizzled
    __shared__ char Blds[2][8192];   // 64 rows x 64 f16
    int d0 = blockIdx.x;
    int xcd = d0 & 7, sx = d0 >> 3;            // sx 0..63
    int bm = xcd * 4 + (sx & 3);               // 0..31
    int bn = sx >> 2;                          // 0..15
    int tid = threadIdx.x, w = tid >> 6, l = tid & 63;
    int l15 = l & 15, lg = l >> 4;
    int wm = w >> 1, wn = w & 1;               // 4 x 2 wave grid
    f32x4 acc[2][2] = {};

    const char* ag[2]; int ao[2];
#pragma unroll
    for (int jj = 0; jj < 2; ++jj) {
        int instr = w + 8 * jj;                // 0..15
        int r = instr * 8 + (l >> 3);          // LDS row 0..127
        int cc = (l & 7) ^ (r & 7);            // inverse-swizzled source chunk
        ag[jj] = (const char*)A + ((size_t)(bm * 128 + r) * K + cc * 8) * 2;
        ao[jj] = instr * 1024;
    }
    int rB = w * 8 + (l >> 3);                 // 0..63
    int ccB = (l & 7) ^ (rB & 7);
    const char* bgp = (const char*)BT + ((size_t)(bn * 64 + rB) * K + ccB * 8) * 2;
    int boB = w * 1024;

#define GSTAGE(buf, kt)                                       \
    {                                                         \
        g2lds16(ag[0] + (size_t)(kt) * 128, &Alds[buf][ao[0]]); \
        g2lds16(ag[1] + (size_t)(kt) * 128, &Alds[buf][ao[1]]); \
        g2lds16(bgp + (size_t)(kt) * 128, &Blds[buf][boB]);     \
    }

    int nk = K >> 6;
    GSTAGE(0, 0);
    asm volatile("s_waitcnt vmcnt(0)" ::: "memory");
    __syncthreads();

    for (int kt = 0; kt < nk; ++kt) {
        int cur = kt & 1;
        if (kt + 1 < nk) GSTAGE(cur ^ 1, kt + 1);
#pragma unroll
        for (int ks = 0; ks < 2; ++ks) {
            f16x8 af[2], bf[2];
#pragma unroll
            for (int m = 0; m < 2; ++m) {
                int r = wm * 32 + m * 16 + l15;
                af[m] = *(const f16x8*)(&Alds[cur][r * 128 + ((ks * 64 + lg * 16) ^ ((r & 7) << 4))]);
            }
#pragma unroll
            for (int n = 0; n < 2; ++n) {
                int r = wn * 32 + n * 16 + l15;
                bf[n] = *(const f16x8*)(&Blds[cur][r * 128 + ((ks * 64 + lg * 16) ^ ((r & 7) << 4))]);
            }
#pragma unroll
            for (int m = 0; m < 2; ++m)
#pragma unroll
                for (int n = 0; n < 2; ++n)
                    acc[m][n] = __builtin_amdgcn_mfma_f32_16x16x32_f16(af[m], bf[n], acc[m][n], 0, 0, 0);
        }
        asm volatile("s_waitcnt vmcnt(0)" ::: "memory");
        __syncthreads();
    }

#pragma unroll
    for (int m = 0; m < 2; ++m)
#pragma unroll
        for (int n = 0; n < 2; ++n)
#pragma unroll
            for (int i = 0; i < 4; ++i) {
                int row = bm * 128 + wm * 32 + m * 16 + lg * 4 + i;
                int col = bn * 64 + wn * 32 + n * 16 + l15;
                if (EPI == 0) {
                    float v = acc[m][n][i] * L2E;
                    int b = row >> 10, q = row & 1023, h = col >> 6, d = col & 63;
                    ((f16*)Cout)[(((size_t)b * H_ + h) * QL_ + q) * HD_ + d] = (f16)v;
                } else {
                    ((float*)Cout)[(size_t)row * N + col] = acc[m][n][i];
                }
            }
#undef GSTAGE
}

// ---- fused flash attention, swapped 32x32x16 MFMA + in-block kv-split ----
// 512 thr (8 waves). Waves 0-3: kv 0..1023. Waves 4-7: kv 1024..2047.
// Staged chunks of 64 kv are consumed as TWO independent 32-kv online-softmax
// granules so only one f32x16 St is live (peak regs ~100 < 128 cap -> no spill).
__global__ __launch_bounds__(512, 4) void attn_fused(
    const f16* __restrict__ qh, const f16* __restrict__ kh, const f16* __restrict__ vt,
    const float* __restrict__ mask, f16* __restrict__ aout) {
    __shared__ char lds_buf[65536];  // per group g: K dbuf [g*32768, +16K), V dbuf +16K
    __shared__ float frl[8][32];     // in-loop rescale broadcast
    __shared__ float fr2[4][2][32];  // merge gA/gB broadcast
    __shared__ float2 msx[4][32];    // merge (m, s) exchange

    int tid = threadIdx.x, w = tid >> 6, l = tid & 63;
    int l31 = l & 31, hi = l >> 5;
    int swl = (l31 & 7) << 4;
    int g = w >> 2, wg = w & 3;
    // bijective XCD swizzle: 8 bh per XCD
    int d0 = blockIdx.x;                 // 0..511
    int xcd = d0 & 7, sx = d0 >> 3;      // sx 0..63
    int bh = xcd * 8 + (sx & 7);         // 0..63
    int qt = sx >> 3;                    // 0..7
    int b = bh >> 4, h = bh & 15;

    char* Kst = lds_buf + g * 32768;
    char* Vst = lds_buf + g * 32768 + 16384;

    // Q B-fragments: col q = l31, k(d) = ds*16 + hi*8 + j
    f16x8 Qf[4];
    {
        const f16* qp = qh + ((size_t)bh * QL_ + qt * 128 + wg * 32 + l31) * HD_ + hi * 8;
#pragma unroll
        for (int ds_ = 0; ds_ < 4; ++ds_) Qf[ds_] = *(const f16x8*)(qp + ds_ * 16);
    }

    // staging: one base pointer each; second instr = uniform byte delta
    const char* kg0; const char* vg0; int ko0, vo0;
    {
        int instr = wg;                          // 0..3
        int r = instr * 8 + (l >> 3);            // LDS row 0..31
        int cc = (l & 7) ^ (r & 7);
        kg0 = (const char*)kh + ((size_t)bh * KVL_ + g * 1024 + r) * 128 + cc * 16;
        ko0 = instr * 1024;
        vg0 = (const char*)vt + ((size_t)bh * HD_ + r) * (KVL_ * 2) + g * 2048 + cc * 16;
        vo0 = instr * 1024;
    }

#define ASTAGE(buf, ch)                                                              \
    {                                                                                \
        g2lds16(kg0 + (size_t)(ch) * 8192, Kst + (buf) * 8192 + ko0);                \
        g2lds16(kg0 + (size_t)(ch) * 8192 + 4096, Kst + (buf) * 8192 + ko0 + 4096);  \
        g2lds16(vg0 + (size_t)(ch) * 128, Vst + (buf) * 8192 + vo0);                 \
        g2lds16(vg0 + (size_t)(ch) * 128 + 131072, Vst + (buf) * 8192 + vo0 + 4096); \
    }

    float mrun = -1e30f, ssum = 0.f;     // per lane: q = l31
    f32x16 acc[2] = {};                  // O: col d = c*32+l31, row q' = (r&3)+8*(r>>2)+4hi
    const float* mpb = mask + b * KVL_ + g * 1024;

    ASTAGE(0, 0);
    asm volatile("s_waitcnt vmcnt(0)" ::: "memory");
    __syncthreads();

    for (int ch = 0; ch < 16; ++ch) {
        int cur = ch & 1;
        if (ch + 1 < 16) ASTAGE(cur ^ 1, ch + 1);
        const char* Kc = Kst + cur * 8192;
        const char* Vc = Vst + cur * 8192;

#pragma unroll
        for (int kb = 0; kb < 2; ++kb) {
            // S^T granule: kv = ch*64 + kb*32 + (r&3)+8*(r>>2)+4hi, col q = l31
            f32x16 St = {};
            __builtin_amdgcn_s_setprio(1);
#pragma unroll
            for (int ds_ = 0; ds_ < 4; ++ds_) {
                f16x8 kf = *(const f16x8*)(Kc + (kb * 32 + l31) * 128 + ((ds_ * 32 + hi * 16) ^ swl));
                St = __builtin_amdgcn_mfma_f32_32x32x16_f16(kf, Qf[ds_], St, 0, 0, 0);
            }
            __builtin_amdgcn_s_setprio(0);
            // + mask*log2e
#pragma unroll
            for (int g4 = 0; g4 < 4; ++g4) {
                f32x4 mv = *(const f32x4*)(mpb + ch * 64 + kb * 32 + g4 * 8 + hi * 4);
#pragma unroll
                for (int j = 0; j < 4; ++j) St[g4 * 4 + j] += mv[j] * L2E;
            }

            // row max over this granule (16 local + partner half)
            float q0 = fmaxf(fmaxf(St[0], St[1]), fmaxf(St[2], St[3]));
            float q1 = fmaxf(fmaxf(St[4], St[5]), fmaxf(St[6], St[7]));
            float q2 = fmaxf(fmaxf(St[8], St[9]), fmaxf(St[10], St[11]));
            float q3 = fmaxf(fmaxf(St[12], St[13]), fmaxf(St[14], St[15]));
            float pm = fmaxf(fmaxf(q0, q1), fmaxf(q2, q3));
            pm = fmaxf(pm, __shfl_xor(pm, 32));

            // deferred-max rescale (rare)
            if (__any(pm > mrun + 12.f)) {
                float mn = fmaxf(mrun, pm);
                float fac = exp2f(mrun - mn);
                mrun = mn;
                ssum *= fac;
                frl[w][l31] = fac;
                asm volatile("s_waitcnt lgkmcnt(0)" ::: "memory");
#pragma unroll
                for (int g4 = 0; g4 < 4; ++g4) {
                    f32x4 fv = *(const f32x4*)&frl[w][g4 * 8 + hi * 4];
#pragma unroll
                    for (int c = 0; c < 2; ++c)
#pragma unroll
                        for (int j = 0; j < 4; ++j) acc[c][g4 * 4 + j] *= fv[j];
                }
            }

            // P = exp2(S - mrun); per-lane partial sum
#pragma unroll
            for (int r = 0; r < 16; ++r) {
                float p = exp2f(St[r] - mrun);
                St[r] = p;
                ssum += p;
            }

            // PV: A = P packed at point of use; B = single b128 (kv quad-permuted V)
            __builtin_amdgcn_s_setprio(1);
#pragma unroll
            for (int sti = 0; sti < 2; ++sti) {
                U8 pa;
                int half = sti * 8;
#pragma unroll
                for (int ii = 0; ii < 4; ++ii)
                    pa.u[ii] = pkrtz(St[half + 2 * ii], St[half + 2 * ii + 1]);
                int st_ = kb * 2 + sti;
#pragma unroll
                for (int c = 0; c < 2; ++c) {
                    U8 vb;
                    vb.v = *(const f16x8*)(Vc + (c * 32 + l31) * 128 + ((st_ * 32 + hi * 16) ^ swl));
                    acc[c] = __builtin_amdgcn_mfma_f32_32x32x16_f16(pa.v, vb.v, acc[c], 0, 0, 0);
                }
            }
            __builtin_amdgcn_s_setprio(0);
        }
        asm volatile("s_waitcnt vmcnt(0)" ::: "memory");
        __syncthreads();
    }

    // ---- merge the two kv halves ----
    ssum += __shfl_xor(ssum, 32);     // full row sum for this group
    char* exch = lds_buf;             // 32KB, aliases group-0 staging (done with it)
    if (g == 1) {
        int base = (wg * 64 + l) * 128;
#pragma unroll
        for (int i = 0; i < 8; ++i) {
            int c = i >> 2, j0 = (i & 3) * 4;
            f32x4 vv = { acc[c][j0], acc[c][j0 + 1], acc[c][j0 + 2], acc[c][j0 + 3] };
            *(f32x4*)(exch + base + ((i * 16) ^ ((l & 7) << 4))) = vv;
        }
        if (hi == 0) msx[wg][l31] = make_float2(mrun, ssum);
    }
    __syncthreads();
    if (g == 0) {
        float2 mb = msx[wg][l31];
        float m = fmaxf(mrun, mb.x);
        float fA = exp2f(mrun - m), fB = exp2f(mb.x - m);
        float s = ssum * fA + mb.y * fB;
        float rinv = 1.0f / s;
        if (hi == 0) { fr2[wg][0][l31] = fA * rinv; fr2[wg][1][l31] = fB * rinv; }
        asm volatile("s_waitcnt lgkmcnt(0)" ::: "memory");
        int base = (wg * 64 + l) * 128;
#pragma unroll
        for (int c = 0; c < 2; ++c)
#pragma unroll
            for (int g4 = 0; g4 < 4; ++g4) {
                f32x4 gAv = *(const f32x4*)&fr2[wg][0][g4 * 8 + hi * 4];
                f32x4 gBv = *(const f32x4*)&fr2[wg][1][g4 * 8 + hi * 4];
                int i = c * 4 + g4;
                f32x4 pv = *(const f32x4*)(exch + base + ((i * 16) ^ ((l & 7) << 4)));
#pragma unroll
                for (int j = 0; j < 4; ++j) {
                    float o = acc[c][g4 * 4 + j] * gAv[j] + pv[j] * gBv[j];
                    int q = qt * 128 + wg * 32 + g4 * 8 + hi * 4 + j;
                    int dd = c * 32 + l31;
                    aout[((size_t)b * QL_ + q) * D_ + h * HD_ + dd] = (f16)o;
                }
            }
    }
#undef ASTAGE
}

extern "C" void kernel_launch(void* const* d_in, const int* in_sizes, int n_in,
                              void* d_out, int out_size, void* d_ws, size_t ws_size,
                              hipStream_t stream) {
    const float* hs = (const float*)d_in[0];
    const float* K  = (const float*)d_in[1];
    const float* V  = (const float*)d_in[2];
    const float* mask = (const float*)d_in[3];
    const float* Wq = (const float*)d_in[4];
    const float* Wo = (const float*)d_in[5];
    float* out = (float*)d_out;
    char* ws = (char*)d_ws;

    f16* hs_h = (f16*)(ws + 0);           //  8 MB
    f16* Wq_t = (f16*)(ws + 8388608);     //  2 MB (Wq^T)
    f16* Wo_t = (f16*)(ws + 10485760);    //  2 MB (Wo^T)
    f16* K_h  = (f16*)(ws + 12582912);    // 16 MB
    f16* V_t  = (f16*)(ws + 29360128);    // 16 MB (b,h,d,kv) kv quad-permuted
    f16* q_h  = (f16*)(ws + 46137344);    //  8 MB (b,h,q,d), pre-scaled by log2e
    f16* a_o  = (f16*)(ws + 54525952);    //  8 MB (b,q,h*64+d)

    cvt_both<<<2048, 256, 0, stream>>>(hs, hs_h, (B_ * QL_ * D_) / 4,
                                       K, K_h, (B_ * H_ * KVL_ * HD_) / 4);
    wt_transpose2<<<512, 256, 0, stream>>>(Wq, Wq_t, Wo, Wo_t);
    v_transpose<<<2048, 256, 0, stream>>>(V, V_t);

    gemm_tn<0><<<512, 512, 0, stream>>>(hs_h, Wq_t, (void*)q_h, 4096, 1024, 1024);
    attn_fused<<<512, 512, 0, stream>>>(q_h, K_h, V_t, mask, a_o);
    gemm_tn<1><<<512, 512, 0, stream>>>(a_o, Wo_t, (void*)out, 4096, 1024, 1024);
}

// Round 7
// 117.589 us; speedup vs baseline: 1.6559x; 1.0470x over previous
//
#include <hip/hip_runtime.h>
#include <hip/hip_bf16.h>
#include <hip/hip_fp16.h>
#include <stdint.h>

typedef _Float16 f16;
typedef _Float16 f16x2 __attribute__((ext_vector_type(2)));
typedef _Float16 f16x4 __attribute__((ext_vector_type(4)));
typedef _Float16 f16x8 __attribute__((ext_vector_type(8)));
typedef float f32x4 __attribute__((ext_vector_type(4)));
typedef float f32x16 __attribute__((ext_vector_type(16)));

#define B_ 4
#define QL_ 1024
#define D_ 1024
#define H_ 16
#define HD_ 64
#define KVL_ 2048
#define L2E 1.44269504088896f

// ---- async global->LDS, 16B per lane, wave-uniform LDS base ----
__device__ __forceinline__ void g2lds16(const void* g, void* l) {
    __builtin_amdgcn_global_load_lds(
        (const __attribute__((address_space(1))) uint32_t*)g,
        (__attribute__((address_space(3))) uint32_t*)l,
        16, 0, 0);
}

union U8 { uint32_t u[4]; f16x8 v; };

__device__ __forceinline__ uint32_t pkrtz(float a, float b) {
    auto t = __builtin_amdgcn_cvt_pkrtz(a, b);
    return __builtin_bit_cast(uint32_t, t);
}

// ---- merged preprocessing: converts + weight transposes + V transpose + mask ----
// blocks [0,2048): f32->f16 convert of hs and K (grid-stride)
// blocks [2048,2560): Wq/Wo transpose (64x64 tiles)
// blocks [2560,4608): V transpose (kv quad-permuted {0,2,1,3} per 16)
// blocks [4608,4616): mask * log2e
__global__ void preprocess(const float* __restrict__ hs, f16* __restrict__ hs_h,
                           const float* __restrict__ K, f16* __restrict__ K_h,
                           const float* __restrict__ Wq, f16* __restrict__ Wq_t,
                           const float* __restrict__ Wo, f16* __restrict__ Wo_t,
                           const float* __restrict__ V, f16* __restrict__ V_t,
                           const float* __restrict__ mask, float* __restrict__ mL) {
    __shared__ float t[64][65];
    int bid = blockIdx.x, tid = threadIdx.x;
    if (bid < 2048) {
        const int n4a = (B_ * QL_ * D_) / 4;           // 1048576
        const int n4b = (B_ * H_ * KVL_ * HD_) / 4;    // 2097152
        int i = bid * 256 + tid;
        int st = 2048 * 256;
        for (; i < n4a + n4b; i += st) {
            float4 v = (i < n4a) ? ((const float4*)hs)[i] : ((const float4*)K)[i - n4a];
            f16x4 o = { (f16)v.x, (f16)v.y, (f16)v.z, (f16)v.w };
            if (i < n4a) ((f16x4*)hs_h)[i] = o; else ((f16x4*)K_h)[i - n4a] = o;
        }
    } else if (bid < 2560) {
        int wbid = bid - 2048;
        const float* src = wbid < 256 ? Wq : Wo;
        f16* dst = wbid < 256 ? Wq_t : Wo_t;
        int b2 = wbid & 255;
        int k0 = (b2 >> 4) << 6, n0 = (b2 & 15) << 6;
        int rr = tid >> 4, c4 = (tid & 15) << 2;
#pragma unroll
        for (int i = 0; i < 4; ++i) {
            int r = i * 16 + rr;
            float4 v = *(const float4*)(src + (size_t)(k0 + r) * 1024 + n0 + c4);
            t[r][c4 + 0] = v.x; t[r][c4 + 1] = v.y; t[r][c4 + 2] = v.z; t[r][c4 + 3] = v.w;
        }
        __syncthreads();
#pragma unroll
        for (int i = 0; i < 4; ++i) {
            int n = i * 16 + rr;
            f16x4 o;
#pragma unroll
            for (int j = 0; j < 4; ++j) o[j] = (f16)t[c4 + j][n];
            *(f16x4*)(dst + (size_t)(n0 + n) * 1024 + k0 + c4) = o;
        }
    } else if (bid < 4608) {
        int vbid = bid - 2560;
        int bh = vbid >> 5, kv0 = (vbid & 31) << 6;
        int rr = tid >> 4, c4 = (tid & 15) << 2;
        const int permq[4] = {0, 2, 1, 3};
        int pc4 = (c4 & ~15) + permq[(c4 >> 2) & 3] * 4;
#pragma unroll
        for (int i = 0; i < 4; ++i) {
            int r = i * 16 + rr;
            float4 v = *(const float4*)(V + ((size_t)bh * KVL_ + kv0 + r) * HD_ + c4);
            t[r][c4 + 0] = v.x; t[r][c4 + 1] = v.y; t[r][c4 + 2] = v.z; t[r][c4 + 3] = v.w;
        }
        __syncthreads();
#pragma unroll
        for (int i = 0; i < 4; ++i) {
            int d = i * 16 + rr;
            f16x4 o;
#pragma unroll
            for (int j = 0; j < 4; ++j) o[j] = (f16)t[c4 + j][d];
            *(f16x4*)(V_t + ((size_t)bh * HD_ + d) * KVL_ + kv0 + pc4) = o;
        }
    } else {
        int i = (bid - 4608) * 256 + tid;       // f32x4 index over B*KVL floats
        if (i < (B_ * KVL_) / 4) {
            f32x4 v = ((const f32x4*)mask)[i];
            v *= L2E;
            ((f32x4*)mL)[i] = v;
        }
    }
}

// ---- GEMM: C[M][N] = A[M][K] * BT[N][K]^T, f16 in, fp32 acc, 2-phase dbuf ----
template <int EPI>
__global__ __launch_bounds__(512) void gemm_tn(
    const f16* __restrict__ A, const f16* __restrict__ BT, void* __restrict__ Cout,
    int M, int N, int K) {
    __shared__ char Alds[2][16384];  // 128 rows x 64 f16 (128B), XOR-swizzled
    __shared__ char Blds[2][8192];   // 64 rows x 64 f16
    int d0 = blockIdx.x;
    int xcd = d0 & 7, sx = d0 >> 3;            // sx 0..63
    int bm = xcd * 4 + (sx & 3);               // 0..31
    int bn = sx >> 2;                          // 0..15
    int tid = threadIdx.x, w = tid >> 6, l = tid & 63;
    int l15 = l & 15, lg = l >> 4;
    int wm = w >> 1, wn = w & 1;               // 4 x 2 wave grid
    f32x4 acc[2][2] = {};

    const char* ag[2]; int ao[2];
#pragma unroll
    for (int jj = 0; jj < 2; ++jj) {
        int instr = w + 8 * jj;                // 0..15
        int r = instr * 8 + (l >> 3);          // LDS row 0..127
        int cc = (l & 7) ^ (r & 7);            // inverse-swizzled source chunk
        ag[jj] = (const char*)A + ((size_t)(bm * 128 + r) * K + cc * 8) * 2;
        ao[jj] = instr * 1024;
    }
    int rB = w * 8 + (l >> 3);                 // 0..63
    int ccB = (l & 7) ^ (rB & 7);
    const char* bgp = (const char*)BT + ((size_t)(bn * 64 + rB) * K + ccB * 8) * 2;
    int boB = w * 1024;

#define GSTAGE(buf, kt)                                       \
    {                                                         \
        g2lds16(ag[0] + (size_t)(kt) * 128, &Alds[buf][ao[0]]); \
        g2lds16(ag[1] + (size_t)(kt) * 128, &Alds[buf][ao[1]]); \
        g2lds16(bgp + (size_t)(kt) * 128, &Blds[buf][boB]);     \
    }

    int nk = K >> 6;
    GSTAGE(0, 0);
    asm volatile("s_waitcnt vmcnt(0)" ::: "memory");
    __syncthreads();

    for (int kt = 0; kt < nk; ++kt) {
        int cur = kt & 1;
        if (kt + 1 < nk) GSTAGE(cur ^ 1, kt + 1);
#pragma unroll
        for (int ks = 0; ks < 2; ++ks) {
            f16x8 af[2], bf[2];
#pragma unroll
            for (int m = 0; m < 2; ++m) {
                int r = wm * 32 + m * 16 + l15;
                af[m] = *(const f16x8*)(&Alds[cur][r * 128 + ((ks * 64 + lg * 16) ^ ((r & 7) << 4))]);
            }
#pragma unroll
            for (int n = 0; n < 2; ++n) {
                int r = wn * 32 + n * 16 + l15;
                bf[n] = *(const f16x8*)(&Blds[cur][r * 128 + ((ks * 64 + lg * 16) ^ ((r & 7) << 4))]);
            }
#pragma unroll
            for (int m = 0; m < 2; ++m)
#pragma unroll
                for (int n = 0; n < 2; ++n)
                    acc[m][n] = __builtin_amdgcn_mfma_f32_16x16x32_f16(af[m], bf[n], acc[m][n], 0, 0, 0);
        }
        asm volatile("s_waitcnt vmcnt(0)" ::: "memory");
        __syncthreads();
    }

#pragma unroll
    for (int m = 0; m < 2; ++m)
#pragma unroll
        for (int n = 0; n < 2; ++n)
#pragma unroll
            for (int i = 0; i < 4; ++i) {
                int row = bm * 128 + wm * 32 + m * 16 + lg * 4 + i;
                int col = bn * 64 + wn * 32 + n * 16 + l15;
                if (EPI == 0) {
                    float v = acc[m][n][i] * L2E;
                    int b = row >> 10, q = row & 1023, h = col >> 6, d = col & 63;
                    ((f16*)Cout)[(((size_t)b * H_ + h) * QL_ + q) * HD_ + d] = (f16)v;
                } else {
                    ((float*)Cout)[(size_t)row * N + col] = acc[m][n][i];
                }
            }
#undef GSTAGE
}

// ---- fused flash attention, swapped 32x32x16 MFMA + in-block kv-split ----
// 512 thr (8 waves). Waves 0-3: kv 0..1023. Waves 4-7: kv 1024..2047.
// 32-kv granules; mask(*log2e) loaded directly as the QK MFMA C-init;
// sum via packed v_dot2 on the exact f16 P used by PV.
__global__ __launch_bounds__(512, 4) void attn_fused(
    const f16* __restrict__ qh, const f16* __restrict__ kh, const f16* __restrict__ vt,
    const float* __restrict__ mL, f16* __restrict__ aout) {
    __shared__ char lds_buf[65536];  // per group g: K dbuf [g*32768, +16K), V dbuf +16K
    __shared__ float frl[8][32];     // in-loop rescale broadcast
    __shared__ float fr2[4][2][32];  // merge gA/gB broadcast
    __shared__ float2 msx[4][32];    // merge (m, s) exchange

    int tid = threadIdx.x, w = tid >> 6, l = tid & 63;
    int l31 = l & 31, hi = l >> 5;
    int swl = (l31 & 7) << 4;
    int g = w >> 2, wg = w & 3;
    // bijective XCD swizzle: 8 bh per XCD
    int d0 = blockIdx.x;                 // 0..511
    int xcd = d0 & 7, sx = d0 >> 3;      // sx 0..63
    int bh = xcd * 8 + (sx & 7);         // 0..63
    int qt = sx >> 3;                    // 0..7
    int b = bh >> 4, h = bh & 15;

    char* Kst = lds_buf + g * 32768;
    char* Vst = lds_buf + g * 32768 + 16384;

    // Q B-fragments: col q = l31, k(d) = ds*16 + hi*8 + j
    f16x8 Qf[4];
    {
        const f16* qp = qh + ((size_t)bh * QL_ + qt * 128 + wg * 32 + l31) * HD_ + hi * 8;
#pragma unroll
        for (int ds_ = 0; ds_ < 4; ++ds_) Qf[ds_] = *(const f16x8*)(qp + ds_ * 16);
    }

    // staging: one base pointer each; second instr = uniform byte delta
    const char* kg0; const char* vg0; int ko0, vo0;
    {
        int instr = wg;                          // 0..3
        int r = instr * 8 + (l >> 3);            // LDS row 0..31
        int cc = (l & 7) ^ (r & 7);
        kg0 = (const char*)kh + ((size_t)bh * KVL_ + g * 1024 + r) * 128 + cc * 16;
        ko0 = instr * 1024;
        vg0 = (const char*)vt + ((size_t)bh * HD_ + r) * (KVL_ * 2) + g * 2048 + cc * 16;
        vo0 = instr * 1024;
    }

#define ASTAGE(buf, ch)                                                              \
    {                                                                                \
        g2lds16(kg0 + (size_t)(ch) * 8192, Kst + (buf) * 8192 + ko0);                \
        g2lds16(kg0 + (size_t)(ch) * 8192 + 4096, Kst + (buf) * 8192 + ko0 + 4096);  \
        g2lds16(vg0 + (size_t)(ch) * 128, Vst + (buf) * 8192 + vo0);                 \
        g2lds16(vg0 + (size_t)(ch) * 128 + 131072, Vst + (buf) * 8192 + vo0 + 4096); \
    }

    float mrun = -1e30f, ssum = 0.f;     // per lane: q = l31
    f32x16 acc[2] = {};                  // O: col d = c*32+l31, row q' = (r&3)+8*(r>>2)+4hi
    const float* mpb = mL + b * KVL_ + g * 1024;
    const f16x2 one2 = { (f16)1.0f, (f16)1.0f };

    ASTAGE(0, 0);
    asm volatile("s_waitcnt vmcnt(0)" ::: "memory");
    __syncthreads();

    for (int ch = 0; ch < 16; ++ch) {
        int cur = ch & 1;
        if (ch + 1 < 16) ASTAGE(cur ^ 1, ch + 1);
        const char* Kc = Kst + cur * 8192;
        const char* Vc = Vst + cur * 8192;

#pragma unroll
        for (int kb = 0; kb < 2; ++kb) {
            // C-init = prescaled mask (kv row = (r&3)+8*(r>>2)+4hi matches g4*8+hi*4+j)
            f32x16 St;
#pragma unroll
            for (int g4 = 0; g4 < 4; ++g4) {
                f32x4 mv = *(const f32x4*)(mpb + ch * 64 + kb * 32 + g4 * 8 + hi * 4);
                St[g4 * 4 + 0] = mv[0]; St[g4 * 4 + 1] = mv[1];
                St[g4 * 4 + 2] = mv[2]; St[g4 * 4 + 3] = mv[3];
            }
            __builtin_amdgcn_s_setprio(1);
#pragma unroll
            for (int ds_ = 0; ds_ < 4; ++ds_) {
                f16x8 kf = *(const f16x8*)(Kc + (kb * 32 + l31) * 128 + ((ds_ * 32 + hi * 16) ^ swl));
                St = __builtin_amdgcn_mfma_f32_32x32x16_f16(kf, Qf[ds_], St, 0, 0, 0);
            }
            __builtin_amdgcn_s_setprio(0);

            // row max via max3 tree (+ partner half)
            float a0 = fmaxf(fmaxf(St[0], St[1]), St[2]);
            float a1 = fmaxf(fmaxf(St[3], St[4]), St[5]);
            float a2 = fmaxf(fmaxf(St[6], St[7]), St[8]);
            float a3 = fmaxf(fmaxf(St[9], St[10]), St[11]);
            float a4 = fmaxf(fmaxf(St[12], St[13]), St[14]);
            float pm = fmaxf(fmaxf(fmaxf(a0, a1), St[15]), fmaxf(fmaxf(a2, a3), a4));
            pm = fmaxf(pm, __shfl_xor(pm, 32));

            // deferred-max rescale (rare)
            if (__any(pm > mrun + 12.f)) {
                float mn = fmaxf(mrun, pm);
                float fac = exp2f(mrun - mn);
                mrun = mn;
                ssum *= fac;
                frl[w][l31] = fac;
                asm volatile("s_waitcnt lgkmcnt(0)" ::: "memory");
#pragma unroll
                for (int g4 = 0; g4 < 4; ++g4) {
                    f32x4 fv = *(const f32x4*)&frl[w][g4 * 8 + hi * 4];
#pragma unroll
                    for (int c = 0; c < 2; ++c)
#pragma unroll
                        for (int j = 0; j < 4; ++j) acc[c][g4 * 4 + j] *= fv[j];
                }
            }

            // P = exp2(S - mrun) packed to f16 pairs; ssum via packed dot2
            uint32_t pk[8];
#pragma unroll
            for (int i = 0; i < 8; ++i) {
                float p0 = exp2f(St[2 * i] - mrun);
                float p1 = exp2f(St[2 * i + 1] - mrun);
                uint32_t u = pkrtz(p0, p1);
                pk[i] = u;
                ssum = __builtin_amdgcn_fdot2(__builtin_bit_cast(f16x2, u), one2, ssum, false);
            }

            // PV: A = P; B = single b128 (kv quad-permuted V)
            __builtin_amdgcn_s_setprio(1);
#pragma unroll
            for (int sti = 0; sti < 2; ++sti) {
                U8 pa;
                pa.u[0] = pk[sti * 4 + 0]; pa.u[1] = pk[sti * 4 + 1];
                pa.u[2] = pk[sti * 4 + 2]; pa.u[3] = pk[sti * 4 + 3];
                int st_ = kb * 2 + sti;
#pragma unroll
                for (int c = 0; c < 2; ++c) {
                    U8 vb;
                    vb.v = *(const f16x8*)(Vc + (c * 32 + l31) * 128 + ((st_ * 32 + hi * 16) ^ swl));
                    acc[c] = __builtin_amdgcn_mfma_f32_32x32x16_f16(pa.v, vb.v, acc[c], 0, 0, 0);
                }
            }
            __builtin_amdgcn_s_setprio(0);
        }
        asm volatile("s_waitcnt vmcnt(0)" ::: "memory");
        __syncthreads();
    }

    // ---- merge the two kv halves ----
    ssum += __shfl_xor(ssum, 32);     // full row sum for this group
    char* exch = lds_buf;             // 32KB, aliases group-0 staging (done with it)
    if (g == 1) {
        int base = (wg * 64 + l) * 128;
#pragma unroll
        for (int i = 0; i < 8; ++i) {
            int c = i >> 2, j0 = (i & 3) * 4;
            f32x4 vv = { acc[c][j0], acc[c][j0 + 1], acc[c][j0 + 2], acc[c][j0 + 3] };
            *(f32x4*)(exch + base + ((i * 16) ^ ((l & 7) << 4))) = vv;
        }
        if (hi == 0) msx[wg][l31] = make_float2(mrun, ssum);
    }
    __syncthreads();
    if (g == 0) {
        float2 mb = msx[wg][l31];
        float m = fmaxf(mrun, mb.x);
        float fA = exp2f(mrun - m), fB = exp2f(mb.x - m);
        float s = ssum * fA + mb.y * fB;
        float rinv = 1.0f / s;
        if (hi == 0) { fr2[wg][0][l31] = fA * rinv; fr2[wg][1][l31] = fB * rinv; }
        asm volatile("s_waitcnt lgkmcnt(0)" ::: "memory");
        int base = (wg * 64 + l) * 128;
#pragma unroll
        for (int c = 0; c < 2; ++c)
#pragma unroll
            for (int g4 = 0; g4 < 4; ++g4) {
                f32x4 gAv = *(const f32x4*)&fr2[wg][0][g4 * 8 + hi * 4];
                f32x4 gBv = *(const f32x4*)&fr2[wg][1][g4 * 8 + hi * 4];
                int i = c * 4 + g4;
                f32x4 pv = *(const f32x4*)(exch + base + ((i * 16) ^ ((l & 7) << 4)));
#pragma unroll
                for (int j = 0; j < 4; ++j) {
                    float o = acc[c][g4 * 4 + j] * gAv[j] + pv[j] * gBv[j];
                    int q = qt * 128 + wg * 32 + g4 * 8 + hi * 4 + j;
                    int dd = c * 32 + l31;
                    aout[((size_t)b * QL_ + q) * D_ + h * HD_ + dd] = (f16)o;
                }
            }
    }
#undef ASTAGE
}

extern "C" void kernel_launch(void* const* d_in, const int* in_sizes, int n_in,
                              void* d_out, int out_size, void* d_ws, size_t ws_size,
                              hipStream_t stream) {
    const float* hs = (const float*)d_in[0];
    const float* K  = (const float*)d_in[1];
    const float* V  = (const float*)d_in[2];
    const float* mask = (const float*)d_in[3];
    const float* Wq = (const float*)d_in[4];
    const float* Wo = (const float*)d_in[5];
    float* out = (float*)d_out;
    char* ws = (char*)d_ws;

    f16* hs_h = (f16*)(ws + 0);           //  8 MB
    f16* Wq_t = (f16*)(ws + 8388608);     //  2 MB (Wq^T)
    f16* Wo_t = (f16*)(ws + 10485760);    //  2 MB (Wo^T)
    f16* K_h  = (f16*)(ws + 12582912);    // 16 MB
    f16* V_t  = (f16*)(ws + 29360128);    // 16 MB (b,h,d,kv) kv quad-permuted
    f16* q_h  = (f16*)(ws + 46137344);    //  8 MB (b,h,q,d), pre-scaled by log2e
    f16* a_o  = (f16*)(ws + 54525952);    //  8 MB (b,q,h*64+d)
    float* mL = (float*)(ws + 62914560);  // 32 KB (mask * log2e)

    preprocess<<<4616, 256, 0, stream>>>(hs, hs_h, K, K_h, Wq, Wq_t, Wo, Wo_t,
                                         V, V_t, mask, mL);
    gemm_tn<0><<<512, 512, 0, stream>>>(hs_h, Wq_t, (void*)q_h, 4096, 1024, 1024);
    attn_fused<<<512, 512, 0, stream>>>(q_h, K_h, V_t, mL, a_o);
    gemm_tn<1><<<512, 512, 0, stream>>>(a_o, Wo_t, (void*)out, 4096, 1024, 1024);
}

// Round 8
// 117.443 us; speedup vs baseline: 1.6579x; 1.0012x over previous
//
#include <hip/hip_runtime.h>
#include <hip/hip_bf16.h>
#include <hip/hip_fp16.h>
#include <stdint.h>

typedef _Float16 f16;
typedef _Float16 f16x2 __attribute__((ext_vector_type(2)));
typedef _Float16 f16x4 __attribute__((ext_vector_type(4)));
typedef _Float16 f16x8 __attribute__((ext_vector_type(8)));
typedef float f32x4 __attribute__((ext_vector_type(4)));
typedef float f32x16 __attribute__((ext_vector_type(16)));

#define B_ 4
#define QL_ 1024
#define D_ 1024
#define H_ 16
#define HD_ 64
#define KVL_ 2048
#define L2E 1.44269504088896f

// ---- async global->LDS, 16B per lane, wave-uniform LDS base ----
__device__ __forceinline__ void g2lds16(const void* g, void* l) {
    __builtin_amdgcn_global_load_lds(
        (const __attribute__((address_space(1))) uint32_t*)g,
        (__attribute__((address_space(3))) uint32_t*)l,
        16, 0, 0);
}

union U8 { uint32_t u[4]; f16x8 v; };

__device__ __forceinline__ uint32_t pkrtz(float a, float b) {
    auto t = __builtin_amdgcn_cvt_pkrtz(a, b);
    return __builtin_bit_cast(uint32_t, t);
}

// ---- merged preprocessing ----
// [0,1024):    hs f32->f16 (grid-stride)
// [1024,3072): K f32->f16 into chunk-major layout:
//              unit16B[(bh*32+ch)*512 + ds*128 + kv*2 + hi] = K[bh][ch*64+kv][ds*16+hi*8 ..+8)
// [3072,3584): Wq/Wo transpose
// [3584,5632): V f32->f16 transposed+permuted chunk-major:
//              unit[(bh*32+ch)*512 + st*128 + d*2 + hi], elem j = V[bh][ch*64+st*16+(j&3)+8*(j>>2)+4*hi][d]
// [5632,5640): mask * log2e
__global__ void preprocess(const float* __restrict__ hs, f16* __restrict__ hs_h,
                           const float* __restrict__ K, f16* __restrict__ K_h,
                           const float* __restrict__ Wq, f16* __restrict__ Wq_t,
                           const float* __restrict__ Wo, f16* __restrict__ Wo_t,
                           const float* __restrict__ V, f16* __restrict__ V_t,
                           const float* __restrict__ mask, float* __restrict__ mL) {
    __shared__ float t[64][65];
    int bid = blockIdx.x, tid = threadIdx.x;
    if (bid < 1024) {
        const int n4 = (B_ * QL_ * D_) / 4;
        for (int i = bid * 256 + tid; i < n4; i += 1024 * 256) {
            float4 v = ((const float4*)hs)[i];
            f16x4 o = { (f16)v.x, (f16)v.y, (f16)v.z, (f16)v.w };
            ((f16x4*)hs_h)[i] = o;
        }
    } else if (bid < 3072) {
        int t0 = (bid - 1024) * 256 + tid;
#pragma unroll
        for (int rep = 0; rep < 2; ++rep) {
            int U = t0 + rep * 524288;
            int bh = U >> 14, rem = U & 16383;
            int ch = rem >> 9, r2 = rem & 511;
            int dsl = r2 >> 7, r3 = r2 & 127;
            int kv = r3 >> 1, hi2 = r3 & 1;
            const float* sp = K + (((size_t)bh * KVL_ + ch * 64 + kv) * HD_ + dsl * 16 + hi2 * 8);
            f16x8 o;
#pragma unroll
            for (int j = 0; j < 8; ++j) o[j] = (f16)sp[j];
            *(f16x8*)(K_h + (size_t)U * 8) = o;
        }
    } else if (bid < 3584) {
        int wbid = bid - 3072;
        const float* src = wbid < 256 ? Wq : Wo;
        f16* dst = wbid < 256 ? Wq_t : Wo_t;
        int b2 = wbid & 255;
        int k0 = (b2 >> 4) << 6, n0 = (b2 & 15) << 6;
        int rr = tid >> 4, c4 = (tid & 15) << 2;
#pragma unroll
        for (int i = 0; i < 4; ++i) {
            int r = i * 16 + rr;
            float4 v = *(const float4*)(src + (size_t)(k0 + r) * 1024 + n0 + c4);
            t[r][c4 + 0] = v.x; t[r][c4 + 1] = v.y; t[r][c4 + 2] = v.z; t[r][c4 + 3] = v.w;
        }
        __syncthreads();
#pragma unroll
        for (int i = 0; i < 4; ++i) {
            int n = i * 16 + rr;
            f16x4 o;
#pragma unroll
            for (int j = 0; j < 4; ++j) o[j] = (f16)t[c4 + j][n];
            *(f16x4*)(dst + (size_t)(n0 + n) * 1024 + k0 + c4) = o;
        }
    } else if (bid < 5632) {
        int vb = bid - 3584;
        int bh = vb >> 5, ch = vb & 31;
        int rr = tid >> 4, c4 = (tid & 15) << 2;
#pragma unroll
        for (int i = 0; i < 4; ++i) {
            int r = i * 16 + rr;
            float4 v = *(const float4*)(V + ((size_t)bh * KVL_ + ch * 64 + r) * HD_ + c4);
            t[r][c4 + 0] = v.x; t[r][c4 + 1] = v.y; t[r][c4 + 2] = v.z; t[r][c4 + 3] = v.w;
        }
        __syncthreads();
#pragma unroll
        for (int rep = 0; rep < 2; ++rep) {
            int u = tid + rep * 256;
            int st = u >> 7, d = (u >> 1) & 63, hi2 = u & 1;
            f16x8 o;
#pragma unroll
            for (int j = 0; j < 8; ++j) {
                int kvl = st * 16 + (j & 3) + 8 * (j >> 2) + 4 * hi2;
                o[j] = (f16)t[kvl][d];
            }
            *(f16x8*)(V_t + ((size_t)(bh * 32 + ch) * 512 + u) * 8) = o;
        }
    } else {
        int i = (bid - 5632) * 256 + tid;
        if (i < (B_ * KVL_) / 4) {
            f32x4 v = ((const f32x4*)mask)[i];
            v *= L2E;
            ((f32x4*)mL)[i] = v;
        }
    }
}

// ---- GEMM: C[M][N] = A[M][K] * BT[N][K]^T, 2-phase dbuf, hoisted addresses ----
template <int EPI>
__global__ __launch_bounds__(512) void gemm_tn(
    const f16* __restrict__ A, const f16* __restrict__ BT, void* __restrict__ Cout,
    int M, int N, int K) {
    __shared__ char Alds[2][16384];  // 128 rows x 64 f16, XOR-swizzled
    __shared__ char Blds[2][8192];   // 64 rows x 64 f16
    int d0 = blockIdx.x;
    int xcd = d0 & 7, sx = d0 >> 3;
    int bm = xcd * 4 + (sx & 3);
    int bn = sx >> 2;
    int tid = threadIdx.x, w = tid >> 6, l = tid & 63;
    int l15 = l & 15, lg = l >> 4;
    int wm = w >> 1, wn = w & 1;
    f32x4 acc[2][2] = {};

    const char* ag0; const char* ag1; int ao0, ao1;
    {
        int i0 = w, i1 = w + 8;
        int r0 = i0 * 8 + (l >> 3), r1 = i1 * 8 + (l >> 3);
        int c0 = (l & 7) ^ (r0 & 7), c1 = (l & 7) ^ (r1 & 7);
        ag0 = (const char*)A + ((size_t)(bm * 128 + r0) * K + c0 * 8) * 2;
        ag1 = (const char*)A + ((size_t)(bm * 128 + r1) * K + c1 * 8) * 2;
        ao0 = i0 * 1024; ao1 = i1 * 1024;
    }
    int rB = w * 8 + (l >> 3);
    int ccB = (l & 7) ^ (rB & 7);
    const char* bgp = (const char*)BT + ((size_t)(bn * 64 + rB) * K + ccB * 8) * 2;
    int boB = w * 1024;

    // hoisted LDS read offsets
    int aoff[2][2], boff[2][2];
#pragma unroll
    for (int ks = 0; ks < 2; ++ks)
#pragma unroll
        for (int m = 0; m < 2; ++m) {
            int ra = wm * 32 + m * 16 + l15;
            aoff[ks][m] = ra * 128 + ((ks * 64 + lg * 16) ^ ((ra & 7) << 4));
            int rb = wn * 32 + m * 16 + l15;
            boff[ks][m] = rb * 128 + ((ks * 64 + lg * 16) ^ ((rb & 7) << 4));
        }
    const char* Ab = &Alds[0][0];
    const char* Bb = &Blds[0][0];

#define GSTAGE(buf, soff)                                      \
    {                                                          \
        g2lds16(ag0 + (soff), &Alds[buf][ao0]);                \
        g2lds16(ag1 + (soff), &Alds[buf][ao1]);                \
        g2lds16(bgp + (soff), &Blds[buf][boB]);                \
    }
#define GCOMP(buf)                                                               \
    _Pragma("unroll") for (int ks = 0; ks < 2; ++ks) {                           \
        f16x8 af[2], bf[2];                                                      \
        af[0] = *(const f16x8*)(Ab + (buf) * 16384 + aoff[ks][0]);               \
        af[1] = *(const f16x8*)(Ab + (buf) * 16384 + aoff[ks][1]);               \
        bf[0] = *(const f16x8*)(Bb + (buf) * 8192 + boff[ks][0]);                \
        bf[1] = *(const f16x8*)(Bb + (buf) * 8192 + boff[ks][1]);                \
        _Pragma("unroll") for (int m = 0; m < 2; ++m)                            \
            _Pragma("unroll") for (int n = 0; n < 2; ++n)                        \
                acc[m][n] = __builtin_amdgcn_mfma_f32_16x16x32_f16(af[m], bf[n], acc[m][n], 0, 0, 0); \
    }

    GSTAGE(0, 0);
    asm volatile("s_waitcnt vmcnt(0)" ::: "memory");
    __syncthreads();

    for (int t2 = 0; t2 < 8; ++t2) {        // K = 1024 -> 16 kt steps, x2 unrolled
        GSTAGE(1, 128);
        GCOMP(0);
        asm volatile("s_waitcnt vmcnt(0)" ::: "memory");
        __syncthreads();
        if (t2 < 7) GSTAGE(0, 256);
        GCOMP(1);
        asm volatile("s_waitcnt vmcnt(0)" ::: "memory");
        __syncthreads();
        ag0 += 256; ag1 += 256; bgp += 256;
    }

#pragma unroll
    for (int m = 0; m < 2; ++m)
#pragma unroll
        for (int n = 0; n < 2; ++n)
#pragma unroll
            for (int i = 0; i < 4; ++i) {
                int row = bm * 128 + wm * 32 + m * 16 + lg * 4 + i;
                int col = bn * 64 + wn * 32 + n * 16 + l15;
                if (EPI == 0) {
                    float v = acc[m][n][i] * L2E;
                    int b = row >> 10, q = row & 1023, h = col >> 6, d = col & 63;
                    ((f16*)Cout)[(((size_t)b * H_ + h) * QL_ + q) * HD_ + d] = (f16)v;
                } else {
                    ((float*)Cout)[(size_t)row * N + col] = acc[m][n][i];
                }
            }
#undef GSTAGE
#undef GCOMP
}

// ---- fused flash attention: conflict-free 32B-row LDS, zero steady-state addr math ----
// 512 thr (8 waves), groups of 4 waves split kv. K LDS chunk [ds 4][kv 64][32B],
// V LDS chunk [st 4][d 64][32B] (kv-permutation baked in preprocess).
__global__ __launch_bounds__(512, 4) void attn_fused(
    const f16* __restrict__ qh, const f16* __restrict__ kh, const f16* __restrict__ vt,
    const float* __restrict__ mL, f16* __restrict__ aout) {
    __shared__ char lds_buf[65536];  // per group: K dbuf 16K, V dbuf 16K
    __shared__ float frl[8][32];
    __shared__ float fr2[4][2][32];
    __shared__ float2 msx[4][32];

    int tid = threadIdx.x, w = tid >> 6, l = tid & 63;
    int l31 = l & 31, hi = l >> 5;
    int g = w >> 2, wg = w & 3;
    int d0 = blockIdx.x;
    int xcd = d0 & 7, sx = d0 >> 3;
    int bh = xcd * 8 + (sx & 7);
    int qt = sx >> 3;
    int b = bh >> 4, h = bh & 15;

    // single per-lane LDS read base; all reads are lbase + compile-time imm
    const char* lbase = lds_buf + g * 32768 + l31 * 32 + hi * 16;

    f16x8 Qf[4];
    {
        const f16* qp = qh + ((size_t)bh * QL_ + qt * 128 + wg * 32 + l31) * HD_ + hi * 8;
#pragma unroll
        for (int ds_ = 0; ds_ < 4; ++ds_) Qf[ds_] = *(const f16x8*)(qp + ds_ * 16);
    }

    // linear staging (chunk-major global layouts): 2 K + 2 V instrs per wave
    int i0 = wg * 2;
    const char* kgp0 = (const char*)kh + (((size_t)(bh * 32 + g * 16) * 512) + i0 * 64 + l) * 16;
    const char* kgp1 = kgp0 + 1024;
    const char* vgp0 = (const char*)vt + (((size_t)(bh * 32 + g * 16) * 512) + i0 * 64 + l) * 16;
    const char* vgp1 = vgp0 + 1024;
    char* kl0 = lds_buf + g * 32768 + i0 * 1024;
    char* kl1 = kl0 + 1024;
    char* vl0 = lds_buf + g * 32768 + 16384 + i0 * 1024;
    char* vl1 = vl0 + 1024;

#define PREF(buf, soff)                                  \
    {                                                    \
        g2lds16(kgp0 + (soff), kl0 + (buf) * 8192);      \
        g2lds16(kgp1 + (soff), kl1 + (buf) * 8192);      \
        g2lds16(vgp0 + (soff), vl0 + (buf) * 8192);      \
        g2lds16(vgp1 + (soff), vl1 + (buf) * 8192);      \
    }

    float mrun = -1e30f, ssum = 0.f;
    f32x16 acc[2] = {};
    const float* mp = mL + b * KVL_ + g * 1024;
    const f16x2 one2 = { (f16)1.0f, (f16)1.0f };

#define BODY(buf, mo)                                                                     \
    _Pragma("unroll") for (int kb = 0; kb < 2; ++kb) {                                    \
        f32x16 St;                                                                        \
        _Pragma("unroll") for (int g4 = 0; g4 < 4; ++g4) {                                \
            f32x4 mv = *(const f32x4*)(mp + (mo) + kb * 32 + g4 * 8 + hi * 4);            \
            St[g4 * 4 + 0] = mv[0]; St[g4 * 4 + 1] = mv[1];                               \
            St[g4 * 4 + 2] = mv[2]; St[g4 * 4 + 3] = mv[3];                               \
        }                                                                                 \
        __builtin_amdgcn_s_setprio(1);                                                    \
        _Pragma("unroll") for (int ds_ = 0; ds_ < 4; ++ds_) {                             \
            f16x8 kf = *(const f16x8*)(lbase + (buf) * 8192 + ds_ * 2048 + kb * 1024);    \
            St = __builtin_amdgcn_mfma_f32_32x32x16_f16(kf, Qf[ds_], St, 0, 0, 0);        \
        }                                                                                 \
        __builtin_amdgcn_s_setprio(0);                                                    \
        float a0 = fmaxf(fmaxf(St[0], St[1]), St[2]);                                     \
        float a1 = fmaxf(fmaxf(St[3], St[4]), St[5]);                                     \
        float a2 = fmaxf(fmaxf(St[6], St[7]), St[8]);                                     \
        float a3 = fmaxf(fmaxf(St[9], St[10]), St[11]);                                   \
        float a4 = fmaxf(fmaxf(St[12], St[13]), St[14]);                                  \
        float pm = fmaxf(fmaxf(fmaxf(a0, a1), St[15]), fmaxf(fmaxf(a2, a3), a4));         \
        pm = fmaxf(pm, __shfl_xor(pm, 32));                                               \
        if (__any(pm > mrun + 12.f)) {                                                    \
            float mn = fmaxf(mrun, pm);                                                   \
            float fac = exp2f(mrun - mn);                                                 \
            mrun = mn; ssum *= fac;                                                       \
            frl[w][l31] = fac;                                                            \
            asm volatile("s_waitcnt lgkmcnt(0)" ::: "memory");                            \
            _Pragma("unroll") for (int g4 = 0; g4 < 4; ++g4) {                            \
                f32x4 fv = *(const f32x4*)&frl[w][g4 * 8 + hi * 4];                       \
                _Pragma("unroll") for (int c = 0; c < 2; ++c)                             \
                    _Pragma("unroll") for (int j = 0; j < 4; ++j)                         \
                        acc[c][g4 * 4 + j] *= fv[j];                                      \
            }                                                                             \
        }                                                                                 \
        uint32_t pk[8];                                                                   \
        _Pragma("unroll") for (int i = 0; i < 8; ++i) {                                   \
            float p0 = exp2f(St[2 * i] - mrun);                                           \
            float p1 = exp2f(St[2 * i + 1] - mrun);                                       \
            uint32_t u = pkrtz(p0, p1);                                                   \
            pk[i] = u;                                                                    \
            ssum = __builtin_amdgcn_fdot2(__builtin_bit_cast(f16x2, u), one2, ssum, false); \
        }                                                                                 \
        __builtin_amdgcn_s_setprio(1);                                                    \
        _Pragma("unroll") for (int sti = 0; sti < 2; ++sti) {                             \
            U8 pa;                                                                        \
            pa.u[0] = pk[sti * 4 + 0]; pa.u[1] = pk[sti * 4 + 1];                         \
            pa.u[2] = pk[sti * 4 + 2]; pa.u[3] = pk[sti * 4 + 3];                         \
            const int st_ = kb * 2 + sti;                                                 \
            _Pragma("unroll") for (int c = 0; c < 2; ++c) {                               \
                U8 vb;                                                                    \
                vb.v = *(const f16x8*)(lbase + 16384 + (buf) * 8192 + st_ * 2048 + c * 1024); \
                acc[c] = __builtin_amdgcn_mfma_f32_32x32x16_f16(pa.v, vb.v, acc[c], 0, 0, 0); \
            }                                                                             \
        }                                                                                 \
        __builtin_amdgcn_s_setprio(0);                                                    \
    }

    PREF(0, 0);
    asm volatile("s_waitcnt vmcnt(0)" ::: "memory");
    __syncthreads();

    for (int it = 0; it < 8; ++it) {
        PREF(1, 8192);
        BODY(0, 0);
        asm volatile("s_waitcnt vmcnt(0)" ::: "memory");
        __syncthreads();
        if (it < 7) PREF(0, 16384);
        BODY(1, 64);
        asm volatile("s_waitcnt vmcnt(0)" ::: "memory");
        __syncthreads();
        kgp0 += 16384; kgp1 += 16384; vgp0 += 16384; vgp1 += 16384;
        mp += 128;
    }

    // ---- merge the two kv halves ----
    ssum += __shfl_xor(ssum, 32);
    char* exch = lds_buf;
    if (g == 1) {
        int base = (wg * 64 + l) * 128;
#pragma unroll
        for (int i = 0; i < 8; ++i) {
            int c = i >> 2, j0 = (i & 3) * 4;
            f32x4 vv = { acc[c][j0], acc[c][j0 + 1], acc[c][j0 + 2], acc[c][j0 + 3] };
            *(f32x4*)(exch + base + ((i * 16) ^ ((l & 7) << 4))) = vv;
        }
        if (hi == 0) msx[wg][l31] = make_float2(mrun, ssum);
    }
    __syncthreads();
    if (g == 0) {
        float2 mb = msx[wg][l31];
        float m = fmaxf(mrun, mb.x);
        float fA = exp2f(mrun - m), fB = exp2f(mb.x - m);
        float s = ssum * fA + mb.y * fB;
        float rinv = 1.0f / s;
        if (hi == 0) { fr2[wg][0][l31] = fA * rinv; fr2[wg][1][l31] = fB * rinv; }
        asm volatile("s_waitcnt lgkmcnt(0)" ::: "memory");
        int base = (wg * 64 + l) * 128;
#pragma unroll
        for (int c = 0; c < 2; ++c)
#pragma unroll
            for (int g4 = 0; g4 < 4; ++g4) {
                f32x4 gAv = *(const f32x4*)&fr2[wg][0][g4 * 8 + hi * 4];
                f32x4 gBv = *(const f32x4*)&fr2[wg][1][g4 * 8 + hi * 4];
                int i = c * 4 + g4;
                f32x4 pv = *(const f32x4*)(exch + base + ((i * 16) ^ ((l & 7) << 4)));
#pragma unroll
                for (int j = 0; j < 4; ++j) {
                    float o = acc[c][g4 * 4 + j] * gAv[j] + pv[j] * gBv[j];
                    int q = qt * 128 + wg * 32 + g4 * 8 + hi * 4 + j;
                    int dd = c * 32 + l31;
                    aout[((size_t)b * QL_ + q) * D_ + h * HD_ + dd] = (f16)o;
                }
            }
    }
#undef PREF
#undef BODY
}

extern "C" void kernel_launch(void* const* d_in, const int* in_sizes, int n_in,
                              void* d_out, int out_size, void* d_ws, size_t ws_size,
                              hipStream_t stream) {
    const float* hs = (const float*)d_in[0];
    const float* K  = (const float*)d_in[1];
    const float* V  = (const float*)d_in[2];
    const float* mask = (const float*)d_in[3];
    const float* Wq = (const float*)d_in[4];
    const float* Wo = (const float*)d_in[5];
    float* out = (float*)d_out;
    char* ws = (char*)d_ws;

    f16* hs_h = (f16*)(ws + 0);           //  8 MB
    f16* Wq_t = (f16*)(ws + 8388608);     //  2 MB
    f16* Wo_t = (f16*)(ws + 10485760);    //  2 MB
    f16* K_h  = (f16*)(ws + 12582912);    // 16 MB, chunk-major
    f16* V_t  = (f16*)(ws + 29360128);    // 16 MB, chunk-major transposed+permuted
    f16* q_h  = (f16*)(ws + 46137344);    //  8 MB (b,h,q,d), pre-scaled by log2e
    f16* a_o  = (f16*)(ws + 54525952);    //  8 MB (b,q,h*64+d)
    float* mL = (float*)(ws + 62914560);  // 32 KB (mask * log2e)

    preprocess<<<5640, 256, 0, stream>>>(hs, hs_h, K, K_h, Wq, Wq_t, Wo, Wo_t,
                                         V, V_t, mask, mL);
    gemm_tn<0><<<512, 512, 0, stream>>>(hs_h, Wq_t, (void*)q_h, 4096, 1024, 1024);
    attn_fused<<<512, 512, 0, stream>>>(q_h, K_h, V_t, mL, a_o);
    gemm_tn<1><<<512, 512, 0, stream>>>(a_o, Wo_t, (void*)out, 4096, 1024, 1024);
}

// Round 9
// 117.214 us; speedup vs baseline: 1.6612x; 1.0020x over previous
//
#include <hip/hip_runtime.h>
#include <hip/hip_bf16.h>
#include <hip/hip_fp16.h>
#include <stdint.h>

typedef _Float16 f16;
typedef _Float16 f16x2 __attribute__((ext_vector_type(2)));
typedef _Float16 f16x4 __attribute__((ext_vector_type(4)));
typedef _Float16 f16x8 __attribute__((ext_vector_type(8)));
typedef float f32x4 __attribute__((ext_vector_type(4)));
typedef float f32x16 __attribute__((ext_vector_type(16)));

#define B_ 4
#define QL_ 1024
#define D_ 1024
#define H_ 16
#define HD_ 64
#define KVL_ 2048
#define L2E 1.44269504088896f

// ---- async global->LDS, 16B per lane, wave-uniform LDS base ----
__device__ __forceinline__ void g2lds16(const void* g, void* l) {
    __builtin_amdgcn_global_load_lds(
        (const __attribute__((address_space(1))) uint32_t*)g,
        (__attribute__((address_space(3))) uint32_t*)l,
        16, 0, 0);
}

union U8 { uint32_t u[4]; f16x8 v; };

__device__ __forceinline__ uint32_t pkrtz(float a, float b) {
    auto t = __builtin_amdgcn_cvt_pkrtz(a, b);
    return __builtin_bit_cast(uint32_t, t);
}

// ---- merged preprocessing ----
// [0,1024):    hs f32->f16 (grid-stride)
// [1024,3072): K f32->f16 chunk-major: unit16B[(bh*32+ch)*512 + ds*128 + kv*2 + hi]
// [3072,3584): Wq/Wo transpose
// [3584,5632): V f32->f16 transposed+permuted chunk-major
// [5632,5640): mask * log2e
__global__ void preprocess(const float* __restrict__ hs, f16* __restrict__ hs_h,
                           const float* __restrict__ K, f16* __restrict__ K_h,
                           const float* __restrict__ Wq, f16* __restrict__ Wq_t,
                           const float* __restrict__ Wo, f16* __restrict__ Wo_t,
                           const float* __restrict__ V, f16* __restrict__ V_t,
                           const float* __restrict__ mask, float* __restrict__ mL) {
    __shared__ float t[64][65];
    int bid = blockIdx.x, tid = threadIdx.x;
    if (bid < 1024) {
        const int n4 = (B_ * QL_ * D_) / 4;
        for (int i = bid * 256 + tid; i < n4; i += 1024 * 256) {
            float4 v = ((const float4*)hs)[i];
            f16x4 o = { (f16)v.x, (f16)v.y, (f16)v.z, (f16)v.w };
            ((f16x4*)hs_h)[i] = o;
        }
    } else if (bid < 3072) {
        int t0 = (bid - 1024) * 256 + tid;
#pragma unroll
        for (int rep = 0; rep < 2; ++rep) {
            int U = t0 + rep * 524288;
            int bh = U >> 14, rem = U & 16383;
            int ch = rem >> 9, r2 = rem & 511;
            int dsl = r2 >> 7, r3 = r2 & 127;
            int kv = r3 >> 1, hi2 = r3 & 1;
            const float* sp = K + (((size_t)bh * KVL_ + ch * 64 + kv) * HD_ + dsl * 16 + hi2 * 8);
            f16x8 o;
#pragma unroll
            for (int j = 0; j < 8; ++j) o[j] = (f16)sp[j];
            *(f16x8*)(K_h + (size_t)U * 8) = o;
        }
    } else if (bid < 3584) {
        int wbid = bid - 3072;
        const float* src = wbid < 256 ? Wq : Wo;
        f16* dst = wbid < 256 ? Wq_t : Wo_t;
        int b2 = wbid & 255;
        int k0 = (b2 >> 4) << 6, n0 = (b2 & 15) << 6;
        int rr = tid >> 4, c4 = (tid & 15) << 2;
#pragma unroll
        for (int i = 0; i < 4; ++i) {
            int r = i * 16 + rr;
            float4 v = *(const float4*)(src + (size_t)(k0 + r) * 1024 + n0 + c4);
            t[r][c4 + 0] = v.x; t[r][c4 + 1] = v.y; t[r][c4 + 2] = v.z; t[r][c4 + 3] = v.w;
        }
        __syncthreads();
#pragma unroll
        for (int i = 0; i < 4; ++i) {
            int n = i * 16 + rr;
            f16x4 o;
#pragma unroll
            for (int j = 0; j < 4; ++j) o[j] = (f16)t[c4 + j][n];
            *(f16x4*)(dst + (size_t)(n0 + n) * 1024 + k0 + c4) = o;
        }
    } else if (bid < 5632) {
        int vb = bid - 3584;
        int bh = vb >> 5, ch = vb & 31;
        int rr = tid >> 4, c4 = (tid & 15) << 2;
#pragma unroll
        for (int i = 0; i < 4; ++i) {
            int r = i * 16 + rr;
            float4 v = *(const float4*)(V + ((size_t)bh * KVL_ + ch * 64 + r) * HD_ + c4);
            t[r][c4 + 0] = v.x; t[r][c4 + 1] = v.y; t[r][c4 + 2] = v.z; t[r][c4 + 3] = v.w;
        }
        __syncthreads();
#pragma unroll
        for (int rep = 0; rep < 2; ++rep) {
            int u = tid + rep * 256;
            int st = u >> 7, d = (u >> 1) & 63, hi2 = u & 1;
            f16x8 o;
#pragma unroll
            for (int j = 0; j < 8; ++j) {
                int kvl = st * 16 + (j & 3) + 8 * (j >> 2) + 4 * hi2;
                o[j] = (f16)t[kvl][d];
            }
            *(f16x8*)(V_t + ((size_t)(bh * 32 + ch) * 512 + u) * 8) = o;
        }
    } else {
        int i = (bid - 5632) * 256 + tid;
        if (i < (B_ * KVL_) / 4) {
            f32x4 v = ((const f32x4*)mask)[i];
            v *= L2E;
            ((f32x4*)mL)[i] = v;
        }
    }
}

// ---- GEMM: C[M][N] = A[M][K] * BT[N][K]^T, 2-phase dbuf, hoisted addresses ----
template <int EPI>
__global__ __launch_bounds__(512) void gemm_tn(
    const f16* __restrict__ A, const f16* __restrict__ BT, void* __restrict__ Cout,
    int M, int N, int K) {
    __shared__ char Alds[2][16384];
    __shared__ char Blds[2][8192];
    int d0 = blockIdx.x;
    int xcd = d0 & 7, sx = d0 >> 3;
    int bm = xcd * 4 + (sx & 3);
    int bn = sx >> 2;
    int tid = threadIdx.x, w = tid >> 6, l = tid & 63;
    int l15 = l & 15, lg = l >> 4;
    int wm = w >> 1, wn = w & 1;
    f32x4 acc[2][2] = {};

    const char* ag0; const char* ag1; int ao0, ao1;
    {
        int i0 = w, i1 = w + 8;
        int r0 = i0 * 8 + (l >> 3), r1 = i1 * 8 + (l >> 3);
        int c0 = (l & 7) ^ (r0 & 7), c1 = (l & 7) ^ (r1 & 7);
        ag0 = (const char*)A + ((size_t)(bm * 128 + r0) * K + c0 * 8) * 2;
        ag1 = (const char*)A + ((size_t)(bm * 128 + r1) * K + c1 * 8) * 2;
        ao0 = i0 * 1024; ao1 = i1 * 1024;
    }
    int rB = w * 8 + (l >> 3);
    int ccB = (l & 7) ^ (rB & 7);
    const char* bgp = (const char*)BT + ((size_t)(bn * 64 + rB) * K + ccB * 8) * 2;
    int boB = w * 1024;

    int aoff[2][2], boff[2][2];
#pragma unroll
    for (int ks = 0; ks < 2; ++ks)
#pragma unroll
        for (int m = 0; m < 2; ++m) {
            int ra = wm * 32 + m * 16 + l15;
            aoff[ks][m] = ra * 128 + ((ks * 64 + lg * 16) ^ ((ra & 7) << 4));
            int rb = wn * 32 + m * 16 + l15;
            boff[ks][m] = rb * 128 + ((ks * 64 + lg * 16) ^ ((rb & 7) << 4));
        }
    const char* Ab = &Alds[0][0];
    const char* Bb = &Blds[0][0];

#define GSTAGE(buf, soff)                                      \
    {                                                          \
        g2lds16(ag0 + (soff), &Alds[buf][ao0]);                \
        g2lds16(ag1 + (soff), &Alds[buf][ao1]);                \
        g2lds16(bgp + (soff), &Blds[buf][boB]);                \
    }
#define GCOMP(buf)                                                               \
    _Pragma("unroll") for (int ks = 0; ks < 2; ++ks) {                           \
        f16x8 af[2], bf[2];                                                      \
        af[0] = *(const f16x8*)(Ab + (buf) * 16384 + aoff[ks][0]);               \
        af[1] = *(const f16x8*)(Ab + (buf) * 16384 + aoff[ks][1]);               \
        bf[0] = *(const f16x8*)(Bb + (buf) * 8192 + boff[ks][0]);                \
        bf[1] = *(const f16x8*)(Bb + (buf) * 8192 + boff[ks][1]);                \
        _Pragma("unroll") for (int m = 0; m < 2; ++m)                            \
            _Pragma("unroll") for (int n = 0; n < 2; ++n)                        \
                acc[m][n] = __builtin_amdgcn_mfma_f32_16x16x32_f16(af[m], bf[n], acc[m][n], 0, 0, 0); \
    }

    GSTAGE(0, 0);
    asm volatile("s_waitcnt vmcnt(0)" ::: "memory");
    __syncthreads();

    for (int t2 = 0; t2 < 8; ++t2) {
        GSTAGE(1, 128);
        GCOMP(0);
        asm volatile("s_waitcnt vmcnt(0)" ::: "memory");
        __syncthreads();
        if (t2 < 7) GSTAGE(0, 256);
        GCOMP(1);
        asm volatile("s_waitcnt vmcnt(0)" ::: "memory");
        __syncthreads();
        ag0 += 256; ag1 += 256; bgp += 256;
    }

#pragma unroll
    for (int m = 0; m < 2; ++m)
#pragma unroll
        for (int n = 0; n < 2; ++n)
#pragma unroll
            for (int i = 0; i < 4; ++i) {
                int row = bm * 128 + wm * 32 + m * 16 + lg * 4 + i;
                int col = bn * 64 + wn * 32 + n * 16 + l15;
                if (EPI == 0) {
                    float v = acc[m][n][i] * L2E;
                    int b = row >> 10, q = row & 1023, h = col >> 6, d = col & 63;
                    ((f16*)Cout)[(((size_t)b * H_ + h) * QL_ + q) * HD_ + d] = (f16)v;
                } else {
                    ((float*)Cout)[(size_t)row * N + col] = acc[m][n][i];
                }
            }
#undef GSTAGE
#undef GCOMP
}

// ---- fused flash attention: granule-pipelined (SM[g] under MFMA[g+1] shadow) ----
// 512 thr (8 waves), 2 groups of 4 waves split kv; conflict-free 32B-row LDS;
// mask staged in LDS; common-path softmax has NO cross-lane ops.
__global__ __launch_bounds__(512, 4) void attn_fused(
    const f16* __restrict__ qh, const f16* __restrict__ kh, const f16* __restrict__ vt,
    const float* __restrict__ mL, f16* __restrict__ aout) {
    __shared__ char lds_buf[65536];  // per group: K dbuf 16K, V dbuf 16K
    __shared__ float msk[2][1024];   // per group: prescaled mask (4KB)
    __shared__ float frl[8][32];
    __shared__ float fr2[4][2][32];
    __shared__ float2 msx[4][32];

    int tid = threadIdx.x, w = tid >> 6, l = tid & 63;
    int l31 = l & 31, hi = l >> 5;
    int g = w >> 2, wg = w & 3;
    int d0 = blockIdx.x;
    int xcd = d0 & 7, sx = d0 >> 3;
    int bh = xcd * 8 + (sx & 7);
    int qt = sx >> 3;
    int b = bh >> 4, h = bh & 15;

    const char* lbase = lds_buf + g * 32768 + l31 * 32 + hi * 16;
    const char* mlb = (const char*)&msk[g][0] + hi * 16;

    f16x8 Qf[4];
    {
        const f16* qp = qh + ((size_t)bh * QL_ + qt * 128 + wg * 32 + l31) * HD_ + hi * 8;
#pragma unroll
        for (int ds_ = 0; ds_ < 4; ++ds_) Qf[ds_] = *(const f16x8*)(qp + ds_ * 16);
    }

    int i0 = wg * 2;
    const char* kgp0 = (const char*)kh + (((size_t)(bh * 32 + g * 16) * 512) + i0 * 64 + l) * 16;
    const char* kgp1 = kgp0 + 1024;
    const char* vgp0 = (const char*)vt + (((size_t)(bh * 32 + g * 16) * 512) + i0 * 64 + l) * 16;
    const char* vgp1 = vgp0 + 1024;
    char* kl0 = lds_buf + g * 32768 + i0 * 1024;
    char* kl1 = kl0 + 1024;
    char* vl0 = lds_buf + g * 32768 + 16384 + i0 * 1024;
    char* vl1 = vl0 + 1024;

#define PREF(buf, soff)                                  \
    {                                                    \
        g2lds16(kgp0 + (soff), kl0 + (buf) * 8192);      \
        g2lds16(kgp1 + (soff), kl1 + (buf) * 8192);      \
        g2lds16(vgp0 + (soff), vl0 + (buf) * 8192);      \
        g2lds16(vgp1 + (soff), vl1 + (buf) * 8192);      \
    }

    float mrun = -1e30f, ssum = 0.f;
    f32x16 acc[2] = {};
    const f16x2 one2 = { (f16)1.0f, (f16)1.0f };

    // softmax + PV for one 32-kv granule (St consumed); no shfl in common path
#define SMPV(St, buf, stbase)                                                             \
    {                                                                                     \
        float a0 = fmaxf(fmaxf(St[0], St[1]), St[2]);                                     \
        float a1 = fmaxf(fmaxf(St[3], St[4]), St[5]);                                     \
        float a2 = fmaxf(fmaxf(St[6], St[7]), St[8]);                                     \
        float a3 = fmaxf(fmaxf(St[9], St[10]), St[11]);                                   \
        float a4 = fmaxf(fmaxf(St[12], St[13]), St[14]);                                  \
        float lmax = fmaxf(fmaxf(fmaxf(a0, a1), St[15]), fmaxf(a2, fmaxf(a3, a4)));       \
        if (__any(lmax > mrun + 12.f)) {                                                  \
            float pm = fmaxf(lmax, __shfl_xor(lmax, 32));                                 \
            float mn = fmaxf(mrun, pm);                                                   \
            float fac = exp2f(mrun - mn);                                                 \
            mrun = mn; ssum *= fac;                                                       \
            frl[w][l31] = fac;                                                            \
            asm volatile("s_waitcnt lgkmcnt(0)" ::: "memory");                            \
            _Pragma("unroll") for (int g4 = 0; g4 < 4; ++g4) {                            \
                f32x4 fv = *(const f32x4*)&frl[w][g4 * 8 + hi * 4];                       \
                _Pragma("unroll") for (int c = 0; c < 2; ++c)                             \
                    _Pragma("unroll") for (int j = 0; j < 4; ++j)                         \
                        acc[c][g4 * 4 + j] *= fv[j];                                      \
            }                                                                             \
        }                                                                                 \
        uint32_t pk[8];                                                                   \
        _Pragma("unroll") for (int i = 0; i < 8; ++i) {                                   \
            float p0 = exp2f(St[2 * i] - mrun);                                           \
            float p1 = exp2f(St[2 * i + 1] - mrun);                                       \
            uint32_t u = pkrtz(p0, p1);                                                   \
            pk[i] = u;                                                                    \
            ssum = __builtin_amdgcn_fdot2(__builtin_bit_cast(f16x2, u), one2, ssum, false); \
        }                                                                                 \
        __builtin_amdgcn_s_setprio(1);                                                    \
        _Pragma("unroll") for (int sti = 0; sti < 2; ++sti) {                             \
            U8 pa;                                                                        \
            pa.u[0] = pk[sti * 4 + 0]; pa.u[1] = pk[sti * 4 + 1];                         \
            pa.u[2] = pk[sti * 4 + 2]; pa.u[3] = pk[sti * 4 + 3];                         \
            const int st_ = (stbase) + sti;                                               \
            _Pragma("unroll") for (int c = 0; c < 2; ++c) {                               \
                U8 vb;                                                                    \
                vb.v = *(const f16x8*)(lbase + 16384 + (buf) * 8192 + st_ * 2048 + c * 1024); \
                acc[c] = __builtin_amdgcn_mfma_f32_32x32x16_f16(pa.v, vb.v, acc[c], 0, 0, 0); \
            }                                                                             \
        }                                                                                 \
        __builtin_amdgcn_s_setprio(0);                                                    \
    }

    // one 64-kv chunk: QK(g0), QK(g1) issued back-to-back, then SM/PV pipelined
#define CHUNK(buf, mo)                                                                    \
    {                                                                                     \
        f32x16 St0, St1;                                                                  \
        _Pragma("unroll") for (int g4 = 0; g4 < 4; ++g4) {                                \
            f32x4 m0 = *(const f32x4*)(mlb + (mo) + g4 * 32);                             \
            f32x4 m1 = *(const f32x4*)(mlb + (mo) + 128 + g4 * 32);                       \
            St0[g4 * 4 + 0] = m0[0]; St0[g4 * 4 + 1] = m0[1];                             \
            St0[g4 * 4 + 2] = m0[2]; St0[g4 * 4 + 3] = m0[3];                             \
            St1[g4 * 4 + 0] = m1[0]; St1[g4 * 4 + 1] = m1[1];                             \
            St1[g4 * 4 + 2] = m1[2]; St1[g4 * 4 + 3] = m1[3];                             \
        }                                                                                 \
        __builtin_amdgcn_s_setprio(1);                                                    \
        _Pragma("unroll") for (int ds_ = 0; ds_ < 4; ++ds_) {                             \
            f16x8 kf = *(const f16x8*)(lbase + (buf) * 8192 + ds_ * 2048);                \
            St0 = __builtin_amdgcn_mfma_f32_32x32x16_f16(kf, Qf[ds_], St0, 0, 0, 0);      \
        }                                                                                 \
        _Pragma("unroll") for (int ds_ = 0; ds_ < 4; ++ds_) {                             \
            f16x8 kf = *(const f16x8*)(lbase + (buf) * 8192 + ds_ * 2048 + 1024);         \
            St1 = __builtin_amdgcn_mfma_f32_32x32x16_f16(kf, Qf[ds_], St1, 0, 0, 0);      \
        }                                                                                 \
        __builtin_amdgcn_s_setprio(0);                                                    \
        SMPV(St0, buf, 0);                                                                \
        SMPV(St1, buf, 2);                                                                \
    }

    // stage mask (1 g2lds16 per wave) + first K/V chunk
    g2lds16((const char*)(mL + b * KVL_ + g * 1024 + wg * 256), (char*)&msk[g][wg * 256]);
    PREF(0, 0);
    asm volatile("s_waitcnt vmcnt(0)" ::: "memory");
    __syncthreads();

    for (int it = 0; it < 8; ++it) {
        PREF(1, 8192);
        CHUNK(0, 0);
        asm volatile("s_waitcnt vmcnt(0)" ::: "memory");
        __syncthreads();
        if (it < 7) PREF(0, 16384);
        CHUNK(1, 256);
        asm volatile("s_waitcnt vmcnt(0)" ::: "memory");
        __syncthreads();
        kgp0 += 16384; kgp1 += 16384; vgp0 += 16384; vgp1 += 16384;
        mlb += 512;
    }

    // ---- merge the two kv halves ----
    ssum += __shfl_xor(ssum, 32);
    char* exch = lds_buf;
    if (g == 1) {
        int base = (wg * 64 + l) * 128;
#pragma unroll
        for (int i = 0; i < 8; ++i) {
            int c = i >> 2, j0 = (i & 3) * 4;
            f32x4 vv = { acc[c][j0], acc[c][j0 + 1], acc[c][j0 + 2], acc[c][j0 + 3] };
            *(f32x4*)(exch + base + ((i * 16) ^ ((l & 7) << 4))) = vv;
        }
        if (hi == 0) msx[wg][l31] = make_float2(mrun, ssum);
    }
    __syncthreads();
    if (g == 0) {
        float2 mb = msx[wg][l31];
        float m = fmaxf(mrun, mb.x);
        float fA = exp2f(mrun - m), fB = exp2f(mb.x - m);
        float s = ssum * fA + mb.y * fB;
        float rinv = 1.0f / s;
        if (hi == 0) { fr2[wg][0][l31] = fA * rinv; fr2[wg][1][l31] = fB * rinv; }
        asm volatile("s_waitcnt lgkmcnt(0)" ::: "memory");
        int base = (wg * 64 + l) * 128;
#pragma unroll
        for (int c = 0; c < 2; ++c)
#pragma unroll
            for (int g4 = 0; g4 < 4; ++g4) {
                f32x4 gAv = *(const f32x4*)&fr2[wg][0][g4 * 8 + hi * 4];
                f32x4 gBv = *(const f32x4*)&fr2[wg][1][g4 * 8 + hi * 4];
                int i = c * 4 + g4;
                f32x4 pv = *(const f32x4*)(exch + base + ((i * 16) ^ ((l & 7) << 4)));
#pragma unroll
                for (int j = 0; j < 4; ++j) {
                    float o = acc[c][g4 * 4 + j] * gAv[j] + pv[j] * gBv[j];
                    int q = qt * 128 + wg * 32 + g4 * 8 + hi * 4 + j;
                    int dd = c * 32 + l31;
                    aout[((size_t)b * QL_ + q) * D_ + h * HD_ + dd] = (f16)o;
                }
            }
    }
#undef PREF
#undef SMPV
#undef CHUNK
}

extern "C" void kernel_launch(void* const* d_in, const int* in_sizes, int n_in,
                              void* d_out, int out_size, void* d_ws, size_t ws_size,
                              hipStream_t stream) {
    const float* hs = (const float*)d_in[0];
    const float* K  = (const float*)d_in[1];
    const float* V  = (const float*)d_in[2];
    const float* mask = (const float*)d_in[3];
    const float* Wq = (const float*)d_in[4];
    const float* Wo = (const float*)d_in[5];
    float* out = (float*)d_out;
    char* ws = (char*)d_ws;

    f16* hs_h = (f16*)(ws + 0);           //  8 MB
    f16* Wq_t = (f16*)(ws + 8388608);     //  2 MB
    f16* Wo_t = (f16*)(ws + 10485760);    //  2 MB
    f16* K_h  = (f16*)(ws + 12582912);    // 16 MB, chunk-major
    f16* V_t  = (f16*)(ws + 29360128);    // 16 MB, chunk-major transposed+permuted
    f16* q_h  = (f16*)(ws + 46137344);    //  8 MB (b,h,q,d), pre-scaled by log2e
    f16* a_o  = (f16*)(ws + 54525952);    //  8 MB (b,q,h*64+d)
    float* mL = (float*)(ws + 62914560);  // 32 KB (mask * log2e)

    preprocess<<<5640, 256, 0, stream>>>(hs, hs_h, K, K_h, Wq, Wq_t, Wo, Wo_t,
                                         V, V_t, mask, mL);
    gemm_tn<0><<<512, 512, 0, stream>>>(hs_h, Wq_t, (void*)q_h, 4096, 1024, 1024);
    attn_fused<<<512, 512, 0, stream>>>(q_h, K_h, V_t, mL, a_o);
    gemm_tn<1><<<512, 512, 0, stream>>>(a_o, Wo_t, (void*)out, 4096, 1024, 1024);
}

// Round 10
// 107.139 us; speedup vs baseline: 1.8174x; 1.0940x over previous
//
#include <hip/hip_runtime.h>
#include <hip/hip_bf16.h>
#include <hip/hip_fp16.h>
#include <stdint.h>

typedef _Float16 f16;
typedef _Float16 f16x2 __attribute__((ext_vector_type(2)));
typedef _Float16 f16x4 __attribute__((ext_vector_type(4)));
typedef _Float16 f16x8 __attribute__((ext_vector_type(8)));
typedef float f32x4 __attribute__((ext_vector_type(4)));
typedef float f32x16 __attribute__((ext_vector_type(16)));

#define B_ 4
#define QL_ 1024
#define D_ 1024
#define H_ 16
#define HD_ 64
#define KVL_ 2048
#define L2E 1.44269504088896f

// ---- async global->LDS, 16B per lane, wave-uniform LDS base ----
__device__ __forceinline__ void g2lds16(const void* g, void* l) {
    __builtin_amdgcn_global_load_lds(
        (const __attribute__((address_space(1))) uint32_t*)g,
        (__attribute__((address_space(3))) uint32_t*)l,
        16, 0, 0);
}

union U8 { uint32_t u[4]; f16x8 v; };

__device__ __forceinline__ uint32_t pkrtz(float a, float b) {
    auto t = __builtin_amdgcn_cvt_pkrtz(a, b);
    return __builtin_bit_cast(uint32_t, t);
}

// ---- merged preprocessing ----
// [0,1024):    hs f32->f16 (grid-stride)
// [1024,3072): K f32->f16 chunk-major: unit16B[(bh*32+ch)*512 + ds*128 + kv*2 + hi]
// [3072,3584): Wq/Wo transpose
// [3584,5632): V f32->f16 transposed+permuted chunk-major
// [5632,5640): mask * log2e
__global__ void preprocess(const float* __restrict__ hs, f16* __restrict__ hs_h,
                           const float* __restrict__ K, f16* __restrict__ K_h,
                           const float* __restrict__ Wq, f16* __restrict__ Wq_t,
                           const float* __restrict__ Wo, f16* __restrict__ Wo_t,
                           const float* __restrict__ V, f16* __restrict__ V_t,
                           const float* __restrict__ mask, float* __restrict__ mL) {
    __shared__ float t[64][65];
    int bid = blockIdx.x, tid = threadIdx.x;
    if (bid < 1024) {
        const int n4 = (B_ * QL_ * D_) / 4;
        for (int i = bid * 256 + tid; i < n4; i += 1024 * 256) {
            float4 v = ((const float4*)hs)[i];
            f16x4 o = { (f16)v.x, (f16)v.y, (f16)v.z, (f16)v.w };
            ((f16x4*)hs_h)[i] = o;
        }
    } else if (bid < 3072) {
        int t0 = (bid - 1024) * 256 + tid;
#pragma unroll
        for (int rep = 0; rep < 2; ++rep) {
            int U = t0 + rep * 524288;
            int bh = U >> 14, rem = U & 16383;
            int ch = rem >> 9, r2 = rem & 511;
            int dsl = r2 >> 7, r3 = r2 & 127;
            int kv = r3 >> 1, hi2 = r3 & 1;
            const float* sp = K + (((size_t)bh * KVL_ + ch * 64 + kv) * HD_ + dsl * 16 + hi2 * 8);
            f16x8 o;
#pragma unroll
            for (int j = 0; j < 8; ++j) o[j] = (f16)sp[j];
            *(f16x8*)(K_h + (size_t)U * 8) = o;
        }
    } else if (bid < 3584) {
        int wbid = bid - 3072;
        const float* src = wbid < 256 ? Wq : Wo;
        f16* dst = wbid < 256 ? Wq_t : Wo_t;
        int b2 = wbid & 255;
        int k0 = (b2 >> 4) << 6, n0 = (b2 & 15) << 6;
        int rr = tid >> 4, c4 = (tid & 15) << 2;
#pragma unroll
        for (int i = 0; i < 4; ++i) {
            int r = i * 16 + rr;
            float4 v = *(const float4*)(src + (size_t)(k0 + r) * 1024 + n0 + c4);
            t[r][c4 + 0] = v.x; t[r][c4 + 1] = v.y; t[r][c4 + 2] = v.z; t[r][c4 + 3] = v.w;
        }
        __syncthreads();
#pragma unroll
        for (int i = 0; i < 4; ++i) {
            int n = i * 16 + rr;
            f16x4 o;
#pragma unroll
            for (int j = 0; j < 4; ++j) o[j] = (f16)t[c4 + j][n];
            *(f16x4*)(dst + (size_t)(n0 + n) * 1024 + k0 + c4) = o;
        }
    } else if (bid < 5632) {
        int vb = bid - 3584;
        int bh = vb >> 5, ch = vb & 31;
        int rr = tid >> 4, c4 = (tid & 15) << 2;
#pragma unroll
        for (int i = 0; i < 4; ++i) {
            int r = i * 16 + rr;
            float4 v = *(const float4*)(V + ((size_t)bh * KVL_ + ch * 64 + r) * HD_ + c4);
            t[r][c4 + 0] = v.x; t[r][c4 + 1] = v.y; t[r][c4 + 2] = v.z; t[r][c4 + 3] = v.w;
        }
        __syncthreads();
#pragma unroll
        for (int rep = 0; rep < 2; ++rep) {
            int u = tid + rep * 256;
            int st = u >> 7, d = (u >> 1) & 63, hi2 = u & 1;
            f16x8 o;
#pragma unroll
            for (int j = 0; j < 8; ++j) {
                int kvl = st * 16 + (j & 3) + 8 * (j >> 2) + 4 * hi2;
                o[j] = (f16)t[kvl][d];
            }
            *(f16x8*)(V_t + ((size_t)(bh * 32 + ch) * 512 + u) * 8) = o;
        }
    } else {
        int i = (bid - 5632) * 256 + tid;
        if (i < (B_ * KVL_) / 4) {
            f32x4 v = ((const f32x4*)mask)[i];
            v *= L2E;
            ((f32x4*)mL)[i] = v;
        }
    }
}

// ---- GEMM: C[M][N] = A[M][K] * BT[N][K]^T, 2-phase dbuf, hoisted addresses ----
template <int EPI>
__global__ __launch_bounds__(512) void gemm_tn(
    const f16* __restrict__ A, const f16* __restrict__ BT, void* __restrict__ Cout,
    int M, int N, int K) {
    __shared__ char Alds[2][16384];
    __shared__ char Blds[2][8192];
    int d0 = blockIdx.x;
    int xcd = d0 & 7, sx = d0 >> 3;
    int bm = xcd * 4 + (sx & 3);
    int bn = sx >> 2;
    int tid = threadIdx.x, w = tid >> 6, l = tid & 63;
    int l15 = l & 15, lg = l >> 4;
    int wm = w >> 1, wn = w & 1;
    f32x4 acc[2][2] = {};

    const char* ag0; const char* ag1; int ao0, ao1;
    {
        int i0 = w, i1 = w + 8;
        int r0 = i0 * 8 + (l >> 3), r1 = i1 * 8 + (l >> 3);
        int c0 = (l & 7) ^ (r0 & 7), c1 = (l & 7) ^ (r1 & 7);
        ag0 = (const char*)A + ((size_t)(bm * 128 + r0) * K + c0 * 8) * 2;
        ag1 = (const char*)A + ((size_t)(bm * 128 + r1) * K + c1 * 8) * 2;
        ao0 = i0 * 1024; ao1 = i1 * 1024;
    }
    int rB = w * 8 + (l >> 3);
    int ccB = (l & 7) ^ (rB & 7);
    const char* bgp = (const char*)BT + ((size_t)(bn * 64 + rB) * K + ccB * 8) * 2;
    int boB = w * 1024;

    int aoff[2][2], boff[2][2];
#pragma unroll
    for (int ks = 0; ks < 2; ++ks)
#pragma unroll
        for (int m = 0; m < 2; ++m) {
            int ra = wm * 32 + m * 16 + l15;
            aoff[ks][m] = ra * 128 + ((ks * 64 + lg * 16) ^ ((ra & 7) << 4));
            int rb = wn * 32 + m * 16 + l15;
            boff[ks][m] = rb * 128 + ((ks * 64 + lg * 16) ^ ((rb & 7) << 4));
        }
    const char* Ab = &Alds[0][0];
    const char* Bb = &Blds[0][0];

#define GSTAGE(buf, soff)                                      \
    {                                                          \
        g2lds16(ag0 + (soff), &Alds[buf][ao0]);                \
        g2lds16(ag1 + (soff), &Alds[buf][ao1]);                \
        g2lds16(bgp + (soff), &Blds[buf][boB]);                \
    }
#define GCOMP(buf)                                                               \
    _Pragma("unroll") for (int ks = 0; ks < 2; ++ks) {                           \
        f16x8 af[2], bf[2];                                                      \
        af[0] = *(const f16x8*)(Ab + (buf) * 16384 + aoff[ks][0]);               \
        af[1] = *(const f16x8*)(Ab + (buf) * 16384 + aoff[ks][1]);               \
        bf[0] = *(const f16x8*)(Bb + (buf) * 8192 + boff[ks][0]);                \
        bf[1] = *(const f16x8*)(Bb + (buf) * 8192 + boff[ks][1]);                \
        _Pragma("unroll") for (int m = 0; m < 2; ++m)                            \
            _Pragma("unroll") for (int n = 0; n < 2; ++n)                        \
                acc[m][n] = __builtin_amdgcn_mfma_f32_16x16x32_f16(af[m], bf[n], acc[m][n], 0, 0, 0); \
    }

    GSTAGE(0, 0);
    asm volatile("s_waitcnt vmcnt(0)" ::: "memory");
    __syncthreads();

    for (int t2 = 0; t2 < 8; ++t2) {
        GSTAGE(1, 128);
        GCOMP(0);
        asm volatile("s_waitcnt vmcnt(0)" ::: "memory");
        __syncthreads();
        if (t2 < 7) GSTAGE(0, 256);
        GCOMP(1);
        asm volatile("s_waitcnt vmcnt(0)" ::: "memory");
        __syncthreads();
        ag0 += 256; ag1 += 256; bgp += 256;
    }

#pragma unroll
    for (int m = 0; m < 2; ++m)
#pragma unroll
        for (int n = 0; n < 2; ++n)
#pragma unroll
            for (int i = 0; i < 4; ++i) {
                int row = bm * 128 + wm * 32 + m * 16 + lg * 4 + i;
                int col = bn * 64 + wn * 32 + n * 16 + l15;
                if (EPI == 0) {
                    float v = acc[m][n][i] * L2E;
                    int b = row >> 10, q = row & 1023, h = col >> 6, d = col & 63;
                    ((f16*)Cout)[(((size_t)b * H_ + h) * QL_ + q) * HD_ + d] = (f16)v;
                } else {
                    ((float*)Cout)[(size_t)row * N + col] = acc[m][n][i];
                }
            }
#undef GSTAGE
#undef GCOMP
}

// ---- fused flash attention: single-St granules, raw v_exp, split ssum chains ----
// 512 thr (8 waves), 2 groups of 4 waves split kv; conflict-free 32B-row LDS;
// mask staged in LDS; common-path softmax has NO cross-lane ops.
__global__ __launch_bounds__(512, 4) void attn_fused(
    const f16* __restrict__ qh, const f16* __restrict__ kh, const f16* __restrict__ vt,
    const float* __restrict__ mL, f16* __restrict__ aout) {
    __shared__ char lds_buf[65536];  // per group: K dbuf 16K, V dbuf 16K
    __shared__ float msk[2][1024];   // per group: prescaled mask (4KB)
    __shared__ float frl[8][32];
    __shared__ float fr2[4][2][32];
    __shared__ float2 msx[4][32];

    int tid = threadIdx.x, w = tid >> 6, l = tid & 63;
    int l31 = l & 31, hi = l >> 5;
    int g = w >> 2, wg = w & 3;
    int d0 = blockIdx.x;
    int xcd = d0 & 7, sx = d0 >> 3;
    int bh = xcd * 8 + (sx & 7);
    int qt = sx >> 3;
    int b = bh >> 4, h = bh & 15;

    const char* lbase = lds_buf + g * 32768 + l31 * 32 + hi * 16;
    const char* mlb = (const char*)&msk[g][0] + hi * 16;

    f16x8 Qf[4];
    {
        const f16* qp = qh + ((size_t)bh * QL_ + qt * 128 + wg * 32 + l31) * HD_ + hi * 8;
#pragma unroll
        for (int ds_ = 0; ds_ < 4; ++ds_) Qf[ds_] = *(const f16x8*)(qp + ds_ * 16);
    }

    int i0 = wg * 2;
    const char* kgp0 = (const char*)kh + (((size_t)(bh * 32 + g * 16) * 512) + i0 * 64 + l) * 16;
    const char* kgp1 = kgp0 + 1024;
    const char* vgp0 = (const char*)vt + (((size_t)(bh * 32 + g * 16) * 512) + i0 * 64 + l) * 16;
    const char* vgp1 = vgp0 + 1024;
    char* kl0 = lds_buf + g * 32768 + i0 * 1024;
    char* kl1 = kl0 + 1024;
    char* vl0 = lds_buf + g * 32768 + 16384 + i0 * 1024;
    char* vl1 = vl0 + 1024;

#define PREF(buf, soff)                                  \
    {                                                    \
        g2lds16(kgp0 + (soff), kl0 + (buf) * 8192);      \
        g2lds16(kgp1 + (soff), kl1 + (buf) * 8192);      \
        g2lds16(vgp0 + (soff), vl0 + (buf) * 8192);      \
        g2lds16(vgp1 + (soff), vl1 + (buf) * 8192);      \
    }

    float mrun = -1e30f, ssA = 0.f, ssB = 0.f;
    f32x16 acc[2] = {};
    const f16x2 one2 = { (f16)1.0f, (f16)1.0f };

    // one 32-kv granule: C-init from LDS mask, QK, softmax (no cross-lane in
    // common path, raw v_exp_f32), pack, PV.
#define BODY(buf, kb, mo)                                                                 \
    {                                                                                     \
        f32x16 St;                                                                        \
        _Pragma("unroll") for (int g4 = 0; g4 < 4; ++g4) {                                \
            f32x4 mv = *(const f32x4*)(mlb + (mo) + (kb) * 128 + g4 * 32);                \
            St[g4 * 4 + 0] = mv[0]; St[g4 * 4 + 1] = mv[1];                               \
            St[g4 * 4 + 2] = mv[2]; St[g4 * 4 + 3] = mv[3];                               \
        }                                                                                 \
        __builtin_amdgcn_s_setprio(1);                                                    \
        _Pragma("unroll") for (int ds_ = 0; ds_ < 4; ++ds_) {                             \
            f16x8 kf = *(const f16x8*)(lbase + (buf) * 8192 + ds_ * 2048 + (kb) * 1024);  \
            St = __builtin_amdgcn_mfma_f32_32x32x16_f16(kf, Qf[ds_], St, 0, 0, 0);        \
        }                                                                                 \
        __builtin_amdgcn_s_setprio(0);                                                    \
        float a0 = fmaxf(fmaxf(St[0], St[1]), St[2]);                                     \
        float a1 = fmaxf(fmaxf(St[3], St[4]), St[5]);                                     \
        float a2 = fmaxf(fmaxf(St[6], St[7]), St[8]);                                     \
        float a3 = fmaxf(fmaxf(St[9], St[10]), St[11]);                                   \
        float a4 = fmaxf(fmaxf(St[12], St[13]), St[14]);                                  \
        float lmax = fmaxf(fmaxf(fmaxf(a0, a1), St[15]), fmaxf(a2, fmaxf(a3, a4)));       \
        if (__any(lmax > mrun + 12.f)) {                                                  \
            float pm = fmaxf(lmax, __shfl_xor(lmax, 32));                                 \
            float mn = fmaxf(mrun, pm);                                                   \
            float fac = __builtin_amdgcn_exp2f(mrun - mn);                                \
            mrun = mn; ssA *= fac; ssB *= fac;                                            \
            frl[w][l31] = fac;                                                            \
            asm volatile("s_waitcnt lgkmcnt(0)" ::: "memory");                            \
            _Pragma("unroll") for (int g4 = 0; g4 < 4; ++g4) {                            \
                f32x4 fv = *(const f32x4*)&frl[w][g4 * 8 + hi * 4];                       \
                _Pragma("unroll") for (int c = 0; c < 2; ++c)                             \
                    _Pragma("unroll") for (int j = 0; j < 4; ++j)                         \
                        acc[c][g4 * 4 + j] *= fv[j];                                      \
            }                                                                             \
        }                                                                                 \
        uint32_t pk[8];                                                                   \
        _Pragma("unroll") for (int i = 0; i < 8; ++i) {                                   \
            float p0 = __builtin_amdgcn_exp2f(St[2 * i] - mrun);                          \
            float p1 = __builtin_amdgcn_exp2f(St[2 * i + 1] - mrun);                      \
            pk[i] = pkrtz(p0, p1);                                                        \
        }                                                                                 \
        _Pragma("unroll") for (int i = 0; i < 4; ++i) {                                   \
            ssA = __builtin_amdgcn_fdot2(__builtin_bit_cast(f16x2, pk[2 * i]), one2, ssA, false);     \
            ssB = __builtin_amdgcn_fdot2(__builtin_bit_cast(f16x2, pk[2 * i + 1]), one2, ssB, false); \
        }                                                                                 \
        __builtin_amdgcn_s_setprio(1);                                                    \
        _Pragma("unroll") for (int sti = 0; sti < 2; ++sti) {                             \
            U8 pa;                                                                        \
            pa.u[0] = pk[sti * 4 + 0]; pa.u[1] = pk[sti * 4 + 1];                         \
            pa.u[2] = pk[sti * 4 + 2]; pa.u[3] = pk[sti * 4 + 3];                         \
            const int st_ = (kb) * 2 + sti;                                               \
            _Pragma("unroll") for (int c = 0; c < 2; ++c) {                               \
                U8 vb;                                                                    \
                vb.v = *(const f16x8*)(lbase + 16384 + (buf) * 8192 + st_ * 2048 + c * 1024); \
                acc[c] = __builtin_amdgcn_mfma_f32_32x32x16_f16(pa.v, vb.v, acc[c], 0, 0, 0); \
            }                                                                             \
        }                                                                                 \
        __builtin_amdgcn_s_setprio(0);                                                    \
    }

    // stage mask (1 g2lds16 per wave) + first K/V chunk
    g2lds16((const char*)(mL + b * KVL_ + g * 1024 + wg * 256), (char*)&msk[g][wg * 256]);
    PREF(0, 0);
    asm volatile("s_waitcnt vmcnt(0)" ::: "memory");
    __syncthreads();

    for (int it = 0; it < 8; ++it) {
        PREF(1, 8192);
        BODY(0, 0, 0);
        BODY(0, 1, 0);
        asm volatile("s_waitcnt vmcnt(0)" ::: "memory");
        __syncthreads();
        if (it < 7) PREF(0, 16384);
        BODY(1, 0, 256);
        BODY(1, 1, 256);
        asm volatile("s_waitcnt vmcnt(0)" ::: "memory");
        __syncthreads();
        kgp0 += 16384; kgp1 += 16384; vgp0 += 16384; vgp1 += 16384;
        mlb += 512;
    }

    // ---- merge the two kv halves ----
    float ssum = ssA + ssB;
    ssum += __shfl_xor(ssum, 32);
    char* exch = lds_buf;
    if (g == 1) {
        int base = (wg * 64 + l) * 128;
#pragma unroll
        for (int i = 0; i < 8; ++i) {
            int c = i >> 2, j0 = (i & 3) * 4;
            f32x4 vv = { acc[c][j0], acc[c][j0 + 1], acc[c][j0 + 2], acc[c][j0 + 3] };
            *(f32x4*)(exch + base + ((i * 16) ^ ((l & 7) << 4))) = vv;
        }
        if (hi == 0) msx[wg][l31] = make_float2(mrun, ssum);
    }
    __syncthreads();
    if (g == 0) {
        float2 mb = msx[wg][l31];
        float m = fmaxf(mrun, mb.x);
        float fA = __builtin_amdgcn_exp2f(mrun - m);
        float fB = __builtin_amdgcn_exp2f(mb.x - m);
        float s = ssum * fA + mb.y * fB;
        float rinv = 1.0f / s;
        if (hi == 0) { fr2[wg][0][l31] = fA * rinv; fr2[wg][1][l31] = fB * rinv; }
        asm volatile("s_waitcnt lgkmcnt(0)" ::: "memory");
        int base = (wg * 64 + l) * 128;
#pragma unroll
        for (int c = 0; c < 2; ++c)
#pragma unroll
            for (int g4 = 0; g4 < 4; ++g4) {
                f32x4 gAv = *(const f32x4*)&fr2[wg][0][g4 * 8 + hi * 4];
                f32x4 gBv = *(const f32x4*)&fr2[wg][1][g4 * 8 + hi * 4];
                int i = c * 4 + g4;
                f32x4 pv = *(const f32x4*)(exch + base + ((i * 16) ^ ((l & 7) << 4)));
#pragma unroll
                for (int j = 0; j < 4; ++j) {
                    float o = acc[c][g4 * 4 + j] * gAv[j] + pv[j] * gBv[j];
                    int q = qt * 128 + wg * 32 + g4 * 8 + hi * 4 + j;
                    int dd = c * 32 + l31;
                    aout[((size_t)b * QL_ + q) * D_ + h * HD_ + dd] = (f16)o;
                }
            }
    }
#undef PREF
#undef BODY
}

extern "C" void kernel_launch(void* const* d_in, const int* in_sizes, int n_in,
                              void* d_out, int out_size, void* d_ws, size_t ws_size,
                              hipStream_t stream) {
    const float* hs = (const float*)d_in[0];
    const float* K  = (const float*)d_in[1];
    const float* V  = (const float*)d_in[2];
    const float* mask = (const float*)d_in[3];
    const float* Wq = (const float*)d_in[4];
    const float* Wo = (const float*)d_in[5];
    float* out = (float*)d_out;
    char* ws = (char*)d_ws;

    f16* hs_h = (f16*)(ws + 0);           //  8 MB
    f16* Wq_t = (f16*)(ws + 8388608);     //  2 MB
    f16* Wo_t = (f16*)(ws + 10485760);    //  2 MB
    f16* K_h  = (f16*)(ws + 12582912);    // 16 MB, chunk-major
    f16* V_t  = (f16*)(ws + 29360128);    // 16 MB, chunk-major transposed+permuted
    f16* q_h  = (f16*)(ws + 46137344);    //  8 MB (b,h,q,d), pre-scaled by log2e
    f16* a_o  = (f16*)(ws + 54525952);    //  8 MB (b,q,h*64+d)
    float* mL = (float*)(ws + 62914560);  // 32 KB (mask * log2e)

    preprocess<<<5640, 256, 0, stream>>>(hs, hs_h, K, K_h, Wq, Wq_t, Wo, Wo_t,
                                         V, V_t, mask, mL);
    gemm_tn<0><<<512, 512, 0, stream>>>(hs_h, Wq_t, (void*)q_h, 4096, 1024, 1024);
    attn_fused<<<512, 512, 0, stream>>>(q_h, K_h, V_t, mL, a_o);
    gemm_tn<1><<<512, 512, 0, stream>>>(a_o, Wo_t, (void*)out, 4096, 1024, 1024);
}

// Round 11
// 101.585 us; speedup vs baseline: 1.9168x; 1.0547x over previous
//
#include <hip/hip_runtime.h>
#include <hip/hip_bf16.h>
#include <hip/hip_fp16.h>
#include <stdint.h>

typedef _Float16 f16;
typedef _Float16 f16x2 __attribute__((ext_vector_type(2)));
typedef _Float16 f16x4 __attribute__((ext_vector_type(4)));
typedef _Float16 f16x8 __attribute__((ext_vector_type(8)));
typedef float f32x4 __attribute__((ext_vector_type(4)));
typedef float f32x16 __attribute__((ext_vector_type(16)));

#define B_ 4
#define QL_ 1024
#define D_ 1024
#define H_ 16
#define HD_ 64
#define KVL_ 2048
#define L2E 1.44269504088896f

// ---- async global->LDS, 16B per lane, wave-uniform LDS base ----
__device__ __forceinline__ void g2lds16(const void* g, void* l) {
    __builtin_amdgcn_global_load_lds(
        (const __attribute__((address_space(1))) uint32_t*)g,
        (__attribute__((address_space(3))) uint32_t*)l,
        16, 0, 0);
}

union U8 { uint32_t u[4]; f16x8 v; };

__device__ __forceinline__ uint32_t pkrtz(float a, float b) {
    auto t = __builtin_amdgcn_cvt_pkrtz(a, b);
    return __builtin_bit_cast(uint32_t, t);
}

// ---- slim preprocessing: only what gemm0 needs (hs convert + Wq transpose) ----
// [0,1024): hs f32->f16 (grid-stride); [1024,1280): Wq transpose 64x64 tiles
__global__ void preprocess_slim(const float* __restrict__ hs, f16* __restrict__ hs_h,
                                const float* __restrict__ Wq, f16* __restrict__ Wq_t) {
    __shared__ float t[64][65];
    int bid = blockIdx.x, tid = threadIdx.x;
    if (bid < 1024) {
        const int n4 = (B_ * QL_ * D_) / 4;
        for (int i = bid * 256 + tid; i < n4; i += 1024 * 256) {
            float4 v = ((const float4*)hs)[i];
            f16x4 o = { (f16)v.x, (f16)v.y, (f16)v.z, (f16)v.w };
            ((f16x4*)hs_h)[i] = o;
        }
    } else {
        int b2 = bid - 1024;
        int k0 = (b2 >> 4) << 6, n0 = (b2 & 15) << 6;
        int rr = tid >> 4, c4 = (tid & 15) << 2;
#pragma unroll
        for (int i = 0; i < 4; ++i) {
            int r = i * 16 + rr;
            float4 v = *(const float4*)(Wq + (size_t)(k0 + r) * 1024 + n0 + c4);
            t[r][c4 + 0] = v.x; t[r][c4 + 1] = v.y; t[r][c4 + 2] = v.z; t[r][c4 + 3] = v.w;
        }
        __syncthreads();
#pragma unroll
        for (int i = 0; i < 4; ++i) {
            int n = i * 16 + rr;
            f16x4 o;
#pragma unroll
            for (int j = 0; j < 4; ++j) o[j] = (f16)t[c4 + j][n];
            *(f16x4*)(Wq_t + (size_t)(n0 + n) * 1024 + k0 + c4) = o;
        }
    }
}

// ---- fused: Q-projection GEMM (blocks [0,512)) + K/V/Wo/mask prep (rest) ----
// [512,1536):  K f32->f16 chunk-major: unit16B[(bh*32+ch)*512 + ds*128 + kv*2 + hi]
// [1536,2560): V f32->f16 transposed+permuted chunk-major (2 tiles/block)
// [2560,2688): Wo transpose (2 tiles/block)
// [2688,2692): mask * log2e
__global__ __launch_bounds__(512) void gemm0_fused(
    const f16* __restrict__ A, const f16* __restrict__ BT, f16* __restrict__ q_h,
    const float* __restrict__ K, f16* __restrict__ K_h,
    const float* __restrict__ V, f16* __restrict__ V_t,
    const float* __restrict__ Wo, f16* __restrict__ Wo_t,
    const float* __restrict__ mask, float* __restrict__ mL) {
    __shared__ char shmem[49152];
    int bid = blockIdx.x, tid = threadIdx.x;

    if (bid < 512) {
        // ---------------- GEMM path: M=4096, N=1024, K=1024 ----------------
        char* Alds = shmem;            // [2][16384]
        char* Blds = shmem + 32768;    // [2][8192]
        int xcd = bid & 7, sx = bid >> 3;
        int bm = xcd * 4 + (sx & 3);
        int bn = sx >> 2;
        int w = tid >> 6, l = tid & 63;
        int l15 = l & 15, lg = l >> 4;
        int wm = w >> 1, wn = w & 1;
        f32x4 acc[2][2] = {};

        const char* ag0; const char* ag1; int ao0, ao1;
        {
            int i0 = w, i1 = w + 8;
            int r0 = i0 * 8 + (l >> 3), r1 = i1 * 8 + (l >> 3);
            int c0 = (l & 7) ^ (r0 & 7), c1 = (l & 7) ^ (r1 & 7);
            ag0 = (const char*)A + ((size_t)(bm * 128 + r0) * 1024 + c0 * 8) * 2;
            ag1 = (const char*)A + ((size_t)(bm * 128 + r1) * 1024 + c1 * 8) * 2;
            ao0 = i0 * 1024; ao1 = i1 * 1024;
        }
        int rB = w * 8 + (l >> 3);
        int ccB = (l & 7) ^ (rB & 7);
        const char* bgp = (const char*)BT + ((size_t)(bn * 64 + rB) * 1024 + ccB * 8) * 2;
        int boB = w * 1024;

        int aoff[2][2], boff[2][2];
#pragma unroll
        for (int ks = 0; ks < 2; ++ks)
#pragma unroll
            for (int m = 0; m < 2; ++m) {
                int ra = wm * 32 + m * 16 + l15;
                aoff[ks][m] = ra * 128 + ((ks * 64 + lg * 16) ^ ((ra & 7) << 4));
                int rb = wn * 32 + m * 16 + l15;
                boff[ks][m] = rb * 128 + ((ks * 64 + lg * 16) ^ ((rb & 7) << 4));
            }

#define GSTAGE(buf, soff)                                          \
    {                                                              \
        g2lds16(ag0 + (soff), Alds + (buf) * 16384 + ao0);         \
        g2lds16(ag1 + (soff), Alds + (buf) * 16384 + ao1);         \
        g2lds16(bgp + (soff), Blds + (buf) * 8192 + boB);          \
    }
#define GCOMP(buf)                                                               \
    _Pragma("unroll") for (int ks = 0; ks < 2; ++ks) {                           \
        f16x8 af[2], bf[2];                                                      \
        af[0] = *(const f16x8*)(Alds + (buf) * 16384 + aoff[ks][0]);             \
        af[1] = *(const f16x8*)(Alds + (buf) * 16384 + aoff[ks][1]);             \
        bf[0] = *(const f16x8*)(Blds + (buf) * 8192 + boff[ks][0]);              \
        bf[1] = *(const f16x8*)(Blds + (buf) * 8192 + boff[ks][1]);              \
        _Pragma("unroll") for (int m = 0; m < 2; ++m)                            \
            _Pragma("unroll") for (int n = 0; n < 2; ++n)                        \
                acc[m][n] = __builtin_amdgcn_mfma_f32_16x16x32_f16(af[m], bf[n], acc[m][n], 0, 0, 0); \
    }

        GSTAGE(0, 0);
        asm volatile("s_waitcnt vmcnt(0)" ::: "memory");
        __syncthreads();
        for (int t2 = 0; t2 < 8; ++t2) {
            GSTAGE(1, 128);
            GCOMP(0);
            asm volatile("s_waitcnt vmcnt(0)" ::: "memory");
            __syncthreads();
            if (t2 < 7) GSTAGE(0, 256);
            GCOMP(1);
            asm volatile("s_waitcnt vmcnt(0)" ::: "memory");
            __syncthreads();
            ag0 += 256; ag1 += 256; bgp += 256;
        }
#pragma unroll
        for (int m = 0; m < 2; ++m)
#pragma unroll
            for (int n = 0; n < 2; ++n)
#pragma unroll
                for (int i = 0; i < 4; ++i) {
                    int row = bm * 128 + wm * 32 + m * 16 + lg * 4 + i;
                    int col = bn * 64 + wn * 32 + n * 16 + l15;
                    float v = acc[m][n][i] * L2E;
                    int b = row >> 10, q = row & 1023, h = col >> 6, d = col & 63;
                    q_h[(((size_t)b * H_ + h) * QL_ + q) * HD_ + d] = (f16)v;
                }
#undef GSTAGE
#undef GCOMP
    } else if (bid < 1536) {
        // ---------------- K prep ----------------
        int t0 = (bid - 512) * 512 + tid;
#pragma unroll
        for (int rep = 0; rep < 2; ++rep) {
            int U = t0 + rep * 524288;
            int bh = U >> 14, rem = U & 16383;
            int ch = rem >> 9, r2 = rem & 511;
            int dsl = r2 >> 7, r3 = r2 & 127;
            int kv = r3 >> 1, hi2 = r3 & 1;
            const float* sp = K + (((size_t)bh * KVL_ + ch * 64 + kv) * HD_ + dsl * 16 + hi2 * 8);
            f16x8 o;
#pragma unroll
            for (int j = 0; j < 8; ++j) o[j] = (f16)sp[j];
            *(f16x8*)(K_h + (size_t)U * 8) = o;
        }
    } else if (bid < 2560) {
        // ---------------- V prep (2 tiles/block) ----------------
        int sub = tid >> 8, st2 = tid & 255;
        int vb = (bid - 1536) * 2 + sub;      // 0..2047
        int bh = vb >> 5, ch = vb & 31;
        float (*tt)[65] = (float(*)[65])(shmem + sub * 16640);
        int rr = st2 >> 4, c4 = (st2 & 15) << 2;
#pragma unroll
        for (int i = 0; i < 4; ++i) {
            int r = i * 16 + rr;
            float4 v = *(const float4*)(V + ((size_t)bh * KVL_ + ch * 64 + r) * HD_ + c4);
            tt[r][c4 + 0] = v.x; tt[r][c4 + 1] = v.y; tt[r][c4 + 2] = v.z; tt[r][c4 + 3] = v.w;
        }
        __syncthreads();
#pragma unroll
        for (int rep = 0; rep < 2; ++rep) {
            int u = st2 + rep * 256;
            int st = u >> 7, d = (u >> 1) & 63, hi2 = u & 1;
            f16x8 o;
#pragma unroll
            for (int j = 0; j < 8; ++j) {
                int kvl = st * 16 + (j & 3) + 8 * (j >> 2) + 4 * hi2;
                o[j] = (f16)tt[kvl][d];
            }
            *(f16x8*)(V_t + ((size_t)(bh * 32 + ch) * 512 + u) * 8) = o;
        }
    } else if (bid < 2688) {
        // ---------------- Wo transpose (2 tiles/block) ----------------
        int sub = tid >> 8, st2 = tid & 255;
        int b2 = (bid - 2560) * 2 + sub;      // 0..255
        float (*tt)[65] = (float(*)[65])(shmem + sub * 16640);
        int k0 = (b2 >> 4) << 6, n0 = (b2 & 15) << 6;
        int rr = st2 >> 4, c4 = (st2 & 15) << 2;
#pragma unroll
        for (int i = 0; i < 4; ++i) {
            int r = i * 16 + rr;
            float4 v = *(const float4*)(Wo + (size_t)(k0 + r) * 1024 + n0 + c4);
            tt[r][c4 + 0] = v.x; tt[r][c4 + 1] = v.y; tt[r][c4 + 2] = v.z; tt[r][c4 + 3] = v.w;
        }
        __syncthreads();
#pragma unroll
        for (int i = 0; i < 4; ++i) {
            int n = i * 16 + rr;
            f16x4 o;
#pragma unroll
            for (int j = 0; j < 4; ++j) o[j] = (f16)tt[c4 + j][n];
            *(f16x4*)(Wo_t + (size_t)(n0 + n) * 1024 + k0 + c4) = o;
        }
    } else {
        // ---------------- mask * log2e ----------------
        int i = (bid - 2688) * 512 + tid;
        if (i < (B_ * KVL_) / 4) {
            f32x4 v = ((const f32x4*)mask)[i];
            v *= L2E;
            ((f32x4*)mL)[i] = v;
        }
    }
}

// ---- GEMM1: C[M][N] = A[M][K] * BT[N][K]^T, fp32 out ----
__global__ __launch_bounds__(512) void gemm_tn1(
    const f16* __restrict__ A, const f16* __restrict__ BT, float* __restrict__ Cout) {
    __shared__ char Alds[2][16384];
    __shared__ char Blds[2][8192];
    int d0 = blockIdx.x;
    int xcd = d0 & 7, sx = d0 >> 3;
    int bm = xcd * 4 + (sx & 3);
    int bn = sx >> 2;
    int tid = threadIdx.x, w = tid >> 6, l = tid & 63;
    int l15 = l & 15, lg = l >> 4;
    int wm = w >> 1, wn = w & 1;
    f32x4 acc[2][2] = {};

    const char* ag0; const char* ag1; int ao0, ao1;
    {
        int i0 = w, i1 = w + 8;
        int r0 = i0 * 8 + (l >> 3), r1 = i1 * 8 + (l >> 3);
        int c0 = (l & 7) ^ (r0 & 7), c1 = (l & 7) ^ (r1 & 7);
        ag0 = (const char*)A + ((size_t)(bm * 128 + r0) * 1024 + c0 * 8) * 2;
        ag1 = (const char*)A + ((size_t)(bm * 128 + r1) * 1024 + c1 * 8) * 2;
        ao0 = i0 * 1024; ao1 = i1 * 1024;
    }
    int rB = w * 8 + (l >> 3);
    int ccB = (l & 7) ^ (rB & 7);
    const char* bgp = (const char*)BT + ((size_t)(bn * 64 + rB) * 1024 + ccB * 8) * 2;
    int boB = w * 1024;

    int aoff[2][2], boff[2][2];
#pragma unroll
    for (int ks = 0; ks < 2; ++ks)
#pragma unroll
        for (int m = 0; m < 2; ++m) {
            int ra = wm * 32 + m * 16 + l15;
            aoff[ks][m] = ra * 128 + ((ks * 64 + lg * 16) ^ ((ra & 7) << 4));
            int rb = wn * 32 + m * 16 + l15;
            boff[ks][m] = rb * 128 + ((ks * 64 + lg * 16) ^ ((rb & 7) << 4));
        }
    const char* Ab = &Alds[0][0];
    const char* Bb = &Blds[0][0];

#define GSTAGE(buf, soff)                                      \
    {                                                          \
        g2lds16(ag0 + (soff), &Alds[buf][ao0]);                \
        g2lds16(ag1 + (soff), &Alds[buf][ao1]);                \
        g2lds16(bgp + (soff), &Blds[buf][boB]);                \
    }
#define GCOMP(buf)                                                               \
    _Pragma("unroll") for (int ks = 0; ks < 2; ++ks) {                           \
        f16x8 af[2], bf[2];                                                      \
        af[0] = *(const f16x8*)(Ab + (buf) * 16384 + aoff[ks][0]);               \
        af[1] = *(const f16x8*)(Ab + (buf) * 16384 + aoff[ks][1]);               \
        bf[0] = *(const f16x8*)(Bb + (buf) * 8192 + boff[ks][0]);                \
        bf[1] = *(const f16x8*)(Bb + (buf) * 8192 + boff[ks][1]);                \
        _Pragma("unroll") for (int m = 0; m < 2; ++m)                            \
            _Pragma("unroll") for (int n = 0; n < 2; ++n)                        \
                acc[m][n] = __builtin_amdgcn_mfma_f32_16x16x32_f16(af[m], bf[n], acc[m][n], 0, 0, 0); \
    }

    GSTAGE(0, 0);
    asm volatile("s_waitcnt vmcnt(0)" ::: "memory");
    __syncthreads();
    for (int t2 = 0; t2 < 8; ++t2) {
        GSTAGE(1, 128);
        GCOMP(0);
        asm volatile("s_waitcnt vmcnt(0)" ::: "memory");
        __syncthreads();
        if (t2 < 7) GSTAGE(0, 256);
        GCOMP(1);
        asm volatile("s_waitcnt vmcnt(0)" ::: "memory");
        __syncthreads();
        ag0 += 256; ag1 += 256; bgp += 256;
    }
#pragma unroll
    for (int m = 0; m < 2; ++m)
#pragma unroll
        for (int n = 0; n < 2; ++n)
#pragma unroll
            for (int i = 0; i < 4; ++i) {
                int row = bm * 128 + wm * 32 + m * 16 + lg * 4 + i;
                int col = bn * 64 + wn * 32 + n * 16 + l15;
                Cout[(size_t)row * 1024 + col] = acc[m][n][i];
            }
#undef GSTAGE
#undef GCOMP
}

// ---- fused flash attention: mask from global (L1-hot), LDS reads 16/chunk/wave ----
// 512 thr (8 waves), 2 groups of 4 waves split kv; conflict-free 32B-row LDS.
__global__ __launch_bounds__(512, 4) void attn_fused(
    const f16* __restrict__ qh, const f16* __restrict__ kh, const f16* __restrict__ vt,
    const float* __restrict__ mL, f16* __restrict__ aout) {
    __shared__ char lds_buf[65536];  // per group: K dbuf 16K, V dbuf 16K
    __shared__ float frl[8][32];
    __shared__ float fr2[4][2][32];
    __shared__ float2 msx[4][32];

    int tid = threadIdx.x, w = tid >> 6, l = tid & 63;
    int l31 = l & 31, hi = l >> 5;
    int g = w >> 2, wg = w & 3;
    int d0 = blockIdx.x;
    int xcd = d0 & 7, sx = d0 >> 3;
    int bh = xcd * 8 + (sx & 7);
    int qt = sx >> 3;
    int b = bh >> 4, h = bh & 15;

    const char* lbase = lds_buf + g * 32768 + l31 * 32 + hi * 16;

    f16x8 Qf[4];
    {
        const f16* qp = qh + ((size_t)bh * QL_ + qt * 128 + wg * 32 + l31) * HD_ + hi * 8;
#pragma unroll
        for (int ds_ = 0; ds_ < 4; ++ds_) Qf[ds_] = *(const f16x8*)(qp + ds_ * 16);
    }

    int i0 = wg * 2;
    const char* kgp0 = (const char*)kh + (((size_t)(bh * 32 + g * 16) * 512) + i0 * 64 + l) * 16;
    const char* kgp1 = kgp0 + 1024;
    const char* vgp0 = (const char*)vt + (((size_t)(bh * 32 + g * 16) * 512) + i0 * 64 + l) * 16;
    const char* vgp1 = vgp0 + 1024;
    char* kl0 = lds_buf + g * 32768 + i0 * 1024;
    char* kl1 = kl0 + 1024;
    char* vl0 = lds_buf + g * 32768 + 16384 + i0 * 1024;
    char* vl1 = vl0 + 1024;

#define PREF(buf, soff)                                  \
    {                                                    \
        g2lds16(kgp0 + (soff), kl0 + (buf) * 8192);      \
        g2lds16(kgp1 + (soff), kl1 + (buf) * 8192);      \
        g2lds16(vgp0 + (soff), vl0 + (buf) * 8192);      \
        g2lds16(vgp1 + (soff), vl1 + (buf) * 8192);      \
    }

    float mrun = -1e30f, ssA = 0.f, ssB = 0.f;
    f32x16 acc[2] = {};
    const float* mp = mL + b * KVL_ + g * 1024 + hi * 4;   // per-granule C-init source
    const f16x2 one2 = { (f16)1.0f, (f16)1.0f };

    // one 32-kv granule: C-init from global mask regs, QK, softmax, pack, PV.
#define BODY(buf, kb, mof)                                                                \
    {                                                                                     \
        const float* mq = mp + (mof) + (kb) * 32;                                         \
        f32x4 mv0 = *(const f32x4*)(mq);                                                  \
        f32x4 mv1 = *(const f32x4*)(mq + 8);                                              \
        f32x4 mv2 = *(const f32x4*)(mq + 16);                                             \
        f32x4 mv3 = *(const f32x4*)(mq + 24);                                             \
        f32x16 St;                                                                        \
        _Pragma("unroll") for (int j = 0; j < 4; ++j) {                                   \
            St[j] = mv0[j]; St[4 + j] = mv1[j]; St[8 + j] = mv2[j]; St[12 + j] = mv3[j];  \
        }                                                                                 \
        __builtin_amdgcn_s_setprio(1);                                                    \
        _Pragma("unroll") for (int ds_ = 0; ds_ < 4; ++ds_) {                             \
            f16x8 kf = *(const f16x8*)(lbase + (buf) * 8192 + ds_ * 2048 + (kb) * 1024);  \
            St = __builtin_amdgcn_mfma_f32_32x32x16_f16(kf, Qf[ds_], St, 0, 0, 0);        \
        }                                                                                 \
        __builtin_amdgcn_s_setprio(0);                                                    \
        float a0 = fmaxf(fmaxf(St[0], St[1]), St[2]);                                     \
        float a1 = fmaxf(fmaxf(St[3], St[4]), St[5]);                                     \
        float a2 = fmaxf(fmaxf(St[6], St[7]), St[8]);                                     \
        float a3 = fmaxf(fmaxf(St[9], St[10]), St[11]);                                   \
        float a4 = fmaxf(fmaxf(St[12], St[13]), St[14]);                                  \
        float lmax = fmaxf(fmaxf(fmaxf(a0, a1), St[15]), fmaxf(a2, fmaxf(a3, a4)));       \
        if (__any(lmax > mrun + 12.f)) {                                                  \
            float pm = fmaxf(lmax, __shfl_xor(lmax, 32));                                 \
            float mn = fmaxf(mrun, pm);                                                   \
            float fac = __builtin_amdgcn_exp2f(mrun - mn);                                \
            mrun = mn; ssA *= fac; ssB *= fac;                                            \
            frl[w][l31] = fac;                                                            \
            asm volatile("s_waitcnt lgkmcnt(0)" ::: "memory");                            \
            _Pragma("unroll") for (int g4 = 0; g4 < 4; ++g4) {                            \
                f32x4 fv = *(const f32x4*)&frl[w][g4 * 8 + hi * 4];                       \
                _Pragma("unroll") for (int c = 0; c < 2; ++c)                             \
                    _Pragma("unroll") for (int j = 0; j < 4; ++j)                         \
                        acc[c][g4 * 4 + j] *= fv[j];                                      \
            }                                                                             \
        }                                                                                 \
        uint32_t pk[8];                                                                   \
        _Pragma("unroll") for (int i = 0; i < 8; ++i) {                                   \
            float p0 = __builtin_amdgcn_exp2f(St[2 * i] - mrun);                          \
            float p1 = __builtin_amdgcn_exp2f(St[2 * i + 1] - mrun);                      \
            pk[i] = pkrtz(p0, p1);                                                        \
        }                                                                                 \
        _Pragma("unroll") for (int i = 0; i < 4; ++i) {                                   \
            ssA = __builtin_amdgcn_fdot2(__builtin_bit_cast(f16x2, pk[2 * i]), one2, ssA, false);     \
            ssB = __builtin_amdgcn_fdot2(__builtin_bit_cast(f16x2, pk[2 * i + 1]), one2, ssB, false); \
        }                                                                                 \
        __builtin_amdgcn_s_setprio(1);                                                    \
        _Pragma("unroll") for (int sti = 0; sti < 2; ++sti) {                             \
            U8 pa;                                                                        \
            pa.u[0] = pk[sti * 4 + 0]; pa.u[1] = pk[sti * 4 + 1];                         \
            pa.u[2] = pk[sti * 4 + 2]; pa.u[3] = pk[sti * 4 + 3];                         \
            const int st_ = (kb) * 2 + sti;                                               \
            _Pragma("unroll") for (int c = 0; c < 2; ++c) {                               \
                U8 vb;                                                                    \
                vb.v = *(const f16x8*)(lbase + 16384 + (buf) * 8192 + st_ * 2048 + c * 1024); \
                acc[c] = __builtin_amdgcn_mfma_f32_32x32x16_f16(pa.v, vb.v, acc[c], 0, 0, 0); \
            }                                                                             \
        }                                                                                 \
        __builtin_amdgcn_s_setprio(0);                                                    \
    }

    PREF(0, 0);
    asm volatile("s_waitcnt vmcnt(0)" ::: "memory");
    __syncthreads();

    for (int it = 0; it < 8; ++it) {
        PREF(1, 8192);
        BODY(0, 0, 0);
        BODY(0, 1, 0);
        asm volatile("s_waitcnt vmcnt(0)" ::: "memory");
        __syncthreads();
        if (it < 7) PREF(0, 16384);
        BODY(1, 0, 64);
        BODY(1, 1, 64);
        asm volatile("s_waitcnt vmcnt(0)" ::: "memory");
        __syncthreads();
        kgp0 += 16384; kgp1 += 16384; vgp0 += 16384; vgp1 += 16384;
        mp += 128;
    }

    // ---- merge the two kv halves ----
    float ssum = ssA + ssB;
    ssum += __shfl_xor(ssum, 32);
    char* exch = lds_buf;
    if (g == 1) {
        int base = (wg * 64 + l) * 128;
#pragma unroll
        for (int i = 0; i < 8; ++i) {
            int c = i >> 2, j0 = (i & 3) * 4;
            f32x4 vv = { acc[c][j0], acc[c][j0 + 1], acc[c][j0 + 2], acc[c][j0 + 3] };
            *(f32x4*)(exch + base + ((i * 16) ^ ((l & 7) << 4))) = vv;
        }
        if (hi == 0) msx[wg][l31] = make_float2(mrun, ssum);
    }
    __syncthreads();
    if (g == 0) {
        float2 mb = msx[wg][l31];
        float m = fmaxf(mrun, mb.x);
        float fA = __builtin_amdgcn_exp2f(mrun - m);
        float fB = __builtin_amdgcn_exp2f(mb.x - m);
        float s = ssum * fA + mb.y * fB;
        float rinv = 1.0f / s;
        if (hi == 0) { fr2[wg][0][l31] = fA * rinv; fr2[wg][1][l31] = fB * rinv; }
        asm volatile("s_waitcnt lgkmcnt(0)" ::: "memory");
        int base = (wg * 64 + l) * 128;
#pragma unroll
        for (int c = 0; c < 2; ++c)
#pragma unroll
            for (int g4 = 0; g4 < 4; ++g4) {
                f32x4 gAv = *(const f32x4*)&fr2[wg][0][g4 * 8 + hi * 4];
                f32x4 gBv = *(const f32x4*)&fr2[wg][1][g4 * 8 + hi * 4];
                int i = c * 4 + g4;
                f32x4 pv = *(const f32x4*)(exch + base + ((i * 16) ^ ((l & 7) << 4)));
#pragma unroll
                for (int j = 0; j < 4; ++j) {
                    float o = acc[c][g4 * 4 + j] * gAv[j] + pv[j] * gBv[j];
                    int q = qt * 128 + wg * 32 + g4 * 8 + hi * 4 + j;
                    int dd = c * 32 + l31;
                    aout[((size_t)b * QL_ + q) * D_ + h * HD_ + dd] = (f16)o;
                }
            }
    }
#undef PREF
#undef BODY
}

extern "C" void kernel_launch(void* const* d_in, const int* in_sizes, int n_in,
                              void* d_out, int out_size, void* d_ws, size_t ws_size,
                              hipStream_t stream) {
    const float* hs = (const float*)d_in[0];
    const float* K  = (const float*)d_in[1];
    const float* V  = (const float*)d_in[2];
    const float* mask = (const float*)d_in[3];
    const float* Wq = (const float*)d_in[4];
    const float* Wo = (const float*)d_in[5];
    float* out = (float*)d_out;
    char* ws = (char*)d_ws;

    f16* hs_h = (f16*)(ws + 0);           //  8 MB
    f16* Wq_t = (f16*)(ws + 8388608);     //  2 MB
    f16* Wo_t = (f16*)(ws + 10485760);    //  2 MB
    f16* K_h  = (f16*)(ws + 12582912);    // 16 MB, chunk-major
    f16* V_t  = (f16*)(ws + 29360128);    // 16 MB, chunk-major transposed+permuted
    f16* q_h  = (f16*)(ws + 46137344);    //  8 MB (b,h,q,d), pre-scaled by log2e
    f16* a_o  = (f16*)(ws + 54525952);    //  8 MB (b,q,h*64+d)
    float* mL = (float*)(ws + 62914560);  // 32 KB (mask * log2e)

    preprocess_slim<<<1280, 256, 0, stream>>>(hs, hs_h, Wq, Wq_t);
    gemm0_fused<<<2692, 512, 0, stream>>>(hs_h, Wq_t, q_h, K, K_h, V, V_t,
                                          Wo, Wo_t, mask, mL);
    attn_fused<<<512, 512, 0, stream>>>(q_h, K_h, V_t, mL, a_o);
    gemm_tn1<<<512, 512, 0, stream>>>(a_o, Wo_t, out);
}